// Round 1
// baseline (5111.304 us; speedup 1.0000x reference)
//
#include <hip/hip_runtime.h>
#include <math.h>

#define CC 896
#define TT 512
#define BB 4
#define HH 14
#define NN 64
#define DD 64
#define DGG 160
#define FF4 3584
#define MM (BB*TT)   // 2048

__device__ __forceinline__ float waveRedSum(float x) {
#pragma unroll
  for (int off = 32; off > 0; off >>= 1) x += __shfl_xor(x, off, 64);
  return x;
}

__device__ __forceinline__ float sigmoidf_(float x) { return 1.f / (1.f + expf(-x)); }

// ---------------- LayerNorm (optionally gathering via idx) ----------------
__global__ __launch_bounds__(256)
void ln_kernel(const float* __restrict__ in, const int* __restrict__ idx,
               const float* __restrict__ w, const float* __restrict__ bvec,
               float* __restrict__ out)
{
  int m = blockIdx.x;
  const float* row = idx ? (in + (size_t)idx[m] * CC) : (in + (size_t)m * CC);
  float s = 0.f, s2 = 0.f;
  for (int c = threadIdx.x; c < CC; c += 256) { float x = row[c]; s += x; s2 += x * x; }
  __shared__ float red[2][4];
  float a = waveRedSum(s), b2 = waveRedSum(s2);
  int wid = threadIdx.x >> 6;
  if ((threadIdx.x & 63) == 0) { red[0][wid] = a; red[1][wid] = b2; }
  __syncthreads();
  s  = red[0][0] + red[0][1] + red[0][2] + red[0][3];
  s2 = red[1][0] + red[1][1] + red[1][2] + red[1][3];
  float mean = s * (1.f / CC);
  float var  = s2 * (1.f / CC) - mean * mean;
  float inv  = rsqrtf(var + 1e-5f);
  float* orow = out + (size_t)m * CC;
  for (int c = threadIdx.x; c < CC; c += 256)
    orow[c] = (row[c] - mean) * inv * w[c] + bvec[c];
}

// ---------------- final LN + head (dot with head_w) ----------------
__global__ __launch_bounds__(256)
void head_kernel(const float* __restrict__ x, const float* __restrict__ w,
                 const float* __restrict__ bvec, const float* __restrict__ hw,
                 float* __restrict__ out)
{
  int m = blockIdx.x;
  const float* row = x + (size_t)m * CC;
  float s = 0.f, s2 = 0.f;
  for (int c = threadIdx.x; c < CC; c += 256) { float v = row[c]; s += v; s2 += v * v; }
  __shared__ float red[2][4];
  float a = waveRedSum(s), b2 = waveRedSum(s2);
  int wid = threadIdx.x >> 6;
  if ((threadIdx.x & 63) == 0) { red[0][wid] = a; red[1][wid] = b2; }
  __syncthreads();
  s  = red[0][0] + red[0][1] + red[0][2] + red[0][3];
  s2 = red[1][0] + red[1][1] + red[1][2] + red[1][3];
  float mean = s * (1.f / CC);
  float var  = s2 * (1.f / CC) - mean * mean;
  float inv  = rsqrtf(var + 1e-5f);
  float p = 0.f;
  for (int c = threadIdx.x; c < CC; c += 256)
    p += ((row[c] - mean) * inv * w[c] + bvec[c]) * hw[c];
  p = waveRedSum(p);
  __shared__ float red2[4];
  if ((threadIdx.x & 63) == 0) red2[wid] = p;
  __syncthreads();
  if (threadIdx.x == 0) out[m] = red2[0] + red2[1] + red2[2] + red2[3];
}

// ---------------- token-shift mix: out = xn + (shift(xn)-xn)*coef ----------------
__global__ __launch_bounds__(256)
void mix_kernel(const float* __restrict__ xn, const float* __restrict__ coef,
                float* __restrict__ out)
{
  size_t i = (size_t)blockIdx.x * 256 + threadIdx.x;  // covers MM*CC exactly
  int c = (int)(i % CC);
  size_t m = i / CC;
  int t = (int)(m % TT);
  float cur  = xn[i];
  float prev = (t > 0) ? xn[i - CC] : 0.f;
  out[i] = cur + (prev - cur) * coef[c];
}

// ---------------- generic tiled f32 GEMM with epilogues ----------------
// EPI: 0 none, 1 tanh, 2 decay(-softplus w/ bias then exp(-exp)), 3 sigmoid(bias+acc),
//      4 v-gate, 5 sigmoid(acc), 6 add-to-out, 7 relu^2
template<int EPI>
__global__ __launch_bounds__(256)
void gemm_kernel(const float* __restrict__ A, const float* __restrict__ B,
                 float* __restrict__ Cout, int M, int N, int K,
                 const float* __restrict__ bias,
                 const float* __restrict__ aux0, const float* __restrict__ aux1)
{
  __shared__ __align__(16) float As[16][68];
  __shared__ __align__(16) float Bs[16][68];
  int tid = threadIdx.x;
  int tx = tid & 15, ty = tid >> 4;
  int row0 = blockIdx.y * 64, col0 = blockIdx.x * 64;
  float acc[4][4] = {};
  int a_m = tid >> 2;
  int a_k = (tid & 3) * 4;
  int b_k = tid >> 4;
  int b_n = (tid & 15) * 4;
  for (int k0 = 0; k0 < K; k0 += 16) {
    float4 av = *(const float4*)(A + (size_t)(row0 + a_m) * K + k0 + a_k);
    As[a_k + 0][a_m] = av.x; As[a_k + 1][a_m] = av.y;
    As[a_k + 2][a_m] = av.z; As[a_k + 3][a_m] = av.w;
    float4 bv;
    if (col0 + b_n < N) bv = *(const float4*)(B + (size_t)(k0 + b_k) * N + col0 + b_n);
    else bv = make_float4(0.f, 0.f, 0.f, 0.f);
    *(float4*)&Bs[b_k][b_n] = bv;
    __syncthreads();
#pragma unroll
    for (int kk = 0; kk < 16; kk++) {
      float af[4], bf[4];
#pragma unroll
      for (int i = 0; i < 4; i++) af[i] = As[kk][ty * 4 + i];
#pragma unroll
      for (int j = 0; j < 4; j++) bf[j] = Bs[kk][tx * 4 + j];
#pragma unroll
      for (int i = 0; i < 4; i++)
#pragma unroll
        for (int j = 0; j < 4; j++)
          acc[i][j] = fmaf(af[i], bf[j], acc[i][j]);
    }
    __syncthreads();
  }
#pragma unroll
  for (int i = 0; i < 4; i++) {
    int m = row0 + ty * 4 + i;
#pragma unroll
    for (int j = 0; j < 4; j++) {
      int n = col0 + tx * 4 + j;
      if (n >= N) continue;
      size_t off = (size_t)m * N + n;
      float v = acc[i][j];
      if constexpr (EPI == 0) {
        Cout[off] = v;
      } else if constexpr (EPI == 1) {
        Cout[off] = tanhf(v);
      } else if constexpr (EPI == 2) {
        float z = bias[n] + v;
        float sp = fmaxf(-z, 0.f) + log1pf(expf(-fabsf(z)));  // softplus(-z)
        float w = -sp - 0.5f;
        Cout[off] = expf(-expf(w));
      } else if constexpr (EPI == 3) {
        Cout[off] = sigmoidf_(bias[n] + v);
      } else if constexpr (EPI == 4) {
        float sgate = sigmoidf_(bias[n] + v);
        float vv = aux0[off];
        Cout[off] = vv + (aux1[off] - vv) * sgate;
      } else if constexpr (EPI == 5) {
        Cout[off] = sigmoidf_(v);
      } else if constexpr (EPI == 6) {
        Cout[off] += v;
      } else if constexpr (EPI == 7) {
        float t = fmaxf(v, 0.f);
        Cout[off] = t * t;
      }
    }
  }
}

// ---------------- prep: kk norm, a_in=-kk, b_in=kk*a, k gating ----------------
__global__ __launch_bounds__(896)
void prep_kernel(const float* __restrict__ k_in, const float* __restrict__ a,
                 const float* __restrict__ k_k, const float* __restrict__ k_a,
                 float* __restrict__ kout, float* __restrict__ ain, float* __restrict__ bin)
{
  int m = blockIdx.x;
  int c = threadIdx.x;
  size_t off = (size_t)m * CC + c;
  float kv = k_in[off];
  float av = a[off];
  float kkv = kv * k_k[c];
  float ss = waveRedSum(kkv * kkv);
  float norm = sqrtf(ss);
  float kkn = kkv / fmaxf(norm, 1e-12f);
  ain[off] = -kkn;
  bin[off] = kkn * av;
  kout[off] = kv * (1.f + (av - 1.f) * k_a[c]);
}

// ---------------- RWKV7 sequential scan: one wave per (b,h), lane=row ----------------
__global__ __launch_bounds__(64)
void scan_kernel(const float* __restrict__ rp, const float* __restrict__ dp,
                 const float* __restrict__ kp, const float* __restrict__ vp,
                 const float* __restrict__ ap, const float* __restrict__ bp,
                 float* __restrict__ yp)
{
  int bh = blockIdx.x;
  int b = bh / HH, h = bh - b * HH;
  int lane = threadIdx.x;
  __shared__ __align__(16) float lr[64], ld[64], lk[64], la[64], lb[64];
  float s[64];
#pragma unroll
  for (int j = 0; j < 64; j++) s[j] = 0.f;
  size_t base = ((size_t)b * TT) * CC + h * NN + lane;
  float pr = rp[base], pd = dp[base], pk = kp[base], pa = ap[base], pb = bp[base], pv = vp[base];
  for (int t = 0; t < TT; t++) {
    lr[lane] = pr; ld[lane] = pd; lk[lane] = pk; la[lane] = pa; lb[lane] = pb;
    float vi = pv;
    __syncthreads();
    if (t + 1 < TT) {
      size_t nb = base + (size_t)(t + 1) * CC;
      pr = rp[nb]; pd = dp[nb]; pk = kp[nb]; pa = ap[nb]; pb = bp[nb]; pv = vp[nb];
    }
    float sa = 0.f;
#pragma unroll
    for (int j = 0; j < 64; j += 4) {
      float4 aa = *(const float4*)&la[j];
      sa = fmaf(s[j], aa.x, sa); sa = fmaf(s[j + 1], aa.y, sa);
      sa = fmaf(s[j + 2], aa.z, sa); sa = fmaf(s[j + 3], aa.w, sa);
    }
    float yi = 0.f;
#pragma unroll
    for (int j = 0; j < 64; j += 4) {
      float4 dd  = *(const float4*)&ld[j];
      float4 bb4 = *(const float4*)&lb[j];
      float4 kk4 = *(const float4*)&lk[j];
      float4 rr4 = *(const float4*)&lr[j];
      s[j + 0] = fmaf(s[j + 0], dd.x, fmaf(sa, bb4.x, vi * kk4.x)); yi = fmaf(s[j + 0], rr4.x, yi);
      s[j + 1] = fmaf(s[j + 1], dd.y, fmaf(sa, bb4.y, vi * kk4.y)); yi = fmaf(s[j + 1], rr4.y, yi);
      s[j + 2] = fmaf(s[j + 2], dd.z, fmaf(sa, bb4.z, vi * kk4.z)); yi = fmaf(s[j + 2], rr4.z, yi);
      s[j + 3] = fmaf(s[j + 3], dd.w, fmaf(sa, bb4.w, vi * kk4.w)); yi = fmaf(s[j + 3], rr4.w, yi);
    }
    yp[base + (size_t)t * CC] = yi;
    __syncthreads();
  }
}

// ---------------- groupnorm + rk*v + *g ----------------
__global__ __launch_bounds__(896)
void gn_kernel(const float* __restrict__ y_in, const float* __restrict__ r,
               const float* __restrict__ k, const float* __restrict__ v,
               const float* __restrict__ g, const float* __restrict__ lnx_w,
               const float* __restrict__ lnx_b, const float* __restrict__ r_k,
               float* __restrict__ yout)
{
  int m = blockIdx.x;
  int c = threadIdx.x;
  size_t off = (size_t)m * CC + c;
  float yv = y_in[off];
  float s1 = waveRedSum(yv);
  float s2 = waveRedSum(yv * yv);
  float mean = s1 * (1.f / 64.f);
  float var  = s2 * (1.f / 64.f) - mean * mean;
  float norm = (yv - mean) * rsqrtf(var + 0.00064f);
  float rv = r[off], kv = k[off], vv = v[off];
  float rk = waveRedSum(rv * kv * r_k[c]);
  yout[off] = (norm * lnx_w[c] + lnx_b[c] + rk * vv) * g[off];
}

// ---------------- host ----------------
extern "C" void kernel_launch(void* const* d_in, const int* in_sizes, int n_in,
                              void* d_out, int out_size, void* d_ws, size_t ws_size,
                              hipStream_t stream)
{
  const int*   idx    = (const int*)d_in[0];
  const float* emb    = (const float*)d_in[1];
  const float* ln0_w  = (const float*)d_in[2];
  const float* ln0_b  = (const float*)d_in[3];
  const float* ln1_w  = (const float*)d_in[4];
  const float* ln1_b  = (const float*)d_in[5];
  const float* ln2_w  = (const float*)d_in[6];
  const float* ln2_b  = (const float*)d_in[7];
  const float* x_r    = (const float*)d_in[8];
  const float* x_w    = (const float*)d_in[9];
  const float* x_k    = (const float*)d_in[10];
  const float* x_v    = (const float*)d_in[11];
  const float* x_a    = (const float*)d_in[12];
  const float* x_g    = (const float*)d_in[13];
  const float* w0     = (const float*)d_in[14];
  const float* w1     = (const float*)d_in[15];
  const float* w2     = (const float*)d_in[16];
  const float* a0     = (const float*)d_in[17];
  const float* a1     = (const float*)d_in[18];
  const float* a2     = (const float*)d_in[19];
  const float* v0     = (const float*)d_in[20];
  const float* v1     = (const float*)d_in[21];
  const float* v2     = (const float*)d_in[22];
  const float* g1     = (const float*)d_in[23];
  const float* g2     = (const float*)d_in[24];
  const float* k_k    = (const float*)d_in[25];
  const float* k_a    = (const float*)d_in[26];
  const float* r_k    = (const float*)d_in[27];
  const float* Wr     = (const float*)d_in[28];
  const float* Wk     = (const float*)d_in[29];
  const float* Wv     = (const float*)d_in[30];
  const float* Wo     = (const float*)d_in[31];
  const float* lnx_w  = (const float*)d_in[32];
  const float* lnx_b  = (const float*)d_in[33];
  const float* f_xk   = (const float*)d_in[34];
  const float* f_key  = (const float*)d_in[35];
  const float* f_val  = (const float*)d_in[36];
  const float* lnout_w = (const float*)d_in[37];
  const float* lnout_b = (const float*)d_in[38];
  const float* head_w  = (const float*)d_in[39];
  float* out = (float*)d_out;

  const size_t MC = (size_t)MM * CC;
  float* ws   = (float*)d_ws;
  float* x    = ws;
  float* xn   = x + MC;
  float* mixb = xn + MC;
  float* vfirst = mixb + MC;
  float* rb   = vfirst + MC;
  float* dcy  = rb + MC;      // also reused as h chunk buffer (512*3584 == MC)
  float* kb   = dcy + MC;
  float* vb   = kb + MC;
  float* ab   = vb + MC;
  float* gb   = ab + MC;
  float* ainb = gb + MC;
  float* binb = ainb + MC;
  float* yb   = binb + MC;
  float* t64  = yb + MC;
  float* t160 = t64 + (size_t)MM * DD;

  dim3 blk(256);
  const int MIX_GRID = (int)(MC / 256);  // exact

  // embed gather + ln0
  ln_kernel<<<MM, blk, 0, stream>>>(emb, idx, ln0_w, ln0_b, x);

  for (int l = 0; l < 2; l++) {
    const float* Wr_l = Wr + (size_t)l * CC * CC;
    const float* Wk_l = Wk + (size_t)l * CC * CC;
    const float* Wv_l = Wv + (size_t)l * CC * CC;
    const float* Wo_l = Wo + (size_t)l * CC * CC;
    const float* w1_l = w1 + (size_t)l * CC * DD;
    const float* w2_l = w2 + (size_t)l * DD * CC;
    const float* a1_l = a1 + (size_t)l * CC * DD;
    const float* a2_l = a2 + (size_t)l * DD * CC;
    const float* v1_l = v1 + (size_t)l * CC * DD;
    const float* v2_l = v2 + (size_t)l * DD * CC;
    const float* g1_l = g1 + (size_t)l * CC * DGG;
    const float* g2_l = g2 + (size_t)l * DGG * CC;
    const float* fk_l = f_key + (size_t)l * CC * FF4;
    const float* fv_l = f_val + (size_t)l * FF4 * CC;

    // ln1
    ln_kernel<<<MM, blk, 0, stream>>>(x, nullptr, ln1_w + l * CC, ln1_b + l * CC, xn);

    dim3 gCC(CC / 64, MM / 64);
    dim3 g64(1, MM / 64);
    dim3 g160((DGG + 63) / 64, MM / 64);

    // r
    mix_kernel<<<MIX_GRID, blk, 0, stream>>>(xn, x_r + l * CC, mixb);
    gemm_kernel<0><<<gCC, blk, 0, stream>>>(mixb, Wr_l, rb, MM, CC, CC, nullptr, nullptr, nullptr);
    // w -> decay
    mix_kernel<<<MIX_GRID, blk, 0, stream>>>(xn, x_w + l * CC, mixb);
    gemm_kernel<1><<<g64, blk, 0, stream>>>(mixb, w1_l, t64, MM, DD, CC, nullptr, nullptr, nullptr);
    gemm_kernel<2><<<gCC, blk, 0, stream>>>(t64, w2_l, dcy, MM, CC, DD, w0 + l * CC, nullptr, nullptr);
    // k
    mix_kernel<<<MIX_GRID, blk, 0, stream>>>(xn, x_k + l * CC, mixb);
    gemm_kernel<0><<<gCC, blk, 0, stream>>>(mixb, Wk_l, kb, MM, CC, CC, nullptr, nullptr, nullptr);
    // v (+ gate for l>0)
    mix_kernel<<<MIX_GRID, blk, 0, stream>>>(xn, x_v + l * CC, mixb);
    gemm_kernel<0><<<gCC, blk, 0, stream>>>(mixb, Wv_l, vb, MM, CC, CC, nullptr, nullptr, nullptr);
    if (l == 0) {
      hipMemcpyAsync(vfirst, vb, MC * sizeof(float), hipMemcpyDeviceToDevice, stream);
    } else {
      gemm_kernel<0><<<g64, blk, 0, stream>>>(mixb, v1_l, t64, MM, DD, CC, nullptr, nullptr, nullptr);
      gemm_kernel<4><<<gCC, blk, 0, stream>>>(t64, v2_l, vb, MM, CC, DD, v0 + l * CC, vb, vfirst);
    }
    // a
    mix_kernel<<<MIX_GRID, blk, 0, stream>>>(xn, x_a + l * CC, mixb);
    gemm_kernel<0><<<g64, blk, 0, stream>>>(mixb, a1_l, t64, MM, DD, CC, nullptr, nullptr, nullptr);
    gemm_kernel<3><<<gCC, blk, 0, stream>>>(t64, a2_l, ab, MM, CC, DD, a0 + l * CC, nullptr, nullptr);
    // g
    mix_kernel<<<MIX_GRID, blk, 0, stream>>>(xn, x_g + l * CC, mixb);
    gemm_kernel<5><<<g160, blk, 0, stream>>>(mixb, g1_l, t160, MM, DGG, CC, nullptr, nullptr, nullptr);
    gemm_kernel<0><<<gCC, blk, 0, stream>>>(t160, g2_l, gb, MM, CC, DGG, nullptr, nullptr, nullptr);
    // prep (kk norm etc)
    prep_kernel<<<MM, dim3(896), 0, stream>>>(kb, ab, k_k + l * CC, k_a + l * CC, kb, ainb, binb);
    // scan
    scan_kernel<<<BB * HH, dim3(64), 0, stream>>>(rb, dcy, kb, vb, ainb, binb, yb);
    // groupnorm + rk*v + gate
    gn_kernel<<<MM, dim3(896), 0, stream>>>(yb, rb, kb, vb, gb, lnx_w + l * CC, lnx_b + l * CC,
                                            r_k + (size_t)l * CC, yb);
    // x += (y*g) @ Wo
    gemm_kernel<6><<<gCC, blk, 0, stream>>>(yb, Wo_l, x, MM, CC, CC, nullptr, nullptr, nullptr);

    // ---- channel mix ----
    ln_kernel<<<MM, blk, 0, stream>>>(x, nullptr, ln2_w + l * CC, ln2_b + l * CC, xn);
    mix_kernel<<<MIX_GRID, blk, 0, stream>>>(xn, f_xk + l * CC, mixb);
    for (int ch = 0; ch < 4; ch++) {
      const float* A1 = mixb + (size_t)ch * 512 * CC;
      float* xc = x + (size_t)ch * 512 * CC;
      dim3 gF(FF4 / 64, 512 / 64);
      dim3 gC2(CC / 64, 512 / 64);
      gemm_kernel<7><<<gF, blk, 0, stream>>>(A1, fk_l, dcy, 512, FF4, CC, nullptr, nullptr, nullptr);
      gemm_kernel<6><<<gC2, blk, 0, stream>>>(dcy, fv_l, xc, 512, CC, FF4, nullptr, nullptr, nullptr);
    }
  }

  // final LN + head
  head_kernel<<<MM, blk, 0, stream>>>(x, lnout_w, lnout_b, head_w, out);
}

// Round 2
// 2805.739 us; speedup vs baseline: 1.8217x; 1.8217x over previous
//
#include <hip/hip_runtime.h>
#include <hip/hip_bf16.h>
#include <math.h>

#define CC 896
#define TT 512
#define BB 4
#define HH 14
#define NN 64
#define DD 64
#define DGG 160
#define FF4 3584
#define MM (BB*TT)   // 2048

typedef __attribute__((ext_vector_type(8))) short bf16x8;
typedef __attribute__((ext_vector_type(4))) float f32x4;

__device__ __forceinline__ float waveRedSum(float x) {
#pragma unroll
  for (int off = 32; off > 0; off >>= 1) x += __shfl_xor(x, off, 64);
  return x;
}

__device__ __forceinline__ float sigmoidf_(float x) { return 1.f / (1.f + expf(-x)); }

__device__ __forceinline__ void gload_lds16(const void* g, void* l) {
  __builtin_amdgcn_global_load_lds((const __attribute__((address_space(1))) void*)g,
                                   (__attribute__((address_space(3))) void*)l, 16, 0, 0);
}

// ---------------- LayerNorm (optionally gathering via idx) ----------------
__global__ __launch_bounds__(256)
void ln_kernel(const float* __restrict__ in, const int* __restrict__ idx,
               const float* __restrict__ w, const float* __restrict__ bvec,
               float* __restrict__ out)
{
  int m = blockIdx.x;
  const float* row = idx ? (in + (size_t)idx[m] * CC) : (in + (size_t)m * CC);
  float s = 0.f, s2 = 0.f;
  for (int c = threadIdx.x; c < CC; c += 256) { float x = row[c]; s += x; s2 += x * x; }
  __shared__ float red[2][4];
  float a = waveRedSum(s), b2 = waveRedSum(s2);
  int wid = threadIdx.x >> 6;
  if ((threadIdx.x & 63) == 0) { red[0][wid] = a; red[1][wid] = b2; }
  __syncthreads();
  s  = red[0][0] + red[0][1] + red[0][2] + red[0][3];
  s2 = red[1][0] + red[1][1] + red[1][2] + red[1][3];
  float mean = s * (1.f / CC);
  float var  = s2 * (1.f / CC) - mean * mean;
  float inv  = rsqrtf(var + 1e-5f);
  float* orow = out + (size_t)m * CC;
  for (int c = threadIdx.x; c < CC; c += 256)
    orow[c] = (row[c] - mean) * inv * w[c] + bvec[c];
}

// ---------------- final LN + head ----------------
__global__ __launch_bounds__(256)
void head_kernel(const float* __restrict__ x, const float* __restrict__ w,
                 const float* __restrict__ bvec, const float* __restrict__ hw,
                 float* __restrict__ out)
{
  int m = blockIdx.x;
  const float* row = x + (size_t)m * CC;
  float s = 0.f, s2 = 0.f;
  for (int c = threadIdx.x; c < CC; c += 256) { float v = row[c]; s += v; s2 += v * v; }
  __shared__ float red[2][4];
  float a = waveRedSum(s), b2 = waveRedSum(s2);
  int wid = threadIdx.x >> 6;
  if ((threadIdx.x & 63) == 0) { red[0][wid] = a; red[1][wid] = b2; }
  __syncthreads();
  s  = red[0][0] + red[0][1] + red[0][2] + red[0][3];
  s2 = red[1][0] + red[1][1] + red[1][2] + red[1][3];
  float mean = s * (1.f / CC);
  float var  = s2 * (1.f / CC) - mean * mean;
  float inv  = rsqrtf(var + 1e-5f);
  float p = 0.f;
  for (int c = threadIdx.x; c < CC; c += 256)
    p += ((row[c] - mean) * inv * w[c] + bvec[c]) * hw[c];
  p = waveRedSum(p);
  __shared__ float red2[4];
  if ((threadIdx.x & 63) == 0) red2[wid] = p;
  __syncthreads();
  if (threadIdx.x == 0) out[m] = red2[0] + red2[1] + red2[2] + red2[3];
}

// ---------------- token-shift mix: fp32 + bf16 outputs ----------------
__global__ __launch_bounds__(256)
void mix_kernel(const float* __restrict__ xn, const float* __restrict__ coef,
                float* __restrict__ outf, __hip_bfloat16* __restrict__ outb)
{
  size_t i = (size_t)blockIdx.x * 256 + threadIdx.x;
  int c = (int)(i % CC);
  size_t m = i / CC;
  int t = (int)(m % TT);
  float cur  = xn[i];
  float prev = (t > 0) ? xn[i - CC] : 0.f;
  float val = cur + (prev - cur) * coef[c];
  outf[i] = val;
  outb[i] = __float2bfloat16(val);
}

// ---------------- convert + transpose: W[K][N] f32 -> Wt[N][K] bf16 ----------------
__global__ __launch_bounds__(256)
void convT_kernel(const float* __restrict__ W, __hip_bfloat16* __restrict__ Wt,
                  int K, int N)
{
  __shared__ float tile[32][33];
  int bn = blockIdx.x * 32, bk = blockIdx.y * 32;
  int tx = threadIdx.x & 31, ty = threadIdx.x >> 5;  // ty 0..7
#pragma unroll
  for (int i = 0; i < 4; i++)
    tile[ty + i * 8][tx] = W[(size_t)(bk + ty + i * 8) * N + bn + tx];
  __syncthreads();
#pragma unroll
  for (int i = 0; i < 4; i++)
    Wt[(size_t)(bn + ty + i * 8) * K + bk + tx] = __float2bfloat16(tile[tx][ty + i * 8]);
}

// ---------------- bf16 MFMA GEMM: C[M][N] = A[M][K] * Bt[N][K]^T ----------------
// MEPI: 0 store f32, 1 add into f32, 2 relu^2 -> bf16
template<int MEPI>
__global__ __launch_bounds__(256)
void gemm_bf16(const __hip_bfloat16* __restrict__ A, const __hip_bfloat16* __restrict__ Bt,
               float* __restrict__ C, __hip_bfloat16* __restrict__ Cbf,
               int N, int K)
{
  __shared__ __align__(16) ushort As[128 * 64];
  __shared__ __align__(16) ushort Bs[128 * 64];
  int tid = threadIdx.x;
  int lane = tid & 63, wave = tid >> 6;
  int wm = wave >> 1, wn = wave & 1;
  int fl = lane & 15, fh = lane >> 4;
  int row0 = blockIdx.y * 128, col0 = blockIdx.x * 128;

  const char* Abase = (const char*)A + (size_t)row0 * (size_t)(K * 2);
  const char* Bbase = (const char*)Bt + (size_t)col0 * (size_t)(K * 2);
  char* AsB = (char*)As;
  char* BsB = (char*)Bs;

  f32x4 acc[4][4];
#pragma unroll
  for (int mi = 0; mi < 4; mi++)
#pragma unroll
    for (int ni = 0; ni < 4; ni++)
      acc[mi][ni] = (f32x4){0.f, 0.f, 0.f, 0.f};

  int srow = tid >> 3;            // 0..31
  int scol = (tid & 7) << 4;      // byte in 128B row
  int ldsw = (wave << 10);        // wave-uniform base within 4KB chunk

  for (int k0 = 0; k0 < K; k0 += 64) {
#pragma unroll
    for (int it = 0; it < 4; ++it) {
      int r = it * 32 + srow;
      int cbs = scol ^ ((r & 7) << 4);
      size_t goff = (size_t)r * (size_t)(K * 2) + (size_t)(k0 * 2) + cbs;
      gload_lds16(Abase + goff, AsB + (it << 12) + ldsw);
      gload_lds16(Bbase + goff, BsB + (it << 12) + ldsw);
    }
    __syncthreads();
#pragma unroll
    for (int kk = 0; kk < 2; ++kk) {
      bf16x8 af[4], bfr[4];
      int kb_ = kk * 64 + (fh << 4);
#pragma unroll
      for (int mi = 0; mi < 4; mi++) {
        int r = wm * 64 + mi * 16 + fl;
        af[mi] = *(const bf16x8*)(AsB + r * 128 + (kb_ ^ ((r & 7) << 4)));
      }
#pragma unroll
      for (int ni = 0; ni < 4; ni++) {
        int r = wn * 64 + ni * 16 + fl;
        bfr[ni] = *(const bf16x8*)(BsB + r * 128 + (kb_ ^ ((r & 7) << 4)));
      }
#pragma unroll
      for (int mi = 0; mi < 4; mi++)
#pragma unroll
        for (int ni = 0; ni < 4; ni++)
          acc[mi][ni] = __builtin_amdgcn_mfma_f32_16x16x32_bf16(af[mi], bfr[ni], acc[mi][ni], 0, 0, 0);
    }
    __syncthreads();
  }

#pragma unroll
  for (int mi = 0; mi < 4; mi++) {
    int crow0 = row0 + wm * 64 + mi * 16 + fh * 4;
#pragma unroll
    for (int ni = 0; ni < 4; ni++) {
      int ccol = col0 + wn * 64 + ni * 16 + fl;
#pragma unroll
      for (int e = 0; e < 4; e++) {
        size_t off = (size_t)(crow0 + e) * N + ccol;
        float v = acc[mi][ni][e];
        if constexpr (MEPI == 0) {
          C[off] = v;
        } else if constexpr (MEPI == 1) {
          C[off] += v;
        } else if constexpr (MEPI == 2) {
          float t = fmaxf(v, 0.f);
          Cbf[off] = __float2bfloat16(t * t);
        }
      }
    }
  }
}

// ---------------- generic tiled f32 GEMM with epilogues (small matrices) ----------------
// EPI: 0 none, 1 tanh, 2 decay, 3 sigmoid(bias+acc), 4 v-gate, 5 sigmoid(acc)
template<int EPI>
__global__ __launch_bounds__(256)
void gemm_kernel(const float* __restrict__ A, const float* __restrict__ B,
                 float* __restrict__ Cout, int M, int N, int K,
                 const float* __restrict__ bias,
                 const float* __restrict__ aux0, const float* __restrict__ aux1)
{
  __shared__ __align__(16) float As[16][68];
  __shared__ __align__(16) float Bs[16][68];
  int tid = threadIdx.x;
  int tx = tid & 15, ty = tid >> 4;
  int row0 = blockIdx.y * 64, col0 = blockIdx.x * 64;
  float acc[4][4] = {};
  int a_m = tid >> 2;
  int a_k = (tid & 3) * 4;
  int b_k = tid >> 4;
  int b_n = (tid & 15) * 4;
  for (int k0 = 0; k0 < K; k0 += 16) {
    float4 av = *(const float4*)(A + (size_t)(row0 + a_m) * K + k0 + a_k);
    As[a_k + 0][a_m] = av.x; As[a_k + 1][a_m] = av.y;
    As[a_k + 2][a_m] = av.z; As[a_k + 3][a_m] = av.w;
    float4 bv;
    if (col0 + b_n < N) bv = *(const float4*)(B + (size_t)(k0 + b_k) * N + col0 + b_n);
    else bv = make_float4(0.f, 0.f, 0.f, 0.f);
    *(float4*)&Bs[b_k][b_n] = bv;
    __syncthreads();
#pragma unroll
    for (int kk = 0; kk < 16; kk++) {
      float af[4], bfv[4];
#pragma unroll
      for (int i = 0; i < 4; i++) af[i] = As[kk][ty * 4 + i];
#pragma unroll
      for (int j = 0; j < 4; j++) bfv[j] = Bs[kk][tx * 4 + j];
#pragma unroll
      for (int i = 0; i < 4; i++)
#pragma unroll
        for (int j = 0; j < 4; j++)
          acc[i][j] = fmaf(af[i], bfv[j], acc[i][j]);
    }
    __syncthreads();
  }
#pragma unroll
  for (int i = 0; i < 4; i++) {
    int m = row0 + ty * 4 + i;
#pragma unroll
    for (int j = 0; j < 4; j++) {
      int n = col0 + tx * 4 + j;
      if (n >= N) continue;
      size_t off = (size_t)m * N + n;
      float v = acc[i][j];
      if constexpr (EPI == 0) {
        Cout[off] = v;
      } else if constexpr (EPI == 1) {
        Cout[off] = tanhf(v);
      } else if constexpr (EPI == 2) {
        float z = bias[n] + v;
        float sp = fmaxf(-z, 0.f) + log1pf(expf(-fabsf(z)));
        float w = -sp - 0.5f;
        Cout[off] = expf(-expf(w));
      } else if constexpr (EPI == 3) {
        Cout[off] = sigmoidf_(bias[n] + v);
      } else if constexpr (EPI == 4) {
        float sgate = sigmoidf_(bias[n] + v);
        float vv = aux0[off];
        Cout[off] = vv + (aux1[off] - vv) * sgate;
      } else if constexpr (EPI == 5) {
        Cout[off] = sigmoidf_(v);
      }
    }
  }
}

// ---------------- prep: kk norm, a_in=-kk, b_in=kk*a, k gating ----------------
__global__ __launch_bounds__(896)
void prep_kernel(const float* __restrict__ k_in, const float* __restrict__ a,
                 const float* __restrict__ k_k, const float* __restrict__ k_a,
                 float* __restrict__ kout, float* __restrict__ ain, float* __restrict__ bin)
{
  int m = blockIdx.x;
  int c = threadIdx.x;
  size_t off = (size_t)m * CC + c;
  float kv = k_in[off];
  float av = a[off];
  float kkv = kv * k_k[c];
  float ss = waveRedSum(kkv * kkv);
  float norm = sqrtf(ss);
  float kkn = kkv / fmaxf(norm, 1e-12f);
  ain[off] = -kkn;
  bin[off] = kkn * av;
  kout[off] = kv * (1.f + (av - 1.f) * k_a[c]);
}

// ---------------- RWKV7 sequential scan: one wave per (b,h), lane=row ----------------
__global__ __launch_bounds__(64)
void scan_kernel(const float* __restrict__ rp, const float* __restrict__ dp,
                 const float* __restrict__ kp, const float* __restrict__ vp,
                 const float* __restrict__ ap, const float* __restrict__ bp,
                 float* __restrict__ yp)
{
  int bh = blockIdx.x;
  int b = bh / HH, h = bh - b * HH;
  int lane = threadIdx.x;
  __shared__ __align__(16) float lr[64], ld[64], lk[64], la[64], lb[64];
  float s[64];
#pragma unroll
  for (int j = 0; j < 64; j++) s[j] = 0.f;
  size_t base = ((size_t)b * TT) * CC + h * NN + lane;
  float pr = rp[base], pd = dp[base], pk = kp[base], pa = ap[base], pb = bp[base], pv = vp[base];
  for (int t = 0; t < TT; t++) {
    lr[lane] = pr; ld[lane] = pd; lk[lane] = pk; la[lane] = pa; lb[lane] = pb;
    float vi = pv;
    __syncthreads();
    if (t + 1 < TT) {
      size_t nb = base + (size_t)(t + 1) * CC;
      pr = rp[nb]; pd = dp[nb]; pk = kp[nb]; pa = ap[nb]; pb = bp[nb]; pv = vp[nb];
    }
    float sa0 = 0.f, sa1 = 0.f, sa2 = 0.f, sa3 = 0.f;
#pragma unroll
    for (int j = 0; j < 64; j += 4) {
      float4 aa = *(const float4*)&la[j];
      sa0 = fmaf(s[j], aa.x, sa0); sa1 = fmaf(s[j + 1], aa.y, sa1);
      sa2 = fmaf(s[j + 2], aa.z, sa2); sa3 = fmaf(s[j + 3], aa.w, sa3);
    }
    float sa = (sa0 + sa1) + (sa2 + sa3);
    float y0 = 0.f, y1 = 0.f, y2 = 0.f, y3 = 0.f;
#pragma unroll
    for (int j = 0; j < 64; j += 4) {
      float4 dd  = *(const float4*)&ld[j];
      float4 bb4 = *(const float4*)&lb[j];
      float4 kk4 = *(const float4*)&lk[j];
      float4 rr4 = *(const float4*)&lr[j];
      s[j + 0] = fmaf(s[j + 0], dd.x, fmaf(sa, bb4.x, vi * kk4.x)); y0 = fmaf(s[j + 0], rr4.x, y0);
      s[j + 1] = fmaf(s[j + 1], dd.y, fmaf(sa, bb4.y, vi * kk4.y)); y1 = fmaf(s[j + 1], rr4.y, y1);
      s[j + 2] = fmaf(s[j + 2], dd.z, fmaf(sa, bb4.z, vi * kk4.z)); y2 = fmaf(s[j + 2], rr4.z, y2);
      s[j + 3] = fmaf(s[j + 3], dd.w, fmaf(sa, bb4.w, vi * kk4.w)); y3 = fmaf(s[j + 3], rr4.w, y3);
    }
    yp[base + (size_t)t * CC] = (y0 + y1) + (y2 + y3);
    __syncthreads();
  }
}

// ---------------- groupnorm + rk*v + *g -> bf16 ----------------
__global__ __launch_bounds__(896)
void gn_kernel(const float* __restrict__ y_in, const float* __restrict__ r,
               const float* __restrict__ k, const float* __restrict__ v,
               const float* __restrict__ g, const float* __restrict__ lnx_w,
               const float* __restrict__ lnx_b, const float* __restrict__ r_k,
               __hip_bfloat16* __restrict__ yout_bf)
{
  int m = blockIdx.x;
  int c = threadIdx.x;
  size_t off = (size_t)m * CC + c;
  float yv = y_in[off];
  float s1 = waveRedSum(yv);
  float s2 = waveRedSum(yv * yv);
  float mean = s1 * (1.f / 64.f);
  float var  = s2 * (1.f / 64.f) - mean * mean;
  float norm = (yv - mean) * rsqrtf(var + 0.00064f);
  float rv = r[off], kv = k[off], vv = v[off];
  float rk = waveRedSum(rv * kv * r_k[c]);
  yout_bf[off] = __float2bfloat16((norm * lnx_w[c] + lnx_b[c] + rk * vv) * g[off]);
}

// ---------------- host ----------------
extern "C" void kernel_launch(void* const* d_in, const int* in_sizes, int n_in,
                              void* d_out, int out_size, void* d_ws, size_t ws_size,
                              hipStream_t stream)
{
  const int*   idx    = (const int*)d_in[0];
  const float* emb    = (const float*)d_in[1];
  const float* ln0_w  = (const float*)d_in[2];
  const float* ln0_b  = (const float*)d_in[3];
  const float* ln1_w  = (const float*)d_in[4];
  const float* ln1_b  = (const float*)d_in[5];
  const float* ln2_w  = (const float*)d_in[6];
  const float* ln2_b  = (const float*)d_in[7];
  const float* x_r    = (const float*)d_in[8];
  const float* x_w    = (const float*)d_in[9];
  const float* x_k    = (const float*)d_in[10];
  const float* x_v    = (const float*)d_in[11];
  const float* x_a    = (const float*)d_in[12];
  const float* x_g    = (const float*)d_in[13];
  const float* w0     = (const float*)d_in[14];
  const float* w1     = (const float*)d_in[15];
  const float* w2     = (const float*)d_in[16];
  const float* a0     = (const float*)d_in[17];
  const float* a1     = (const float*)d_in[18];
  const float* a2     = (const float*)d_in[19];
  const float* v0     = (const float*)d_in[20];
  const float* v1     = (const float*)d_in[21];
  const float* v2     = (const float*)d_in[22];
  const float* g1     = (const float*)d_in[23];
  const float* g2     = (const float*)d_in[24];
  const float* k_k    = (const float*)d_in[25];
  const float* k_a    = (const float*)d_in[26];
  const float* r_k    = (const float*)d_in[27];
  const float* Wr     = (const float*)d_in[28];
  const float* Wk     = (const float*)d_in[29];
  const float* Wv     = (const float*)d_in[30];
  const float* Wo     = (const float*)d_in[31];
  const float* lnx_w  = (const float*)d_in[32];
  const float* lnx_b  = (const float*)d_in[33];
  const float* f_xk   = (const float*)d_in[34];
  const float* f_key  = (const float*)d_in[35];
  const float* f_val  = (const float*)d_in[36];
  const float* lnout_w = (const float*)d_in[37];
  const float* lnout_b = (const float*)d_in[38];
  const float* head_w  = (const float*)d_in[39];
  float* out = (float*)d_out;

  const size_t MC = (size_t)MM * CC;
  const size_t W2 = (size_t)CC * CC;      // 802816
  float* ws   = (float*)d_ws;
  float* x    = ws;
  float* xn   = x + MC;
  float* mixb = xn + MC;
  float* vfirst = mixb + MC;
  float* rb   = vfirst + MC;
  float* dcy  = rb + MC;
  float* kb   = dcy + MC;
  float* vb   = kb + MC;
  float* ab   = vb + MC;
  float* gb   = ab + MC;
  float* ainb = gb + MC;
  float* binb = ainb + MC;
  float* yb   = binb + MC;
  float* t64  = yb + MC;
  float* t160 = t64 + (size_t)MM * DD;
  float* fend = t160 + (size_t)MM * DGG;

  __hip_bfloat16* mixb_bf = (__hip_bfloat16*)fend;
  __hip_bfloat16* wbf     = mixb_bf + MC;      // per-layer transposed weights, 9.63M bf16
  __hip_bfloat16* WrT = wbf;
  __hip_bfloat16* WkT = WrT + W2;
  __hip_bfloat16* WvT = WkT + W2;
  __hip_bfloat16* WoT = WvT + W2;
  __hip_bfloat16* fkT = WoT + W2;              // [3584][896]
  __hip_bfloat16* fvT = fkT + (size_t)FF4 * CC;// [896][3584]
  // aliases (dead fp32 buffers reused)
  __hip_bfloat16* h_bf = (__hip_bfloat16*)rb;  // [MM][FF4] spans rb+dcy (2*MC floats)
  __hip_bfloat16* yg_bf = (__hip_bfloat16*)ab; // [MM][CC]

  dim3 blk(256);
  const int MIX_GRID = (int)(MC / 256);

  ln_kernel<<<MM, blk, 0, stream>>>(emb, idx, ln0_w, ln0_b, x);

  for (int l = 0; l < 2; l++) {
    const float* Wr_l = Wr + (size_t)l * W2;
    const float* Wk_l = Wk + (size_t)l * W2;
    const float* Wv_l = Wv + (size_t)l * W2;
    const float* Wo_l = Wo + (size_t)l * W2;
    const float* w1_l = w1 + (size_t)l * CC * DD;
    const float* w2_l = w2 + (size_t)l * DD * CC;
    const float* a1_l = a1 + (size_t)l * CC * DD;
    const float* a2_l = a2 + (size_t)l * DD * CC;
    const float* v1_l = v1 + (size_t)l * CC * DD;
    const float* v2_l = v2 + (size_t)l * DD * CC;
    const float* g1_l = g1 + (size_t)l * CC * DGG;
    const float* g2_l = g2 + (size_t)l * DGG * CC;
    const float* fk_l = f_key + (size_t)l * CC * FF4;
    const float* fv_l = f_val + (size_t)l * FF4 * CC;

    // convert+transpose this layer's big weights to bf16
    convT_kernel<<<dim3(CC/32, CC/32), blk, 0, stream>>>(Wr_l, WrT, CC, CC);
    convT_kernel<<<dim3(CC/32, CC/32), blk, 0, stream>>>(Wk_l, WkT, CC, CC);
    convT_kernel<<<dim3(CC/32, CC/32), blk, 0, stream>>>(Wv_l, WvT, CC, CC);
    convT_kernel<<<dim3(CC/32, CC/32), blk, 0, stream>>>(Wo_l, WoT, CC, CC);
    convT_kernel<<<dim3(FF4/32, CC/32), blk, 0, stream>>>(fk_l, fkT, CC, FF4);
    convT_kernel<<<dim3(CC/32, FF4/32), blk, 0, stream>>>(fv_l, fvT, FF4, CC);

    ln_kernel<<<MM, blk, 0, stream>>>(x, nullptr, ln1_w + l * CC, ln1_b + l * CC, xn);

    dim3 gBig(CC / 128, MM / 128);     // (7,16)
    dim3 gF(FF4 / 128, MM / 128);      // (28,16)
    dim3 g64(1, MM / 64);
    dim3 g160((DGG + 63) / 64, MM / 64);
    dim3 gCCs(CC / 64, MM / 64);

    // r
    mix_kernel<<<MIX_GRID, blk, 0, stream>>>(xn, x_r + l * CC, mixb, mixb_bf);
    gemm_bf16<0><<<gBig, blk, 0, stream>>>(mixb_bf, WrT, rb, nullptr, CC, CC);
    // w -> decay (fp32 path, numerically sensitive)
    mix_kernel<<<MIX_GRID, blk, 0, stream>>>(xn, x_w + l * CC, mixb, mixb_bf);
    gemm_kernel<1><<<g64, blk, 0, stream>>>(mixb, w1_l, t64, MM, DD, CC, nullptr, nullptr, nullptr);
    gemm_kernel<2><<<gCCs, blk, 0, stream>>>(t64, w2_l, dcy, MM, CC, DD, w0 + l * CC, nullptr, nullptr);
    // k
    mix_kernel<<<MIX_GRID, blk, 0, stream>>>(xn, x_k + l * CC, mixb, mixb_bf);
    gemm_bf16<0><<<gBig, blk, 0, stream>>>(mixb_bf, WkT, kb, nullptr, CC, CC);
    // v
    mix_kernel<<<MIX_GRID, blk, 0, stream>>>(xn, x_v + l * CC, mixb, mixb_bf);
    gemm_bf16<0><<<gBig, blk, 0, stream>>>(mixb_bf, WvT, vb, nullptr, CC, CC);
    if (l == 0) {
      hipMemcpyAsync(vfirst, vb, MC * sizeof(float), hipMemcpyDeviceToDevice, stream);
    } else {
      gemm_kernel<0><<<g64, blk, 0, stream>>>(mixb, v1_l, t64, MM, DD, CC, nullptr, nullptr, nullptr);
      gemm_kernel<4><<<gCCs, blk, 0, stream>>>(t64, v2_l, vb, MM, CC, DD, v0 + l * CC, vb, vfirst);
    }
    // a
    mix_kernel<<<MIX_GRID, blk, 0, stream>>>(xn, x_a + l * CC, mixb, mixb_bf);
    gemm_kernel<0><<<g64, blk, 0, stream>>>(mixb, a1_l, t64, MM, DD, CC, nullptr, nullptr, nullptr);
    gemm_kernel<3><<<gCCs, blk, 0, stream>>>(t64, a2_l, ab, MM, CC, DD, a0 + l * CC, nullptr, nullptr);
    // g
    mix_kernel<<<MIX_GRID, blk, 0, stream>>>(xn, x_g + l * CC, mixb, mixb_bf);
    gemm_kernel<5><<<g160, blk, 0, stream>>>(mixb, g1_l, t160, MM, DGG, CC, nullptr, nullptr, nullptr);
    gemm_kernel<0><<<gCCs, blk, 0, stream>>>(t160, g2_l, gb, MM, CC, DGG, nullptr, nullptr, nullptr);
    // prep + scan + gn
    prep_kernel<<<MM, dim3(896), 0, stream>>>(kb, ab, k_k + l * CC, k_a + l * CC, kb, ainb, binb);
    scan_kernel<<<BB * HH, dim3(64), 0, stream>>>(rb, dcy, kb, vb, ainb, binb, yb);
    gn_kernel<<<MM, dim3(896), 0, stream>>>(yb, rb, kb, vb, gb, lnx_w + l * CC, lnx_b + l * CC,
                                            r_k + (size_t)l * CC, yg_bf);
    // x += (y*g) @ Wo
    gemm_bf16<1><<<gBig, blk, 0, stream>>>(yg_bf, WoT, x, nullptr, CC, CC);

    // ---- channel mix ----
    ln_kernel<<<MM, blk, 0, stream>>>(x, nullptr, ln2_w + l * CC, ln2_b + l * CC, xn);
    mix_kernel<<<MIX_GRID, blk, 0, stream>>>(xn, f_xk + l * CC, mixb, mixb_bf);
    gemm_bf16<2><<<gF, blk, 0, stream>>>(mixb_bf, fkT, nullptr, h_bf, FF4, CC);
    gemm_bf16<1><<<gBig, blk, 0, stream>>>(h_bf, fvT, x, nullptr, CC, FF4);
  }

  head_kernel<<<MM, blk, 0, stream>>>(x, lnout_w, lnout_b, head_w, out);
}

// Round 3
// 1489.325 us; speedup vs baseline: 3.4320x; 1.8839x over previous
//
#include <hip/hip_runtime.h>
#include <hip/hip_bf16.h>
#include <math.h>

#define CC 896
#define TT 512
#define BB 4
#define HH 14
#define NN 64
#define DD 64
#define DGG 160
#define FF4 3584
#define MM (BB*TT)   // 2048

typedef __attribute__((ext_vector_type(8))) short bf16x8;
typedef __attribute__((ext_vector_type(4))) float f32x4;

__device__ __forceinline__ float waveRedSum(float x) {
#pragma unroll
  for (int off = 32; off > 0; off >>= 1) x += __shfl_xor(x, off, 64);
  return x;
}

__device__ __forceinline__ float sigmoidf_(float x) { return 1.f / (1.f + expf(-x)); }

__device__ __forceinline__ void gload_lds16(const void* g, void* l) {
  __builtin_amdgcn_global_load_lds((const __attribute__((address_space(1))) void*)g,
                                   (__attribute__((address_space(3))) void*)l, 16, 0, 0);
}

// barrier that waits LDS only (keeps global prefetch loads in flight)
__device__ __forceinline__ void block_sync_lds() {
  asm volatile("s_waitcnt lgkmcnt(0)" ::: "memory");
  __builtin_amdgcn_s_barrier();
  asm volatile("" ::: "memory");
}

// ---------------- LayerNorm (optionally gathering via idx) ----------------
__global__ __launch_bounds__(256)
void ln_kernel(const float* __restrict__ in, const int* __restrict__ idx,
               const float* __restrict__ w, const float* __restrict__ bvec,
               float* __restrict__ out)
{
  int m = blockIdx.x;
  const float* row = idx ? (in + (size_t)idx[m] * CC) : (in + (size_t)m * CC);
  float s = 0.f, s2 = 0.f;
  for (int c = threadIdx.x; c < CC; c += 256) { float x = row[c]; s += x; s2 += x * x; }
  __shared__ float red[2][4];
  float a = waveRedSum(s), b2 = waveRedSum(s2);
  int wid = threadIdx.x >> 6;
  if ((threadIdx.x & 63) == 0) { red[0][wid] = a; red[1][wid] = b2; }
  __syncthreads();
  s  = red[0][0] + red[0][1] + red[0][2] + red[0][3];
  s2 = red[1][0] + red[1][1] + red[1][2] + red[1][3];
  float mean = s * (1.f / CC);
  float var  = s2 * (1.f / CC) - mean * mean;
  float inv  = rsqrtf(var + 1e-5f);
  float* orow = out + (size_t)m * CC;
  for (int c = threadIdx.x; c < CC; c += 256)
    orow[c] = (row[c] - mean) * inv * w[c] + bvec[c];
}

// ---------------- final LN + head ----------------
__global__ __launch_bounds__(256)
void head_kernel(const float* __restrict__ x, const float* __restrict__ w,
                 const float* __restrict__ bvec, const float* __restrict__ hw,
                 float* __restrict__ out)
{
  int m = blockIdx.x;
  const float* row = x + (size_t)m * CC;
  float s = 0.f, s2 = 0.f;
  for (int c = threadIdx.x; c < CC; c += 256) { float v = row[c]; s += v; s2 += v * v; }
  __shared__ float red[2][4];
  float a = waveRedSum(s), b2 = waveRedSum(s2);
  int wid = threadIdx.x >> 6;
  if ((threadIdx.x & 63) == 0) { red[0][wid] = a; red[1][wid] = b2; }
  __syncthreads();
  s  = red[0][0] + red[0][1] + red[0][2] + red[0][3];
  s2 = red[1][0] + red[1][1] + red[1][2] + red[1][3];
  float mean = s * (1.f / CC);
  float var  = s2 * (1.f / CC) - mean * mean;
  float inv  = rsqrtf(var + 1e-5f);
  float p = 0.f;
  for (int c = threadIdx.x; c < CC; c += 256)
    p += ((row[c] - mean) * inv * w[c] + bvec[c]) * hw[c];
  p = waveRedSum(p);
  __shared__ float red2[4];
  if ((threadIdx.x & 63) == 0) red2[wid] = p;
  __syncthreads();
  if (threadIdx.x == 0) out[m] = red2[0] + red2[1] + red2[2] + red2[3];
}

// ---------------- token-shift mix. MODE: 0=f32 only, 1=bf16 only, 2=both ----------------
template<int MODE>
__global__ __launch_bounds__(256)
void mix_kernel(const float* __restrict__ xn, const float* __restrict__ coef,
                float* __restrict__ outf, __hip_bfloat16* __restrict__ outb)
{
  size_t i = (size_t)blockIdx.x * 256 + threadIdx.x;
  int c = (int)(i % CC);
  size_t m = i / CC;
  int t = (int)(m % TT);
  float cur  = xn[i];
  float prev = (t > 0) ? xn[i - CC] : 0.f;
  float val = cur + (prev - cur) * coef[c];
  if constexpr (MODE == 0 || MODE == 2) outf[i] = val;
  if constexpr (MODE == 1 || MODE == 2) outb[i] = __float2bfloat16(val);
}

// ---------------- convert + transpose with padding ----------------
// W[K][N] f32 -> Wt[NP][KP] bf16 (zero-padded). grid (NP/32, KP/32)
__global__ __launch_bounds__(256)
void convT_kernel(const float* __restrict__ W, __hip_bfloat16* __restrict__ Wt,
                  int K, int N, int KP, int NP)
{
  __shared__ float tile[32][33];
  int bn = blockIdx.x * 32, bk = blockIdx.y * 32;
  int tx = threadIdx.x & 31, ty = threadIdx.x >> 5;
#pragma unroll
  for (int i = 0; i < 4; i++) {
    int k = bk + ty + i * 8, n = bn + tx;
    tile[ty + i * 8][tx] = (k < K && n < N) ? W[(size_t)k * N + n] : 0.f;
  }
  __syncthreads();
#pragma unroll
  for (int i = 0; i < 4; i++) {
    int n = bn + ty + i * 8, k = bk + tx;
    if (n < NP && k < KP)
      Wt[(size_t)n * KP + k] = __float2bfloat16(tile[tx][ty + i * 8]);
  }
}

// ---------------- bf16 MFMA GEMM: C[M][N] = A[M][K] * Bt[N][K]^T ----------------
// MEPI: 0 store f32, 1 add f32, 2 relu^2->bf16, 3 store bf16, 4 sigmoid->bf16 (pad0 past Nreal),
//       5 sigmoid(bias+v)->f32, 6 v-gate->f32
template<int MEPI, int BN>
__global__ __launch_bounds__(256)
void gemm_bf16(const __hip_bfloat16* __restrict__ A, const __hip_bfloat16* __restrict__ Bt,
               float* __restrict__ C, __hip_bfloat16* __restrict__ Cbf,
               int N, int K, const float* __restrict__ bias,
               const float* __restrict__ aux0, const float* __restrict__ aux1, int Nreal)
{
  constexpr int WN = BN / 64;        // 2 (BN=128) or 1 (BN=64)
  constexpr int WM = 4 / WN;         // 2 or 4
  constexpr int ROWS = 128 / WM;     // 64 or 32
  constexpr int MI = ROWS / 16;      // 4 or 2
  __shared__ __align__(16) ushort As[128 * 64];
  __shared__ __align__(16) ushort Bs[BN * 64];
  int tid = threadIdx.x;
  int lane = tid & 63, wave = tid >> 6;
  int wm, wn;
  if constexpr (WN == 2) { wm = wave >> 1; wn = wave & 1; } else { wm = wave; wn = 0; }
  int fl = lane & 15, fh = lane >> 4;
  int row0 = blockIdx.y * 128, col0 = blockIdx.x * BN;

  const char* Abase = (const char*)A + (size_t)row0 * (size_t)(K * 2);
  const char* Bbase = (const char*)Bt + (size_t)col0 * (size_t)(K * 2);
  char* AsB = (char*)As;
  char* BsB = (char*)Bs;

  f32x4 acc[MI][4];
#pragma unroll
  for (int mi = 0; mi < MI; mi++)
#pragma unroll
    for (int ni = 0; ni < 4; ni++)
      acc[mi][ni] = (f32x4){0.f, 0.f, 0.f, 0.f};

  int srow = tid >> 3;
  int scol = (tid & 7) << 4;
  int ldsw = (wave << 10);

  for (int k0 = 0; k0 < K; k0 += 64) {
#pragma unroll
    for (int it = 0; it < 4; ++it) {
      int r = it * 32 + srow;
      int cbs = scol ^ ((r & 7) << 4);
      size_t goff = (size_t)r * (size_t)(K * 2) + (size_t)(k0 * 2) + cbs;
      gload_lds16(Abase + goff, AsB + (it << 12) + ldsw);
      if constexpr (BN == 128) {
        gload_lds16(Bbase + goff, BsB + (it << 12) + ldsw);
      } else {
        if (it < 2) gload_lds16(Bbase + goff, BsB + (it << 12) + ldsw);
      }
    }
    __syncthreads();
#pragma unroll
    for (int kk = 0; kk < 2; ++kk) {
      bf16x8 af[MI], bfr[4];
      int kb_ = kk * 64 + (fh << 4);
#pragma unroll
      for (int mi = 0; mi < MI; mi++) {
        int r = wm * ROWS + mi * 16 + fl;
        af[mi] = *(const bf16x8*)(AsB + r * 128 + (kb_ ^ ((r & 7) << 4)));
      }
#pragma unroll
      for (int ni = 0; ni < 4; ni++) {
        int r = wn * 64 + ni * 16 + fl;
        bfr[ni] = *(const bf16x8*)(BsB + r * 128 + (kb_ ^ ((r & 7) << 4)));
      }
#pragma unroll
      for (int mi = 0; mi < MI; mi++)
#pragma unroll
        for (int ni = 0; ni < 4; ni++)
          acc[mi][ni] = __builtin_amdgcn_mfma_f32_16x16x32_bf16(af[mi], bfr[ni], acc[mi][ni], 0, 0, 0);
    }
    __syncthreads();
  }

#pragma unroll
  for (int mi = 0; mi < MI; mi++) {
    int crow0 = row0 + wm * ROWS + mi * 16 + fh * 4;
#pragma unroll
    for (int ni = 0; ni < 4; ni++) {
      int ccol = col0 + wn * 64 + ni * 16 + fl;
#pragma unroll
      for (int e = 0; e < 4; e++) {
        size_t off = (size_t)(crow0 + e) * N + ccol;
        float v = acc[mi][ni][e];
        if constexpr (MEPI == 0) {
          C[off] = v;
        } else if constexpr (MEPI == 1) {
          C[off] += v;
        } else if constexpr (MEPI == 2) {
          float t = fmaxf(v, 0.f);
          Cbf[off] = __float2bfloat16(t * t);
        } else if constexpr (MEPI == 3) {
          Cbf[off] = __float2bfloat16(v);
        } else if constexpr (MEPI == 4) {
          float sv = (ccol < Nreal) ? sigmoidf_(v) : 0.f;
          Cbf[off] = __float2bfloat16(sv);
        } else if constexpr (MEPI == 5) {
          C[off] = sigmoidf_(bias[ccol] + v);
        } else if constexpr (MEPI == 6) {
          float sg = sigmoidf_(bias[ccol] + v);
          float vv = aux0[off];
          C[off] = vv + (aux1[off] - vv) * sg;
        }
      }
    }
  }
}

// ---------------- f32 GEMM (w path only). EPI: 1 tanh, 2 decay ----------------
template<int EPI>
__global__ __launch_bounds__(256)
void gemm_kernel(const float* __restrict__ A, const float* __restrict__ B,
                 float* __restrict__ Cout, int M, int N, int K,
                 const float* __restrict__ bias)
{
  __shared__ __align__(16) float As[16][68];
  __shared__ __align__(16) float Bs[16][68];
  int tid = threadIdx.x;
  int tx = tid & 15, ty = tid >> 4;
  int row0 = blockIdx.y * 64, col0 = blockIdx.x * 64;
  float acc[4][4] = {};
  int a_m = tid >> 2;
  int a_k = (tid & 3) * 4;
  int b_k = tid >> 4;
  int b_n = (tid & 15) * 4;
  for (int k0 = 0; k0 < K; k0 += 16) {
    float4 av = *(const float4*)(A + (size_t)(row0 + a_m) * K + k0 + a_k);
    As[a_k + 0][a_m] = av.x; As[a_k + 1][a_m] = av.y;
    As[a_k + 2][a_m] = av.z; As[a_k + 3][a_m] = av.w;
    float4 bv;
    if (col0 + b_n < N) bv = *(const float4*)(B + (size_t)(k0 + b_k) * N + col0 + b_n);
    else bv = make_float4(0.f, 0.f, 0.f, 0.f);
    *(float4*)&Bs[b_k][b_n] = bv;
    __syncthreads();
#pragma unroll
    for (int kk = 0; kk < 16; kk++) {
      float af[4], bfv[4];
#pragma unroll
      for (int i = 0; i < 4; i++) af[i] = As[kk][ty * 4 + i];
#pragma unroll
      for (int j = 0; j < 4; j++) bfv[j] = Bs[kk][tx * 4 + j];
#pragma unroll
      for (int i = 0; i < 4; i++)
#pragma unroll
        for (int j = 0; j < 4; j++)
          acc[i][j] = fmaf(af[i], bfv[j], acc[i][j]);
    }
    __syncthreads();
  }
#pragma unroll
  for (int i = 0; i < 4; i++) {
    int m = row0 + ty * 4 + i;
#pragma unroll
    for (int j = 0; j < 4; j++) {
      int n = col0 + tx * 4 + j;
      if (n >= N) continue;
      size_t off = (size_t)m * N + n;
      float v = acc[i][j];
      if constexpr (EPI == 1) {
        Cout[off] = tanhf(v);
      } else if constexpr (EPI == 2) {
        float z = bias[n] + v;
        float sp = fmaxf(-z, 0.f) + log1pf(expf(-fabsf(z)));
        float w = -sp - 0.5f;
        Cout[off] = expf(-expf(w));
      }
    }
  }
}

// ---------------- prep: kk norm, a_in=-kk, b_in=kk*a, k gating ----------------
__global__ __launch_bounds__(896)
void prep_kernel(const float* __restrict__ k_in, const float* __restrict__ a,
                 const float* __restrict__ k_k, const float* __restrict__ k_a,
                 float* __restrict__ kout, float* __restrict__ ain, float* __restrict__ bin)
{
  int m = blockIdx.x;
  int c = threadIdx.x;
  size_t off = (size_t)m * CC + c;
  float kv = k_in[off];
  float av = a[off];
  float kkv = kv * k_k[c];
  float ss = waveRedSum(kkv * kkv);
  float norm = sqrtf(ss);
  float kkn = kkv / fmaxf(norm, 1e-12f);
  ain[off] = -kkn;
  bin[off] = kkn * av;
  kout[off] = kv * (1.f + (av - 1.f) * k_a[c]);
}

// ---------------- RWKV7 scan: 4 waves per (b,h); wave w owns state cols 16w..16w+15 ----------------
// lane = row i. One LDS barrier per step; stage/sa_part/y_part double-buffered by parity.
__global__ __launch_bounds__(256)
void scan4_kernel(const float* __restrict__ rp, const float* __restrict__ dp,
                  const float* __restrict__ kp, const float* __restrict__ vp,
                  const float* __restrict__ ap, const float* __restrict__ bp,
                  float* __restrict__ yp)
{
  int bh = blockIdx.x;
  int b = bh / HH, h = bh - b * HH;
  int tid = threadIdx.x;
  int lane = tid & 63;
  int w = tid >> 6;
  int w16 = w * 16;
  __shared__ __align__(16) float stg[2][5][64];   // slots: 0 r, 1 d, 2 k, 3 a, 4 b
  __shared__ float sa_part[2][4][64];
  __shared__ float y_part[2][4][64];

  float s[16];
#pragma unroll
  for (int c = 0; c < 16; c++) s[c] = 0.f;

  size_t base = ((size_t)b * TT) * CC + (size_t)h * NN + lane;

  const float* gA = (w == 0) ? rp : (w == 1) ? dp : (w == 2) ? kp : ap;
  int slotA = w;

  // prologue: t0 -> slot0 regs, t1 -> slot1 regs; stage t0; load t2 -> slot0
  float rA0 = gA[base];
  float rB0 = (w == 0) ? bp[base] : 0.f;
  float pv0 = vp[base];
  float rA1 = gA[base + CC];
  float rB1 = (w == 0) ? bp[base + CC] : 0.f;
  float pv1 = vp[base + CC];
  stg[0][slotA][lane] = rA0;
  if (w == 0) stg[0][4][lane] = rB0;
  rA0 = gA[base + 2 * (size_t)CC];
  if (w == 0) rB0 = bp[base + 2 * (size_t)CC];
  block_sync_lds();

#define SCAN_STEP(t, P, Q) do {                                                  \
    const float4 aa0 = *(const float4*)&stg[P][3][w16 + 0];                      \
    const float4 aa1 = *(const float4*)&stg[P][3][w16 + 4];                      \
    const float4 aa2 = *(const float4*)&stg[P][3][w16 + 8];                      \
    const float4 aa3 = *(const float4*)&stg[P][3][w16 + 12];                     \
    const float4 dd0 = *(const float4*)&stg[P][1][w16 + 0];                      \
    const float4 dd1 = *(const float4*)&stg[P][1][w16 + 4];                      \
    const float4 dd2 = *(const float4*)&stg[P][1][w16 + 8];                      \
    const float4 dd3 = *(const float4*)&stg[P][1][w16 + 12];                     \
    const float4 kk0 = *(const float4*)&stg[P][2][w16 + 0];                      \
    const float4 kk1 = *(const float4*)&stg[P][2][w16 + 4];                      \
    const float4 kk2 = *(const float4*)&stg[P][2][w16 + 8];                      \
    const float4 kk3 = *(const float4*)&stg[P][2][w16 + 12];                     \
    const float4 bb0 = *(const float4*)&stg[P][4][w16 + 0];                      \
    const float4 bb1 = *(const float4*)&stg[P][4][w16 + 4];                      \
    const float4 bb2 = *(const float4*)&stg[P][4][w16 + 8];                      \
    const float4 bb3 = *(const float4*)&stg[P][4][w16 + 12];                     \
    const float4 rr0 = *(const float4*)&stg[P][0][w16 + 0];                      \
    const float4 rr1 = *(const float4*)&stg[P][0][w16 + 4];                      \
    const float4 rr2 = *(const float4*)&stg[P][0][w16 + 8];                      \
    const float4 rr3 = *(const float4*)&stg[P][0][w16 + 12];                     \
    float p0 = s[0] * aa0.x;  p0 = fmaf(s[1], aa0.y, p0);                        \
    p0 = fmaf(s[2], aa0.z, p0); p0 = fmaf(s[3], aa0.w, p0);                      \
    p0 = fmaf(s[4], aa1.x, p0); p0 = fmaf(s[5], aa1.y, p0);                      \
    p0 = fmaf(s[6], aa1.z, p0); p0 = fmaf(s[7], aa1.w, p0);                      \
    float p1 = s[8] * aa2.x;  p1 = fmaf(s[9], aa2.y, p1);                        \
    p1 = fmaf(s[10], aa2.z, p1); p1 = fmaf(s[11], aa2.w, p1);                    \
    p1 = fmaf(s[12], aa3.x, p1); p1 = fmaf(s[13], aa3.y, p1);                    \
    p1 = fmaf(s[14], aa3.z, p1); p1 = fmaf(s[15], aa3.w, p1);                    \
    sa_part[P][w][lane] = p0 + p1;                                               \
    if ((t) + 1 < TT) {                                                          \
      stg[Q][slotA][lane] = rA##Q;                                               \
      if (w == 0) stg[Q][4][lane] = rB##Q;                                       \
    }                                                                            \
    if ((t) + 3 < TT) {                                                          \
      rA##Q = gA[base + (size_t)((t) + 3) * CC];                                 \
      if (w == 0) rB##Q = bp[base + (size_t)((t) + 3) * CC];                     \
    }                                                                            \
    float vi = pv##P;                                                            \
    if ((t) + 2 < TT) pv##P = vp[base + (size_t)((t) + 2) * CC];                 \
    block_sync_lds();                                                            \
    if (w == 0 && (t) > 0) {                                                     \
      float yo = y_part[Q][0][lane] + y_part[Q][1][lane]                         \
               + y_part[Q][2][lane] + y_part[Q][3][lane];                        \
      yp[base + (size_t)((t) - 1) * CC] = yo;                                    \
    }                                                                            \
    float sa = (sa_part[P][0][lane] + sa_part[P][1][lane])                       \
             + (sa_part[P][2][lane] + sa_part[P][3][lane]);                      \
    float y0 = 0.f, y1 = 0.f;                                                    \
    s[0]  = fmaf(s[0],  dd0.x, fmaf(sa, bb0.x, vi * kk0.x)); y0 = fmaf(s[0],  rr0.x, y0); \
    s[1]  = fmaf(s[1],  dd0.y, fmaf(sa, bb0.y, vi * kk0.y)); y1 = fmaf(s[1],  rr0.y, y1); \
    s[2]  = fmaf(s[2],  dd0.z, fmaf(sa, bb0.z, vi * kk0.z)); y0 = fmaf(s[2],  rr0.z, y0); \
    s[3]  = fmaf(s[3],  dd0.w, fmaf(sa, bb0.w, vi * kk0.w)); y1 = fmaf(s[3],  rr0.w, y1); \
    s[4]  = fmaf(s[4],  dd1.x, fmaf(sa, bb1.x, vi * kk1.x)); y0 = fmaf(s[4],  rr1.x, y0); \
    s[5]  = fmaf(s[5],  dd1.y, fmaf(sa, bb1.y, vi * kk1.y)); y1 = fmaf(s[5],  rr1.y, y1); \
    s[6]  = fmaf(s[6],  dd1.z, fmaf(sa, bb1.z, vi * kk1.z)); y0 = fmaf(s[6],  rr1.z, y0); \
    s[7]  = fmaf(s[7],  dd1.w, fmaf(sa, bb1.w, vi * kk1.w)); y1 = fmaf(s[7],  rr1.w, y1); \
    s[8]  = fmaf(s[8],  dd2.x, fmaf(sa, bb2.x, vi * kk2.x)); y0 = fmaf(s[8],  rr2.x, y0); \
    s[9]  = fmaf(s[9],  dd2.y, fmaf(sa, bb2.y, vi * kk2.y)); y1 = fmaf(s[9],  rr2.y, y1); \
    s[10] = fmaf(s[10], dd2.z, fmaf(sa, bb2.z, vi * kk2.z)); y0 = fmaf(s[10], rr2.z, y0); \
    s[11] = fmaf(s[11], dd2.w, fmaf(sa, bb2.w, vi * kk2.w)); y1 = fmaf(s[11], rr2.w, y1); \
    s[12] = fmaf(s[12], dd3.x, fmaf(sa, bb3.x, vi * kk3.x)); y0 = fmaf(s[12], rr3.x, y0); \
    s[13] = fmaf(s[13], dd3.y, fmaf(sa, bb3.y, vi * kk3.y)); y1 = fmaf(s[13], rr3.y, y1); \
    s[14] = fmaf(s[14], dd3.z, fmaf(sa, bb3.z, vi * kk3.z)); y0 = fmaf(s[14], rr3.z, y0); \
    s[15] = fmaf(s[15], dd3.w, fmaf(sa, bb3.w, vi * kk3.w)); y1 = fmaf(s[15], rr3.w, y1); \
    y_part[P][w][lane] = y0 + y1;                                                \
  } while (0)

  for (int t = 0; t < TT; t += 2) {
    SCAN_STEP(t, 0, 1);
    SCAN_STEP(t + 1, 1, 0);
  }
#undef SCAN_STEP

  block_sync_lds();
  if (w == 0) {
    float yo = (y_part[1][0][lane] + y_part[1][1][lane])
             + (y_part[1][2][lane] + y_part[1][3][lane]);
    yp[base + (size_t)(TT - 1) * CC] = yo;
  }
}

// ---------------- groupnorm + rk*v + *g -> bf16 ----------------
__global__ __launch_bounds__(896)
void gn_kernel(const float* __restrict__ y_in, const float* __restrict__ r,
               const float* __restrict__ k, const float* __restrict__ v,
               const float* __restrict__ g, const float* __restrict__ lnx_w,
               const float* __restrict__ lnx_b, const float* __restrict__ r_k,
               __hip_bfloat16* __restrict__ yout_bf)
{
  int m = blockIdx.x;
  int c = threadIdx.x;
  size_t off = (size_t)m * CC + c;
  float yv = y_in[off];
  float s1 = waveRedSum(yv);
  float s2 = waveRedSum(yv * yv);
  float mean = s1 * (1.f / 64.f);
  float var  = s2 * (1.f / 64.f) - mean * mean;
  float norm = (yv - mean) * rsqrtf(var + 0.00064f);
  float rv = r[off], kv = k[off], vv = v[off];
  float rk = waveRedSum(rv * kv * r_k[c]);
  yout_bf[off] = __float2bfloat16((norm * lnx_w[c] + lnx_b[c] + rk * vv) * g[off]);
}

// ---------------- host ----------------
extern "C" void kernel_launch(void* const* d_in, const int* in_sizes, int n_in,
                              void* d_out, int out_size, void* d_ws, size_t ws_size,
                              hipStream_t stream)
{
  const int*   idx    = (const int*)d_in[0];
  const float* emb    = (const float*)d_in[1];
  const float* ln0_w  = (const float*)d_in[2];
  const float* ln0_b  = (const float*)d_in[3];
  const float* ln1_w  = (const float*)d_in[4];
  const float* ln1_b  = (const float*)d_in[5];
  const float* ln2_w  = (const float*)d_in[6];
  const float* ln2_b  = (const float*)d_in[7];
  const float* x_r    = (const float*)d_in[8];
  const float* x_w    = (const float*)d_in[9];
  const float* x_k    = (const float*)d_in[10];
  const float* x_v    = (const float*)d_in[11];
  const float* x_a    = (const float*)d_in[12];
  const float* x_g    = (const float*)d_in[13];
  const float* w0     = (const float*)d_in[14];
  const float* w1     = (const float*)d_in[15];
  const float* w2     = (const float*)d_in[16];
  const float* a0     = (const float*)d_in[17];
  const float* a1     = (const float*)d_in[18];
  const float* a2     = (const float*)d_in[19];
  const float* v0     = (const float*)d_in[20];
  const float* v1     = (const float*)d_in[21];
  const float* v2     = (const float*)d_in[22];
  const float* g1     = (const float*)d_in[23];
  const float* g2     = (const float*)d_in[24];
  const float* k_k    = (const float*)d_in[25];
  const float* k_a    = (const float*)d_in[26];
  const float* r_k    = (const float*)d_in[27];
  const float* Wr     = (const float*)d_in[28];
  const float* Wk     = (const float*)d_in[29];
  const float* Wv     = (const float*)d_in[30];
  const float* Wo     = (const float*)d_in[31];
  const float* lnx_w  = (const float*)d_in[32];
  const float* lnx_b  = (const float*)d_in[33];
  const float* f_xk   = (const float*)d_in[34];
  const float* f_key  = (const float*)d_in[35];
  const float* f_val  = (const float*)d_in[36];
  const float* lnout_w = (const float*)d_in[37];
  const float* lnout_b = (const float*)d_in[38];
  const float* head_w  = (const float*)d_in[39];
  float* out = (float*)d_out;

  const size_t MC = (size_t)MM * CC;
  const size_t W2 = (size_t)CC * CC;
  float* ws   = (float*)d_ws;
  float* x    = ws;
  float* xn   = x + MC;
  float* mixb = xn + MC;
  float* vfirst = mixb + MC;
  float* rb   = vfirst + MC;
  float* dcy  = rb + MC;
  float* kb   = dcy + MC;
  float* vb   = kb + MC;
  float* ab   = vb + MC;
  float* gb   = ab + MC;
  float* ainb = gb + MC;
  float* binb = ainb + MC;
  float* yb   = binb + MC;
  float* t64  = yb + MC;                      // f32, w path
  float* fend = t64 + (size_t)MM * DD;

  __hip_bfloat16* mixb_bf = (__hip_bfloat16*)fend;
  __hip_bfloat16* WrT = mixb_bf + MC;
  __hip_bfloat16* WkT = WrT + W2;
  __hip_bfloat16* WvT = WkT + W2;
  __hip_bfloat16* WoT = WvT + W2;
  __hip_bfloat16* fkT = WoT + W2;                    // [3584][896]
  __hip_bfloat16* fvT = fkT + (size_t)FF4 * CC;      // [896][3584]
  __hip_bfloat16* a1T = fvT + (size_t)FF4 * CC;      // [64][896]
  __hip_bfloat16* a2T = a1T + (size_t)64 * CC;       // [896][64]
  __hip_bfloat16* v1T = a2T + (size_t)64 * CC;
  __hip_bfloat16* v2T = v1T + (size_t)64 * CC;
  __hip_bfloat16* g1T = v2T + (size_t)64 * CC;       // [192][896]
  __hip_bfloat16* g2T = g1T + (size_t)192 * CC;      // [896][192]
  __hip_bfloat16* t64bf  = g2T + (size_t)192 * CC;   // [2048][64]
  __hip_bfloat16* t160bf = t64bf + (size_t)MM * 64;  // [2048][192]
  // aliases (dead fp32 buffers reused)
  __hip_bfloat16* h_bf  = (__hip_bfloat16*)rb;       // [2048][3584] spans rb+dcy
  __hip_bfloat16* yg_bf = (__hip_bfloat16*)ab;       // [2048][896]

  dim3 blk(256);
  const int MIX_GRID = (int)(MC / 256);

  ln_kernel<<<MM, blk, 0, stream>>>(emb, idx, ln0_w, ln0_b, x);

  for (int l = 0; l < 2; l++) {
    const float* Wr_l = Wr + (size_t)l * W2;
    const float* Wk_l = Wk + (size_t)l * W2;
    const float* Wv_l = Wv + (size_t)l * W2;
    const float* Wo_l = Wo + (size_t)l * W2;
    const float* w1_l = w1 + (size_t)l * CC * DD;
    const float* w2_l = w2 + (size_t)l * DD * CC;
    const float* a1_l = a1 + (size_t)l * CC * DD;
    const float* a2_l = a2 + (size_t)l * DD * CC;
    const float* v1_l = v1 + (size_t)l * CC * DD;
    const float* v2_l = v2 + (size_t)l * DD * CC;
    const float* g1_l = g1 + (size_t)l * CC * DGG;
    const float* g2_l = g2 + (size_t)l * DGG * CC;
    const float* fk_l = f_key + (size_t)l * CC * FF4;
    const float* fv_l = f_val + (size_t)l * FF4 * CC;

    convT_kernel<<<dim3(28, 28), blk, 0, stream>>>(Wr_l, WrT, CC, CC, CC, CC);
    convT_kernel<<<dim3(28, 28), blk, 0, stream>>>(Wk_l, WkT, CC, CC, CC, CC);
    convT_kernel<<<dim3(28, 28), blk, 0, stream>>>(Wv_l, WvT, CC, CC, CC, CC);
    convT_kernel<<<dim3(28, 28), blk, 0, stream>>>(Wo_l, WoT, CC, CC, CC, CC);
    convT_kernel<<<dim3(112, 28), blk, 0, stream>>>(fk_l, fkT, CC, FF4, CC, FF4);
    convT_kernel<<<dim3(28, 112), blk, 0, stream>>>(fv_l, fvT, FF4, CC, FF4, CC);
    convT_kernel<<<dim3(2, 28), blk, 0, stream>>>(a1_l, a1T, CC, DD, CC, DD);
    convT_kernel<<<dim3(28, 2), blk, 0, stream>>>(a2_l, a2T, DD, CC, DD, CC);
    if (l == 1) {
      convT_kernel<<<dim3(2, 28), blk, 0, stream>>>(v1_l, v1T, CC, DD, CC, DD);
      convT_kernel<<<dim3(28, 2), blk, 0, stream>>>(v2_l, v2T, DD, CC, DD, CC);
    }
    convT_kernel<<<dim3(6, 28), blk, 0, stream>>>(g1_l, g1T, CC, DGG, CC, 192);
    convT_kernel<<<dim3(28, 6), blk, 0, stream>>>(g2_l, g2T, DGG, CC, 192, CC);

    ln_kernel<<<MM, blk, 0, stream>>>(x, nullptr, ln1_w + l * CC, ln1_b + l * CC, xn);

    dim3 gBig(CC / 128, MM / 128);     // (7,16)
    dim3 gF(FF4 / 128, MM / 128);      // (28,16)
    dim3 g64f(1, MM / 64);
    dim3 gCCs(CC / 64, MM / 64);
    dim3 gN64(1, MM / 128);            // (1,16)
    dim3 gN192(3, MM / 128);           // (3,16)

    // r
    mix_kernel<1><<<MIX_GRID, blk, 0, stream>>>(xn, x_r + l * CC, nullptr, mixb_bf);
    gemm_bf16<0,128><<<gBig, blk, 0, stream>>>(mixb_bf, WrT, rb, nullptr, CC, CC, nullptr, nullptr, nullptr, CC);
    // w (fp32 path)
    mix_kernel<0><<<MIX_GRID, blk, 0, stream>>>(xn, x_w + l * CC, mixb, nullptr);
    gemm_kernel<1><<<g64f, blk, 0, stream>>>(mixb, w1_l, t64, MM, DD, CC, nullptr);
    gemm_kernel<2><<<gCCs, blk, 0, stream>>>(t64, w2_l, dcy, MM, CC, DD, w0 + l * CC);
    // k
    mix_kernel<1><<<MIX_GRID, blk, 0, stream>>>(xn, x_k + l * CC, nullptr, mixb_bf);
    gemm_bf16<0,128><<<gBig, blk, 0, stream>>>(mixb_bf, WkT, kb, nullptr, CC, CC, nullptr, nullptr, nullptr, CC);
    // v
    mix_kernel<1><<<MIX_GRID, blk, 0, stream>>>(xn, x_v + l * CC, nullptr, mixb_bf);
    gemm_bf16<0,128><<<gBig, blk, 0, stream>>>(mixb_bf, WvT, vb, nullptr, CC, CC, nullptr, nullptr, nullptr, CC);
    if (l == 0) {
      hipMemcpyAsync(vfirst, vb, MC * sizeof(float), hipMemcpyDeviceToDevice, stream);
    } else {
      gemm_bf16<3,64><<<gN64, blk, 0, stream>>>(mixb_bf, v1T, nullptr, t64bf, DD, CC, nullptr, nullptr, nullptr, DD);
      gemm_bf16<6,128><<<gBig, blk, 0, stream>>>(t64bf, v2T, vb, nullptr, CC, DD, v0 + l * CC, vb, vfirst, CC);
    }
    // a
    mix_kernel<1><<<MIX_GRID, blk, 0, stream>>>(xn, x_a + l * CC, nullptr, mixb_bf);
    gemm_bf16<3,64><<<gN64, blk, 0, stream>>>(mixb_bf, a1T, nullptr, t64bf, DD, CC, nullptr, nullptr, nullptr, DD);
    gemm_bf16<5,128><<<gBig, blk, 0, stream>>>(t64bf, a2T, ab, nullptr, CC, DD, a0 + l * CC, nullptr, nullptr, CC);
    // g
    mix_kernel<1><<<MIX_GRID, blk, 0, stream>>>(xn, x_g + l * CC, nullptr, mixb_bf);
    gemm_bf16<4,64><<<gN192, blk, 0, stream>>>(mixb_bf, g1T, nullptr, t160bf, 192, CC, nullptr, nullptr, nullptr, DGG);
    gemm_bf16<0,128><<<gBig, blk, 0, stream>>>(t160bf, g2T, gb, nullptr, CC, 192, nullptr, nullptr, nullptr, CC);
    // prep + scan + gn
    prep_kernel<<<MM, dim3(896), 0, stream>>>(kb, ab, k_k + l * CC, k_a + l * CC, kb, ainb, binb);
    scan4_kernel<<<BB * HH, blk, 0, stream>>>(rb, dcy, kb, vb, ainb, binb, yb);
    gn_kernel<<<MM, dim3(896), 0, stream>>>(yb, rb, kb, vb, gb, lnx_w + l * CC, lnx_b + l * CC,
                                            r_k + (size_t)l * CC, yg_bf);
    // x += (y*g) @ Wo
    gemm_bf16<1,128><<<gBig, blk, 0, stream>>>(yg_bf, WoT, x, nullptr, CC, CC, nullptr, nullptr, nullptr, CC);

    // ---- channel mix ----
    ln_kernel<<<MM, blk, 0, stream>>>(x, nullptr, ln2_w + l * CC, ln2_b + l * CC, xn);
    mix_kernel<1><<<MIX_GRID, blk, 0, stream>>>(xn, f_xk + l * CC, nullptr, mixb_bf);
    gemm_bf16<2,128><<<gF, blk, 0, stream>>>(mixb_bf, fkT, nullptr, h_bf, FF4, CC, nullptr, nullptr, nullptr, FF4);
    gemm_bf16<1,128><<<gBig, blk, 0, stream>>>(h_bf, fvT, x, nullptr, CC, FF4, nullptr, nullptr, nullptr, CC);
  }

  head_kernel<<<MM, blk, 0, stream>>>(x, lnout_w, lnout_b, head_w, out);
}

// Round 4
// 1280.459 us; speedup vs baseline: 3.9918x; 1.1631x over previous
//
#include <hip/hip_runtime.h>
#include <hip/hip_bf16.h>
#include <math.h>

#define CC 896
#define TT 512
#define BB 4
#define HH 14
#define NN 64
#define DD 64
#define DGG 160
#define FF4 3584
#define MM (BB*TT)   // 2048
#define RD 8         // scan ring depth

typedef __attribute__((ext_vector_type(8))) short bf16x8;
typedef __attribute__((ext_vector_type(4))) float f32x4;

__device__ __forceinline__ float waveRedSum(float x) {
#pragma unroll
  for (int off = 32; off > 0; off >>= 1) x += __shfl_xor(x, off, 64);
  return x;
}

__device__ __forceinline__ float sigmoidf_(float x) { return 1.f / (1.f + expf(-x)); }

__device__ __forceinline__ void gload_lds16(const void* g, void* l) {
  __builtin_amdgcn_global_load_lds((const __attribute__((address_space(1))) void*)g,
                                   (__attribute__((address_space(3))) void*)l, 16, 0, 0);
}
__device__ __forceinline__ void gload_lds4(const void* g, void* l) {
  __builtin_amdgcn_global_load_lds((const __attribute__((address_space(1))) void*)g,
                                   (__attribute__((address_space(3))) void*)l, 4, 0, 0);
}

// ---------------- LayerNorm (optionally gathering via idx) ----------------
__global__ __launch_bounds__(256)
void ln_kernel(const float* __restrict__ in, const int* __restrict__ idx,
               const float* __restrict__ w, const float* __restrict__ bvec,
               float* __restrict__ out)
{
  int m = blockIdx.x;
  const float* row = idx ? (in + (size_t)idx[m] * CC) : (in + (size_t)m * CC);
  float s = 0.f, s2 = 0.f;
  for (int c = threadIdx.x; c < CC; c += 256) { float x = row[c]; s += x; s2 += x * x; }
  __shared__ float red[2][4];
  float a = waveRedSum(s), b2 = waveRedSum(s2);
  int wid = threadIdx.x >> 6;
  if ((threadIdx.x & 63) == 0) { red[0][wid] = a; red[1][wid] = b2; }
  __syncthreads();
  s  = red[0][0] + red[0][1] + red[0][2] + red[0][3];
  s2 = red[1][0] + red[1][1] + red[1][2] + red[1][3];
  float mean = s * (1.f / CC);
  float var  = s2 * (1.f / CC) - mean * mean;
  float inv  = rsqrtf(var + 1e-5f);
  float* orow = out + (size_t)m * CC;
  for (int c = threadIdx.x; c < CC; c += 256)
    orow[c] = (row[c] - mean) * inv * w[c] + bvec[c];
}

// ---------------- final LN + head ----------------
__global__ __launch_bounds__(256)
void head_kernel(const float* __restrict__ x, const float* __restrict__ w,
                 const float* __restrict__ bvec, const float* __restrict__ hw,
                 float* __restrict__ out)
{
  int m = blockIdx.x;
  const float* row = x + (size_t)m * CC;
  float s = 0.f, s2 = 0.f;
  for (int c = threadIdx.x; c < CC; c += 256) { float v = row[c]; s += v; s2 += v * v; }
  __shared__ float red[2][4];
  float a = waveRedSum(s), b2 = waveRedSum(s2);
  int wid = threadIdx.x >> 6;
  if ((threadIdx.x & 63) == 0) { red[0][wid] = a; red[1][wid] = b2; }
  __syncthreads();
  s  = red[0][0] + red[0][1] + red[0][2] + red[0][3];
  s2 = red[1][0] + red[1][1] + red[1][2] + red[1][3];
  float mean = s * (1.f / CC);
  float var  = s2 * (1.f / CC) - mean * mean;
  float inv  = rsqrtf(var + 1e-5f);
  float p = 0.f;
  for (int c = threadIdx.x; c < CC; c += 256)
    p += ((row[c] - mean) * inv * w[c] + bvec[c]) * hw[c];
  p = waveRedSum(p);
  __shared__ float red2[4];
  if ((threadIdx.x & 63) == 0) red2[wid] = p;
  __syncthreads();
  if (threadIdx.x == 0) out[m] = red2[0] + red2[1] + red2[2] + red2[3];
}

// ---------------- fused 6-way token-shift mix ----------------
__global__ __launch_bounds__(256)
void mix6_kernel(const float* __restrict__ xn,
                 const float* __restrict__ cr, const float* __restrict__ cw,
                 const float* __restrict__ ck, const float* __restrict__ cv,
                 const float* __restrict__ ca, const float* __restrict__ cg,
                 __hip_bfloat16* __restrict__ outr, float* __restrict__ outw,
                 __hip_bfloat16* __restrict__ outk, __hip_bfloat16* __restrict__ outv,
                 __hip_bfloat16* __restrict__ outa, __hip_bfloat16* __restrict__ outg)
{
  size_t i = (size_t)blockIdx.x * 256 + threadIdx.x;
  int c = (int)(i % CC);
  size_t m = i / CC;
  int t = (int)(m % TT);
  float cur  = xn[i];
  float prev = (t > 0) ? xn[i - CC] : 0.f;
  float d = prev - cur;
  outr[i] = __float2bfloat16(fmaf(d, cr[c], cur));
  outw[i] = fmaf(d, cw[c], cur);
  outk[i] = __float2bfloat16(fmaf(d, ck[c], cur));
  outv[i] = __float2bfloat16(fmaf(d, cv[c], cur));
  outa[i] = __float2bfloat16(fmaf(d, ca[c], cur));
  outg[i] = __float2bfloat16(fmaf(d, cg[c], cur));
}

// ---------------- single mix (channel-mix path), bf16 out ----------------
__global__ __launch_bounds__(256)
void mix_kernel(const float* __restrict__ xn, const float* __restrict__ coef,
                __hip_bfloat16* __restrict__ outb)
{
  size_t i = (size_t)blockIdx.x * 256 + threadIdx.x;
  int c = (int)(i % CC);
  size_t m = i / CC;
  int t = (int)(m % TT);
  float cur  = xn[i];
  float prev = (t > 0) ? xn[i - CC] : 0.f;
  outb[i] = __float2bfloat16(fmaf(prev - cur, coef[c], cur));
}

// ---------------- convert + transpose body ----------------
__device__ __forceinline__ void convT_body(const float* __restrict__ W,
                                           __hip_bfloat16* __restrict__ Wt,
                                           int K, int N, int KP, int NP,
                                           int bx, int by)
{
  __shared__ float tile[32][33];
  int bn = bx * 32, bk = by * 32;
  int tx = threadIdx.x & 31, ty = threadIdx.x >> 5;
#pragma unroll
  for (int i = 0; i < 4; i++) {
    int k = bk + ty + i * 8, n = bn + tx;
    tile[ty + i * 8][tx] = (k < K && n < N) ? W[(size_t)k * N + n] : 0.f;
  }
  __syncthreads();
#pragma unroll
  for (int i = 0; i < 4; i++) {
    int n = bn + ty + i * 8, k = bk + tx;
    if (n < NP && k < KP)
      Wt[(size_t)n * KP + k] = __float2bfloat16(tile[tx][ty + i * 8]);
  }
}

__global__ __launch_bounds__(256)
void convT_kernel(const float* __restrict__ W, __hip_bfloat16* __restrict__ Wt,
                  int K, int N, int KP, int NP)
{
  convT_body(W, Wt, K, N, KP, NP, blockIdx.x, blockIdx.y);
}

// all small per-layer weights in one launch, grid (28,28,10)
__global__ __launch_bounds__(256)
void convT_batch(const float* Wr, const float* Wk, const float* Wv, const float* Wo,
                 const float* a1, const float* a2, const float* v1, const float* v2,
                 const float* g1, const float* g2,
                 __hip_bfloat16* WrT, __hip_bfloat16* WkT, __hip_bfloat16* WvT,
                 __hip_bfloat16* WoT, __hip_bfloat16* a1T, __hip_bfloat16* a2T,
                 __hip_bfloat16* v1T, __hip_bfloat16* v2T, __hip_bfloat16* g1T,
                 __hip_bfloat16* g2T)
{
  const float* W; __hip_bfloat16* Wt; int K, N, KP, NP;
  switch (blockIdx.z) {
    case 0: W = Wr; Wt = WrT; K = CC;  N = CC;  KP = CC;  NP = CC;  break;
    case 1: W = Wk; Wt = WkT; K = CC;  N = CC;  KP = CC;  NP = CC;  break;
    case 2: W = Wv; Wt = WvT; K = CC;  N = CC;  KP = CC;  NP = CC;  break;
    case 3: W = Wo; Wt = WoT; K = CC;  N = CC;  KP = CC;  NP = CC;  break;
    case 4: W = a1; Wt = a1T; K = CC;  N = DD;  KP = CC;  NP = DD;  break;
    case 5: W = a2; Wt = a2T; K = DD;  N = CC;  KP = DD;  NP = CC;  break;
    case 6: W = v1; Wt = v1T; K = CC;  N = DD;  KP = CC;  NP = DD;  break;
    case 7: W = v2; Wt = v2T; K = DD;  N = CC;  KP = DD;  NP = CC;  break;
    case 8: W = g1; Wt = g1T; K = CC;  N = DGG; KP = CC;  NP = 192; break;
    default: W = g2; Wt = g2T; K = DGG; N = CC; KP = 192; NP = CC;  break;
  }
  if ((int)blockIdx.x * 32 >= NP || (int)blockIdx.y * 32 >= KP) return;
  convT_body(W, Wt, K, N, KP, NP, blockIdx.x, blockIdx.y);
}

// ---------------- bf16 MFMA GEMM body: C[M][N] = A[M][K] * Bt[N][K]^T ----------------
// MEPI: 0 store f32, 1 add f32, 2 relu^2->bf16, 3 store bf16, 4 sigmoid->bf16 (pad0 past Nreal),
//       5 sigmoid(bias+v)->f32, 6 v-gate->f32
template<int MEPI, int BN>
__device__ __forceinline__ void gemm_body(const __hip_bfloat16* __restrict__ A,
    const __hip_bfloat16* __restrict__ Bt, float* __restrict__ C,
    __hip_bfloat16* __restrict__ Cbf, int N, int K, const float* __restrict__ bias,
    const float* __restrict__ aux0, const float* __restrict__ aux1, int Nreal,
    int bx, int by)
{
  constexpr int WN = BN / 64;
  constexpr int WM = 4 / WN;
  constexpr int ROWS = 128 / WM;
  constexpr int MI = ROWS / 16;
  __shared__ __align__(16) ushort As[128 * 64];
  __shared__ __align__(16) ushort Bs[BN * 64];
  int tid = threadIdx.x;
  int lane = tid & 63, wave = tid >> 6;
  int wm, wn;
  if constexpr (WN == 2) { wm = wave >> 1; wn = wave & 1; } else { wm = wave; wn = 0; }
  int fl = lane & 15, fh = lane >> 4;
  int row0 = by * 128, col0 = bx * BN;

  const char* Abase = (const char*)A + (size_t)row0 * (size_t)(K * 2);
  const char* Bbase = (const char*)Bt + (size_t)col0 * (size_t)(K * 2);
  char* AsB = (char*)As;
  char* BsB = (char*)Bs;

  f32x4 acc[MI][4];
#pragma unroll
  for (int mi = 0; mi < MI; mi++)
#pragma unroll
    for (int ni = 0; ni < 4; ni++)
      acc[mi][ni] = (f32x4){0.f, 0.f, 0.f, 0.f};

  int srow = tid >> 3;
  int scol = (tid & 7) << 4;
  int ldsw = (wave << 10);

  for (int k0 = 0; k0 < K; k0 += 64) {
#pragma unroll
    for (int it = 0; it < 4; ++it) {
      int r = it * 32 + srow;
      int cbs = scol ^ ((r & 7) << 4);
      size_t goff = (size_t)r * (size_t)(K * 2) + (size_t)(k0 * 2) + cbs;
      gload_lds16(Abase + goff, AsB + (it << 12) + ldsw);
      if constexpr (BN == 128) {
        gload_lds16(Bbase + goff, BsB + (it << 12) + ldsw);
      } else {
        if (it < 2) gload_lds16(Bbase + goff, BsB + (it << 12) + ldsw);
      }
    }
    __syncthreads();
#pragma unroll
    for (int kk = 0; kk < 2; ++kk) {
      bf16x8 af[MI], bfr[4];
      int kb_ = kk * 64 + (fh << 4);
#pragma unroll
      for (int mi = 0; mi < MI; mi++) {
        int r = wm * ROWS + mi * 16 + fl;
        af[mi] = *(const bf16x8*)(AsB + r * 128 + (kb_ ^ ((r & 7) << 4)));
      }
#pragma unroll
      for (int ni = 0; ni < 4; ni++) {
        int r = wn * 64 + ni * 16 + fl;
        bfr[ni] = *(const bf16x8*)(BsB + r * 128 + (kb_ ^ ((r & 7) << 4)));
      }
#pragma unroll
      for (int mi = 0; mi < MI; mi++)
#pragma unroll
        for (int ni = 0; ni < 4; ni++)
          acc[mi][ni] = __builtin_amdgcn_mfma_f32_16x16x32_bf16(af[mi], bfr[ni], acc[mi][ni], 0, 0, 0);
    }
    __syncthreads();
  }

#pragma unroll
  for (int mi = 0; mi < MI; mi++) {
    int crow0 = row0 + wm * ROWS + mi * 16 + fh * 4;
#pragma unroll
    for (int ni = 0; ni < 4; ni++) {
      int ccol = col0 + wn * 64 + ni * 16 + fl;
#pragma unroll
      for (int e = 0; e < 4; e++) {
        size_t off = (size_t)(crow0 + e) * N + ccol;
        float v = acc[mi][ni][e];
        if constexpr (MEPI == 0) {
          C[off] = v;
        } else if constexpr (MEPI == 1) {
          C[off] += v;
        } else if constexpr (MEPI == 2) {
          float t = fmaxf(v, 0.f);
          Cbf[off] = __float2bfloat16(t * t);
        } else if constexpr (MEPI == 3) {
          Cbf[off] = __float2bfloat16(v);
        } else if constexpr (MEPI == 4) {
          float sv = (ccol < Nreal) ? sigmoidf_(v) : 0.f;
          Cbf[off] = __float2bfloat16(sv);
        } else if constexpr (MEPI == 5) {
          C[off] = sigmoidf_(bias[ccol] + v);
        } else if constexpr (MEPI == 6) {
          float sg = sigmoidf_(bias[ccol] + v);
          float vv = aux0[off];
          C[off] = vv + (aux1[off] - vv) * sg;
        }
      }
    }
  }
}

template<int MEPI, int BN>
__global__ __launch_bounds__(256)
void gemm_bf16(const __hip_bfloat16* __restrict__ A, const __hip_bfloat16* __restrict__ Bt,
               float* __restrict__ C, __hip_bfloat16* __restrict__ Cbf,
               int N, int K, const float* __restrict__ bias,
               const float* __restrict__ aux0, const float* __restrict__ aux1, int Nreal)
{
  gemm_body<MEPI, BN>(A, Bt, C, Cbf, N, K, bias, aux0, aux1, Nreal, blockIdx.x, blockIdx.y);
}

// batched r/k/v projection, grid (7,16,3)
__global__ __launch_bounds__(256)
void gemm_rkv(const __hip_bfloat16* Ar, const __hip_bfloat16* Ak, const __hip_bfloat16* Av,
              const __hip_bfloat16* Br, const __hip_bfloat16* Bk, const __hip_bfloat16* Bv,
              float* Cr, float* Ck, float* Cv)
{
  const __hip_bfloat16* A; const __hip_bfloat16* Bt; float* C;
  if (blockIdx.z == 0)      { A = Ar; Bt = Br; C = Cr; }
  else if (blockIdx.z == 1) { A = Ak; Bt = Bk; C = Ck; }
  else                      { A = Av; Bt = Bv; C = Cv; }
  gemm_body<0, 128>(A, Bt, C, nullptr, CC, CC, nullptr, nullptr, nullptr, CC,
                    blockIdx.x, blockIdx.y);
}

// ---------------- f32 GEMM (w path only). EPI: 1 tanh, 2 decay ----------------
template<int EPI>
__global__ __launch_bounds__(256)
void gemm_kernel(const float* __restrict__ A, const float* __restrict__ B,
                 float* __restrict__ Cout, int M, int N, int K,
                 const float* __restrict__ bias)
{
  __shared__ __align__(16) float As[16][68];
  __shared__ __align__(16) float Bs[16][68];
  int tid = threadIdx.x;
  int tx = tid & 15, ty = tid >> 4;
  int row0 = blockIdx.y * 64, col0 = blockIdx.x * 64;
  float acc[4][4] = {};
  int a_m = tid >> 2;
  int a_k = (tid & 3) * 4;
  int b_k = tid >> 4;
  int b_n = (tid & 15) * 4;
  for (int k0 = 0; k0 < K; k0 += 16) {
    float4 av = *(const float4*)(A + (size_t)(row0 + a_m) * K + k0 + a_k);
    As[a_k + 0][a_m] = av.x; As[a_k + 1][a_m] = av.y;
    As[a_k + 2][a_m] = av.z; As[a_k + 3][a_m] = av.w;
    float4 bv;
    if (col0 + b_n < N) bv = *(const float4*)(B + (size_t)(k0 + b_k) * N + col0 + b_n);
    else bv = make_float4(0.f, 0.f, 0.f, 0.f);
    *(float4*)&Bs[b_k][b_n] = bv;
    __syncthreads();
#pragma unroll
    for (int kk = 0; kk < 16; kk++) {
      float af[4], bfv[4];
#pragma unroll
      for (int i = 0; i < 4; i++) af[i] = As[kk][ty * 4 + i];
#pragma unroll
      for (int j = 0; j < 4; j++) bfv[j] = Bs[kk][tx * 4 + j];
#pragma unroll
      for (int i = 0; i < 4; i++)
#pragma unroll
        for (int j = 0; j < 4; j++)
          acc[i][j] = fmaf(af[i], bfv[j], acc[i][j]);
    }
    __syncthreads();
  }
#pragma unroll
  for (int i = 0; i < 4; i++) {
    int m = row0 + ty * 4 + i;
#pragma unroll
    for (int j = 0; j < 4; j++) {
      int n = col0 + tx * 4 + j;
      if (n >= N) continue;
      size_t off = (size_t)m * N + n;
      float v = acc[i][j];
      if constexpr (EPI == 1) {
        Cout[off] = tanhf(v);
      } else if constexpr (EPI == 2) {
        float z = bias[n] + v;
        float sp = fmaxf(-z, 0.f) + log1pf(expf(-fabsf(z)));
        float w = -sp - 0.5f;
        Cout[off] = expf(-expf(w));
      }
    }
  }
}

// ---------------- prep: kk norm, a_in=-kk, b_in=kk*a, k gating ----------------
__global__ __launch_bounds__(896)
void prep_kernel(const float* __restrict__ k_in, const float* __restrict__ a,
                 const float* __restrict__ k_k, const float* __restrict__ k_a,
                 float* __restrict__ kout, float* __restrict__ ain, float* __restrict__ bin)
{
  int m = blockIdx.x;
  int c = threadIdx.x;
  size_t off = (size_t)m * CC + c;
  float kv = k_in[off];
  float av = a[off];
  float kkv = kv * k_k[c];
  float ss = waveRedSum(kkv * kkv);
  float norm = sqrtf(ss);
  float kkn = kkv / fmaxf(norm, 1e-12f);
  ain[off] = -kkn;
  bin[off] = kkn * av;
  kout[off] = kv * (1.f + (av - 1.f) * k_a[c]);
}

// ---------------- RWKV7 scan: LDS ring + counted vmcnt; 4 waves per (b,h) ----------------
// wave w owns state cols 16w..16w+15, lane = row. Waves 1..3 load 2 streams each;
// wave 0 writes y (its vmcnt never counted). One barrier per step.
__global__ __launch_bounds__(256)
void scan5_kernel(const float* __restrict__ rp, const float* __restrict__ dp,
                  const float* __restrict__ kp, const float* __restrict__ vp,
                  const float* __restrict__ ap, const float* __restrict__ bp_,
                  float* __restrict__ yp)
{
  int bh = blockIdx.x;
  int b = bh / HH, h = bh - b * HH;
  int tid = threadIdx.x, lane = tid & 63, w = tid >> 6;
  int w16 = w * 16;
  __shared__ __align__(16) float ring[RD][6][64];   // 0 r, 1 d, 2 k, 3 a, 4 b, 5 v
  __shared__ float sa_part[2][4][64];
  __shared__ float y_part[2][4][64];

  float s[16];
#pragma unroll
  for (int c = 0; c < 16; c++) s[c] = 0.f;
  size_t base = ((size_t)b * TT) * CC + (size_t)h * NN + lane;

  const float* gA = nullptr; const float* gB = nullptr; int slA = 0, slB = 0;
  if (w == 1)      { gA = rp;  slA = 0; gB = dp;  slB = 1; }
  else if (w == 2) { gA = kp;  slA = 2; gB = vp;  slB = 5; }
  else if (w == 3) { gA = ap;  slA = 3; gB = bp_; slB = 4; }

  if (w) {
    for (int t0 = 0; t0 < RD; t0++) {
      gload_lds4(gA + base + (size_t)t0 * CC, &ring[t0][slA][0]);
      gload_lds4(gB + base + (size_t)t0 * CC, &ring[t0][slB][0]);
    }
    asm volatile("s_waitcnt vmcnt(0)" ::: "memory");
  }
  __builtin_amdgcn_s_barrier();
  __builtin_amdgcn_sched_barrier(0);

  for (int t = 0; t < TT; ++t) {
    int P = t & 1, Q = P ^ 1;
    int slot = t & (RD - 1);
    // 1. read this step's slices (broadcast within wave, conflict-free)
    const float4 aa0 = *(const float4*)&ring[slot][3][w16 + 0];
    const float4 aa1 = *(const float4*)&ring[slot][3][w16 + 4];
    const float4 aa2 = *(const float4*)&ring[slot][3][w16 + 8];
    const float4 aa3 = *(const float4*)&ring[slot][3][w16 + 12];
    const float4 dd0 = *(const float4*)&ring[slot][1][w16 + 0];
    const float4 dd1 = *(const float4*)&ring[slot][1][w16 + 4];
    const float4 dd2 = *(const float4*)&ring[slot][1][w16 + 8];
    const float4 dd3 = *(const float4*)&ring[slot][1][w16 + 12];
    const float4 kk0 = *(const float4*)&ring[slot][2][w16 + 0];
    const float4 kk1 = *(const float4*)&ring[slot][2][w16 + 4];
    const float4 kk2 = *(const float4*)&ring[slot][2][w16 + 8];
    const float4 kk3 = *(const float4*)&ring[slot][2][w16 + 12];
    const float4 bb0 = *(const float4*)&ring[slot][4][w16 + 0];
    const float4 bb1 = *(const float4*)&ring[slot][4][w16 + 4];
    const float4 bb2 = *(const float4*)&ring[slot][4][w16 + 8];
    const float4 bb3 = *(const float4*)&ring[slot][4][w16 + 12];
    const float4 rr0 = *(const float4*)&ring[slot][0][w16 + 0];
    const float4 rr1 = *(const float4*)&ring[slot][0][w16 + 4];
    const float4 rr2 = *(const float4*)&ring[slot][0][w16 + 8];
    const float4 rr3 = *(const float4*)&ring[slot][0][w16 + 12];
    float vi = ring[slot][5][lane];
    // 2. sa partial (2 parallel chains of 8)
    float p0 = s[0] * aa0.x;    p0 = fmaf(s[1], aa0.y, p0);
    p0 = fmaf(s[2], aa0.z, p0); p0 = fmaf(s[3], aa0.w, p0);
    p0 = fmaf(s[4], aa1.x, p0); p0 = fmaf(s[5], aa1.y, p0);
    p0 = fmaf(s[6], aa1.z, p0); p0 = fmaf(s[7], aa1.w, p0);
    float p1 = s[8] * aa2.x;      p1 = fmaf(s[9], aa2.y, p1);
    p1 = fmaf(s[10], aa2.z, p1);  p1 = fmaf(s[11], aa2.w, p1);
    p1 = fmaf(s[12], aa3.x, p1);  p1 = fmaf(s[13], aa3.y, p1);
    p1 = fmaf(s[14], aa3.z, p1);  p1 = fmaf(s[15], aa3.w, p1);
    sa_part[P][w][lane] = p0 + p1;
    // 3. counted vmcnt (loaders): pending = 7 batches x 2; oldest done at <=12
    if (w) { asm volatile("s_waitcnt vmcnt(12)" ::: "memory"); }
    asm volatile("s_waitcnt lgkmcnt(0)" ::: "memory");
    __builtin_amdgcn_s_barrier();
    __builtin_amdgcn_sched_barrier(0);
    // 4. refill freed slot for step t+RD
    if (w && t + RD < TT) {
      gload_lds4(gA + base + (size_t)(t + RD) * CC, &ring[slot][slA][0]);
      gload_lds4(gB + base + (size_t)(t + RD) * CC, &ring[slot][slB][0]);
    }
    // 5. y output of step t-1
    if (w == 0 && t > 0) {
      float yo = (y_part[Q][0][lane] + y_part[Q][1][lane])
               + (y_part[Q][2][lane] + y_part[Q][3][lane]);
      yp[base + (size_t)(t - 1) * CC] = yo;
    }
    // 6. gather sa, update state, y partial
    float sa = (sa_part[P][0][lane] + sa_part[P][1][lane])
             + (sa_part[P][2][lane] + sa_part[P][3][lane]);
    float y0 = 0.f, y1 = 0.f;
    s[0]  = fmaf(s[0],  dd0.x, fmaf(sa, bb0.x, vi * kk0.x)); y0 = fmaf(s[0],  rr0.x, y0);
    s[1]  = fmaf(s[1],  dd0.y, fmaf(sa, bb0.y, vi * kk0.y)); y1 = fmaf(s[1],  rr0.y, y1);
    s[2]  = fmaf(s[2],  dd0.z, fmaf(sa, bb0.z, vi * kk0.z)); y0 = fmaf(s[2],  rr0.z, y0);
    s[3]  = fmaf(s[3],  dd0.w, fmaf(sa, bb0.w, vi * kk0.w)); y1 = fmaf(s[3],  rr0.w, y1);
    s[4]  = fmaf(s[4],  dd1.x, fmaf(sa, bb1.x, vi * kk1.x)); y0 = fmaf(s[4],  rr1.x, y0);
    s[5]  = fmaf(s[5],  dd1.y, fmaf(sa, bb1.y, vi * kk1.y)); y1 = fmaf(s[5],  rr1.y, y1);
    s[6]  = fmaf(s[6],  dd1.z, fmaf(sa, bb1.z, vi * kk1.z)); y0 = fmaf(s[6],  rr1.z, y0);
    s[7]  = fmaf(s[7],  dd1.w, fmaf(sa, bb1.w, vi * kk1.w)); y1 = fmaf(s[7],  rr1.w, y1);
    s[8]  = fmaf(s[8],  dd2.x, fmaf(sa, bb2.x, vi * kk2.x)); y0 = fmaf(s[8],  rr2.x, y0);
    s[9]  = fmaf(s[9],  dd2.y, fmaf(sa, bb2.y, vi * kk2.y)); y1 = fmaf(s[9],  rr2.y, y1);
    s[10] = fmaf(s[10], dd2.z, fmaf(sa, bb2.z, vi * kk2.z)); y0 = fmaf(s[10], rr2.z, y0);
    s[11] = fmaf(s[11], dd2.w, fmaf(sa, bb2.w, vi * kk2.w)); y1 = fmaf(s[11], rr2.w, y1);
    s[12] = fmaf(s[12], dd3.x, fmaf(sa, bb3.x, vi * kk3.x)); y0 = fmaf(s[12], rr3.x, y0);
    s[13] = fmaf(s[13], dd3.y, fmaf(sa, bb3.y, vi * kk3.y)); y1 = fmaf(s[13], rr3.y, y1);
    s[14] = fmaf(s[14], dd3.z, fmaf(sa, bb3.z, vi * kk3.z)); y0 = fmaf(s[14], rr3.z, y0);
    s[15] = fmaf(s[15], dd3.w, fmaf(sa, bb3.w, vi * kk3.w)); y1 = fmaf(s[15], rr3.w, y1);
    y_part[P][w][lane] = y0 + y1;
  }

  asm volatile("s_waitcnt lgkmcnt(0)" ::: "memory");
  __builtin_amdgcn_s_barrier();
  if (w == 0) {
    int Pl = (TT - 1) & 1;
    float yo = (y_part[Pl][0][lane] + y_part[Pl][1][lane])
             + (y_part[Pl][2][lane] + y_part[Pl][3][lane]);
    yp[base + (size_t)(TT - 1) * CC] = yo;
  }
}

// ---------------- groupnorm + rk*v + *g -> bf16 ----------------
__global__ __launch_bounds__(896)
void gn_kernel(const float* __restrict__ y_in, const float* __restrict__ r,
               const float* __restrict__ k, const float* __restrict__ v,
               const float* __restrict__ g, const float* __restrict__ lnx_w,
               const float* __restrict__ lnx_b, const float* __restrict__ r_k,
               __hip_bfloat16* __restrict__ yout_bf)
{
  int m = blockIdx.x;
  int c = threadIdx.x;
  size_t off = (size_t)m * CC + c;
  float yv = y_in[off];
  float s1 = waveRedSum(yv);
  float s2 = waveRedSum(yv * yv);
  float mean = s1 * (1.f / 64.f);
  float var  = s2 * (1.f / 64.f) - mean * mean;
  float norm = (yv - mean) * rsqrtf(var + 0.00064f);
  float rv = r[off], kv = k[off], vv = v[off];
  float rk = waveRedSum(rv * kv * r_k[c]);
  yout_bf[off] = __float2bfloat16((norm * lnx_w[c] + lnx_b[c] + rk * vv) * g[off]);
}

// ---------------- host ----------------
extern "C" void kernel_launch(void* const* d_in, const int* in_sizes, int n_in,
                              void* d_out, int out_size, void* d_ws, size_t ws_size,
                              hipStream_t stream)
{
  const int*   idx    = (const int*)d_in[0];
  const float* emb    = (const float*)d_in[1];
  const float* ln0_w  = (const float*)d_in[2];
  const float* ln0_b  = (const float*)d_in[3];
  const float* ln1_w  = (const float*)d_in[4];
  const float* ln1_b  = (const float*)d_in[5];
  const float* ln2_w  = (const float*)d_in[6];
  const float* ln2_b  = (const float*)d_in[7];
  const float* x_r    = (const float*)d_in[8];
  const float* x_w    = (const float*)d_in[9];
  const float* x_k    = (const float*)d_in[10];
  const float* x_v    = (const float*)d_in[11];
  const float* x_a    = (const float*)d_in[12];
  const float* x_g    = (const float*)d_in[13];
  const float* w0     = (const float*)d_in[14];
  const float* w1     = (const float*)d_in[15];
  const float* w2     = (const float*)d_in[16];
  const float* a0     = (const float*)d_in[17];
  const float* a1     = (const float*)d_in[18];
  const float* a2     = (const float*)d_in[19];
  const float* v0     = (const float*)d_in[20];
  const float* v1     = (const float*)d_in[21];
  const float* v2     = (const float*)d_in[22];
  const float* g1     = (const float*)d_in[23];
  const float* g2     = (const float*)d_in[24];
  const float* k_k    = (const float*)d_in[25];
  const float* k_a    = (const float*)d_in[26];
  const float* r_k    = (const float*)d_in[27];
  const float* Wr     = (const float*)d_in[28];
  const float* Wk     = (const float*)d_in[29];
  const float* Wv     = (const float*)d_in[30];
  const float* Wo     = (const float*)d_in[31];
  const float* lnx_w  = (const float*)d_in[32];
  const float* lnx_b  = (const float*)d_in[33];
  const float* f_xk   = (const float*)d_in[34];
  const float* f_key  = (const float*)d_in[35];
  const float* f_val  = (const float*)d_in[36];
  const float* lnout_w = (const float*)d_in[37];
  const float* lnout_b = (const float*)d_in[38];
  const float* head_w  = (const float*)d_in[39];
  float* out = (float*)d_out;

  const size_t MC = (size_t)MM * CC;
  const size_t W2 = (size_t)CC * CC;
  float* ws   = (float*)d_ws;
  float* x    = ws;
  float* xn   = x + MC;
  float* mixw = xn + MC;
  float* vfirst = mixw + MC;
  float* rb   = vfirst + MC;
  float* dcy  = rb + MC;
  float* kb   = dcy + MC;
  float* vb   = kb + MC;
  float* ab   = vb + MC;
  float* gb   = ab + MC;
  float* ainb = gb + MC;
  float* binb = ainb + MC;
  float* yb   = binb + MC;
  float* t64  = yb + MC;
  float* fend = t64 + (size_t)MM * DD;

  __hip_bfloat16* mixr_bf = (__hip_bfloat16*)fend;
  __hip_bfloat16* mixk_bf = mixr_bf + MC;
  __hip_bfloat16* mixv_bf = mixk_bf + MC;
  __hip_bfloat16* mixa_bf = mixv_bf + MC;
  __hip_bfloat16* mixg_bf = mixa_bf + MC;
  __hip_bfloat16* WrT = mixg_bf + MC;
  __hip_bfloat16* WkT = WrT + W2;
  __hip_bfloat16* WvT = WkT + W2;
  __hip_bfloat16* WoT = WvT + W2;
  __hip_bfloat16* fkT = WoT + W2;                    // [3584][896]
  __hip_bfloat16* fvT = fkT + (size_t)FF4 * CC;      // [896][3584]
  __hip_bfloat16* a1T = fvT + (size_t)FF4 * CC;      // [64][896]
  __hip_bfloat16* a2T = a1T + (size_t)64 * CC;       // [896][64]
  __hip_bfloat16* v1T = a2T + (size_t)64 * CC;
  __hip_bfloat16* v2T = v1T + (size_t)64 * CC;
  __hip_bfloat16* g1T = v2T + (size_t)64 * CC;       // [192][896]
  __hip_bfloat16* g2T = g1T + (size_t)192 * CC;      // [896][192]
  __hip_bfloat16* t64bf  = g2T + (size_t)192 * CC;   // [2048][64]
  __hip_bfloat16* t160bf = t64bf + (size_t)MM * 64;  // [2048][192]
  // aliases (dead fp32 buffers reused)
  __hip_bfloat16* h_bf  = (__hip_bfloat16*)rb;       // [2048][3584] spans rb+dcy
  __hip_bfloat16* yg_bf = (__hip_bfloat16*)ab;       // [2048][896]

  dim3 blk(256);
  const int MIX_GRID = (int)(MC / 256);

  ln_kernel<<<MM, blk, 0, stream>>>(emb, idx, ln0_w, ln0_b, x);

  for (int l = 0; l < 2; l++) {
    const float* Wr_l = Wr + (size_t)l * W2;
    const float* Wk_l = Wk + (size_t)l * W2;
    const float* Wv_l = Wv + (size_t)l * W2;
    const float* Wo_l = Wo + (size_t)l * W2;
    const float* w1_l = w1 + (size_t)l * CC * DD;
    const float* w2_l = w2 + (size_t)l * DD * CC;
    const float* a1_l = a1 + (size_t)l * CC * DD;
    const float* a2_l = a2 + (size_t)l * DD * CC;
    const float* v1_l = v1 + (size_t)l * CC * DD;
    const float* v2_l = v2 + (size_t)l * DD * CC;
    const float* g1_l = g1 + (size_t)l * CC * DGG;
    const float* g2_l = g2 + (size_t)l * DGG * CC;
    const float* fk_l = f_key + (size_t)l * CC * FF4;
    const float* fv_l = f_val + (size_t)l * FF4 * CC;

    convT_batch<<<dim3(28, 28, 10), blk, 0, stream>>>(
        Wr_l, Wk_l, Wv_l, Wo_l, a1_l, a2_l, v1_l, v2_l, g1_l, g2_l,
        WrT, WkT, WvT, WoT, a1T, a2T, v1T, v2T, g1T, g2T);
    convT_kernel<<<dim3(112, 28), blk, 0, stream>>>(fk_l, fkT, CC, FF4, CC, FF4);
    convT_kernel<<<dim3(28, 112), blk, 0, stream>>>(fv_l, fvT, FF4, CC, FF4, CC);

    ln_kernel<<<MM, blk, 0, stream>>>(x, nullptr, ln1_w + l * CC, ln1_b + l * CC, xn);
    mix6_kernel<<<MIX_GRID, blk, 0, stream>>>(xn,
        x_r + l * CC, x_w + l * CC, x_k + l * CC, x_v + l * CC, x_a + l * CC, x_g + l * CC,
        mixr_bf, mixw, mixk_bf, mixv_bf, mixa_bf, mixg_bf);

    dim3 gBig(CC / 128, MM / 128);     // (7,16)
    dim3 gF(FF4 / 128, MM / 128);      // (28,16)
    dim3 g64f(1, MM / 64);
    dim3 gCCs(CC / 64, MM / 64);
    dim3 gN64(1, MM / 128);
    dim3 gN192(3, MM / 128);

    // r,k,v batched
    gemm_rkv<<<dim3(7, 16, 3), blk, 0, stream>>>(mixr_bf, mixk_bf, mixv_bf,
                                                 WrT, WkT, WvT, rb, kb, vb);
    // w (fp32 path)
    gemm_kernel<1><<<g64f, blk, 0, stream>>>(mixw, w1_l, t64, MM, DD, CC, nullptr);
    gemm_kernel<2><<<gCCs, blk, 0, stream>>>(t64, w2_l, dcy, MM, CC, DD, w0 + l * CC);
    // v gate
    if (l == 0) {
      hipMemcpyAsync(vfirst, vb, MC * sizeof(float), hipMemcpyDeviceToDevice, stream);
    } else {
      gemm_bf16<3, 64><<<gN64, blk, 0, stream>>>(mixv_bf, v1T, nullptr, t64bf, DD, CC, nullptr, nullptr, nullptr, DD);
      gemm_bf16<6, 128><<<gBig, blk, 0, stream>>>(t64bf, v2T, vb, nullptr, CC, DD, v0 + l * CC, vb, vfirst, CC);
    }
    // a
    gemm_bf16<3, 64><<<gN64, blk, 0, stream>>>(mixa_bf, a1T, nullptr, t64bf, DD, CC, nullptr, nullptr, nullptr, DD);
    gemm_bf16<5, 128><<<gBig, blk, 0, stream>>>(t64bf, a2T, ab, nullptr, CC, DD, a0 + l * CC, nullptr, nullptr, CC);
    // g
    gemm_bf16<4, 64><<<gN192, blk, 0, stream>>>(mixg_bf, g1T, nullptr, t160bf, 192, CC, nullptr, nullptr, nullptr, DGG);
    gemm_bf16<0, 128><<<gBig, blk, 0, stream>>>(t160bf, g2T, gb, nullptr, CC, 192, nullptr, nullptr, nullptr, CC);
    // prep + scan + gn
    prep_kernel<<<MM, dim3(896), 0, stream>>>(kb, ab, k_k + l * CC, k_a + l * CC, kb, ainb, binb);
    scan5_kernel<<<BB * HH, blk, 0, stream>>>(rb, dcy, kb, vb, ainb, binb, yb);
    gn_kernel<<<MM, dim3(896), 0, stream>>>(yb, rb, kb, vb, gb, lnx_w + l * CC, lnx_b + l * CC,
                                            r_k + (size_t)l * CC, yg_bf);
    // x += (y*g) @ Wo
    gemm_bf16<1, 128><<<gBig, blk, 0, stream>>>(yg_bf, WoT, x, nullptr, CC, CC, nullptr, nullptr, nullptr, CC);

    // ---- channel mix ----
    ln_kernel<<<MM, blk, 0, stream>>>(x, nullptr, ln2_w + l * CC, ln2_b + l * CC, xn);
    mix_kernel<<<MIX_GRID, blk, 0, stream>>>(xn, f_xk + l * CC, mixr_bf);
    gemm_bf16<2, 128><<<gF, blk, 0, stream>>>(mixr_bf, fkT, nullptr, h_bf, FF4, CC, nullptr, nullptr, nullptr, FF4);
    gemm_bf16<1, 128><<<gBig, blk, 0, stream>>>(h_bf, fvT, x, nullptr, CC, FF4, nullptr, nullptr, nullptr, CC);
  }

  head_kernel<<<MM, blk, 0, stream>>>(x, lnout_w, lnout_b, head_w, out);
}

// Round 5
// 962.623 us; speedup vs baseline: 5.3098x; 1.3302x over previous
//
#include <hip/hip_runtime.h>
#include <hip/hip_bf16.h>
#include <math.h>

#define CC 896
#define TT 512
#define BB 4
#define HH 14
#define NN 64
#define DD 64
#define DGG 160
#define FF4 3584
#define MM (BB*TT)   // 2048
#define RD 8         // scan ring depth
#define NCH 8        // chunks per (b,h)
#define CL 64        // chunk length = TT/NCH

typedef __attribute__((ext_vector_type(8))) short bf16x8;
typedef __attribute__((ext_vector_type(4))) float f32x4;

__device__ __forceinline__ float waveRedSum(float x) {
#pragma unroll
  for (int off = 32; off > 0; off >>= 1) x += __shfl_xor(x, off, 64);
  return x;
}

__device__ __forceinline__ float sigmoidf_(float x) { return 1.f / (1.f + expf(-x)); }

__device__ __forceinline__ void gload_lds16(const void* g, void* l) {
  __builtin_amdgcn_global_load_lds((const __attribute__((address_space(1))) void*)g,
                                   (__attribute__((address_space(3))) void*)l, 16, 0, 0);
}
__device__ __forceinline__ void gload_lds4(const void* g, void* l) {
  __builtin_amdgcn_global_load_lds((const __attribute__((address_space(1))) void*)g,
                                   (__attribute__((address_space(3))) void*)l, 4, 0, 0);
}

// ---------------- LayerNorm (optionally gathering via idx) ----------------
__global__ __launch_bounds__(256)
void ln_kernel(const float* __restrict__ in, const int* __restrict__ idx,
               const float* __restrict__ w, const float* __restrict__ bvec,
               float* __restrict__ out)
{
  int m = blockIdx.x;
  const float* row = idx ? (in + (size_t)idx[m] * CC) : (in + (size_t)m * CC);
  float s = 0.f, s2 = 0.f;
  for (int c = threadIdx.x; c < CC; c += 256) { float x = row[c]; s += x; s2 += x * x; }
  __shared__ float red[2][4];
  float a = waveRedSum(s), b2 = waveRedSum(s2);
  int wid = threadIdx.x >> 6;
  if ((threadIdx.x & 63) == 0) { red[0][wid] = a; red[1][wid] = b2; }
  __syncthreads();
  s  = red[0][0] + red[0][1] + red[0][2] + red[0][3];
  s2 = red[1][0] + red[1][1] + red[1][2] + red[1][3];
  float mean = s * (1.f / CC);
  float var  = s2 * (1.f / CC) - mean * mean;
  float inv  = rsqrtf(var + 1e-5f);
  float* orow = out + (size_t)m * CC;
  for (int c = threadIdx.x; c < CC; c += 256)
    orow[c] = (row[c] - mean) * inv * w[c] + bvec[c];
}

// ---------------- final LN + head ----------------
__global__ __launch_bounds__(256)
void head_kernel(const float* __restrict__ x, const float* __restrict__ w,
                 const float* __restrict__ bvec, const float* __restrict__ hw,
                 float* __restrict__ out)
{
  int m = blockIdx.x;
  const float* row = x + (size_t)m * CC;
  float s = 0.f, s2 = 0.f;
  for (int c = threadIdx.x; c < CC; c += 256) { float v = row[c]; s += v; s2 += v * v; }
  __shared__ float red[2][4];
  float a = waveRedSum(s), b2 = waveRedSum(s2);
  int wid = threadIdx.x >> 6;
  if ((threadIdx.x & 63) == 0) { red[0][wid] = a; red[1][wid] = b2; }
  __syncthreads();
  s  = red[0][0] + red[0][1] + red[0][2] + red[0][3];
  s2 = red[1][0] + red[1][1] + red[1][2] + red[1][3];
  float mean = s * (1.f / CC);
  float var  = s2 * (1.f / CC) - mean * mean;
  float inv  = rsqrtf(var + 1e-5f);
  float p = 0.f;
  for (int c = threadIdx.x; c < CC; c += 256)
    p += ((row[c] - mean) * inv * w[c] + bvec[c]) * hw[c];
  p = waveRedSum(p);
  __shared__ float red2[4];
  if ((threadIdx.x & 63) == 0) red2[wid] = p;
  __syncthreads();
  if (threadIdx.x == 0) out[m] = red2[0] + red2[1] + red2[2] + red2[3];
}

// ---------------- fused 6-way token-shift mix ----------------
__global__ __launch_bounds__(256)
void mix6_kernel(const float* __restrict__ xn,
                 const float* __restrict__ cr, const float* __restrict__ cw,
                 const float* __restrict__ ck, const float* __restrict__ cv,
                 const float* __restrict__ ca, const float* __restrict__ cg,
                 __hip_bfloat16* __restrict__ outr, float* __restrict__ outw,
                 __hip_bfloat16* __restrict__ outk, __hip_bfloat16* __restrict__ outv,
                 __hip_bfloat16* __restrict__ outa, __hip_bfloat16* __restrict__ outg)
{
  size_t i = (size_t)blockIdx.x * 256 + threadIdx.x;
  int c = (int)(i % CC);
  size_t m = i / CC;
  int t = (int)(m % TT);
  float cur  = xn[i];
  float prev = (t > 0) ? xn[i - CC] : 0.f;
  float d = prev - cur;
  outr[i] = __float2bfloat16(fmaf(d, cr[c], cur));
  outw[i] = fmaf(d, cw[c], cur);
  outk[i] = __float2bfloat16(fmaf(d, ck[c], cur));
  outv[i] = __float2bfloat16(fmaf(d, cv[c], cur));
  outa[i] = __float2bfloat16(fmaf(d, ca[c], cur));
  outg[i] = __float2bfloat16(fmaf(d, cg[c], cur));
}

// ---------------- single mix (channel-mix path), bf16 out ----------------
__global__ __launch_bounds__(256)
void mix_kernel(const float* __restrict__ xn, const float* __restrict__ coef,
                __hip_bfloat16* __restrict__ outb)
{
  size_t i = (size_t)blockIdx.x * 256 + threadIdx.x;
  int c = (int)(i % CC);
  size_t m = i / CC;
  int t = (int)(m % TT);
  float cur  = xn[i];
  float prev = (t > 0) ? xn[i - CC] : 0.f;
  outb[i] = __float2bfloat16(fmaf(prev - cur, coef[c], cur));
}

// ---------------- convert + transpose body ----------------
__device__ __forceinline__ void convT_body(const float* __restrict__ W,
                                           __hip_bfloat16* __restrict__ Wt,
                                           int K, int N, int KP, int NP,
                                           int bx, int by)
{
  __shared__ float tile[32][33];
  int bn = bx * 32, bk = by * 32;
  int tx = threadIdx.x & 31, ty = threadIdx.x >> 5;
#pragma unroll
  for (int i = 0; i < 4; i++) {
    int k = bk + ty + i * 8, n = bn + tx;
    tile[ty + i * 8][tx] = (k < K && n < N) ? W[(size_t)k * N + n] : 0.f;
  }
  __syncthreads();
#pragma unroll
  for (int i = 0; i < 4; i++) {
    int n = bn + ty + i * 8, k = bk + tx;
    if (n < NP && k < KP)
      Wt[(size_t)n * KP + k] = __float2bfloat16(tile[tx][ty + i * 8]);
  }
}

__global__ __launch_bounds__(256)
void convT_kernel(const float* __restrict__ W, __hip_bfloat16* __restrict__ Wt,
                  int K, int N, int KP, int NP)
{
  convT_body(W, Wt, K, N, KP, NP, blockIdx.x, blockIdx.y);
}

// all small per-layer weights in one launch, grid (28,28,10)
__global__ __launch_bounds__(256)
void convT_batch(const float* Wr, const float* Wk, const float* Wv, const float* Wo,
                 const float* a1, const float* a2, const float* v1, const float* v2,
                 const float* g1, const float* g2,
                 __hip_bfloat16* WrT, __hip_bfloat16* WkT, __hip_bfloat16* WvT,
                 __hip_bfloat16* WoT, __hip_bfloat16* a1T, __hip_bfloat16* a2T,
                 __hip_bfloat16* v1T, __hip_bfloat16* v2T, __hip_bfloat16* g1T,
                 __hip_bfloat16* g2T)
{
  const float* W; __hip_bfloat16* Wt; int K, N, KP, NP;
  switch (blockIdx.z) {
    case 0: W = Wr; Wt = WrT; K = CC;  N = CC;  KP = CC;  NP = CC;  break;
    case 1: W = Wk; Wt = WkT; K = CC;  N = CC;  KP = CC;  NP = CC;  break;
    case 2: W = Wv; Wt = WvT; K = CC;  N = CC;  KP = CC;  NP = CC;  break;
    case 3: W = Wo; Wt = WoT; K = CC;  N = CC;  KP = CC;  NP = CC;  break;
    case 4: W = a1; Wt = a1T; K = CC;  N = DD;  KP = CC;  NP = DD;  break;
    case 5: W = a2; Wt = a2T; K = DD;  N = CC;  KP = DD;  NP = CC;  break;
    case 6: W = v1; Wt = v1T; K = CC;  N = DD;  KP = CC;  NP = DD;  break;
    case 7: W = v2; Wt = v2T; K = DD;  N = CC;  KP = DD;  NP = CC;  break;
    case 8: W = g1; Wt = g1T; K = CC;  N = DGG; KP = CC;  NP = 192; break;
    default: W = g2; Wt = g2T; K = DGG; N = CC; KP = 192; NP = CC;  break;
  }
  if ((int)blockIdx.x * 32 >= NP || (int)blockIdx.y * 32 >= KP) return;
  convT_body(W, Wt, K, N, KP, NP, blockIdx.x, blockIdx.y);
}

// ---------------- bf16 MFMA GEMM body: C[M][N] = A[M][K] * Bt[N][K]^T ----------------
// MEPI: 0 store f32, 1 add f32, 2 relu^2->bf16, 3 store bf16, 4 sigmoid->bf16 (pad0 past Nreal),
//       5 sigmoid(bias+v)->f32, 6 v-gate->f32
template<int MEPI, int BN>
__device__ __forceinline__ void gemm_body(const __hip_bfloat16* __restrict__ A,
    const __hip_bfloat16* __restrict__ Bt, float* __restrict__ C,
    __hip_bfloat16* __restrict__ Cbf, int N, int K, const float* __restrict__ bias,
    const float* __restrict__ aux0, const float* __restrict__ aux1, int Nreal,
    int bx, int by)
{
  constexpr int WN = BN / 64;
  constexpr int WM = 4 / WN;
  constexpr int ROWS = 128 / WM;
  constexpr int MI = ROWS / 16;
  __shared__ __align__(16) ushort As[128 * 64];
  __shared__ __align__(16) ushort Bs[BN * 64];
  int tid = threadIdx.x;
  int lane = tid & 63, wave = tid >> 6;
  int wm, wn;
  if constexpr (WN == 2) { wm = wave >> 1; wn = wave & 1; } else { wm = wave; wn = 0; }
  int fl = lane & 15, fh = lane >> 4;
  int row0 = by * 128, col0 = bx * BN;

  const char* Abase = (const char*)A + (size_t)row0 * (size_t)(K * 2);
  const char* Bbase = (const char*)Bt + (size_t)col0 * (size_t)(K * 2);
  char* AsB = (char*)As;
  char* BsB = (char*)Bs;

  f32x4 acc[MI][4];
#pragma unroll
  for (int mi = 0; mi < MI; mi++)
#pragma unroll
    for (int ni = 0; ni < 4; ni++)
      acc[mi][ni] = (f32x4){0.f, 0.f, 0.f, 0.f};

  int srow = tid >> 3;
  int scol = (tid & 7) << 4;
  int ldsw = (wave << 10);

  for (int k0 = 0; k0 < K; k0 += 64) {
#pragma unroll
    for (int it = 0; it < 4; ++it) {
      int r = it * 32 + srow;
      int cbs = scol ^ ((r & 7) << 4);
      size_t goff = (size_t)r * (size_t)(K * 2) + (size_t)(k0 * 2) + cbs;
      gload_lds16(Abase + goff, AsB + (it << 12) + ldsw);
      if constexpr (BN == 128) {
        gload_lds16(Bbase + goff, BsB + (it << 12) + ldsw);
      } else {
        if (it < 2) gload_lds16(Bbase + goff, BsB + (it << 12) + ldsw);
      }
    }
    __syncthreads();
#pragma unroll
    for (int kk = 0; kk < 2; ++kk) {
      bf16x8 af[MI], bfr[4];
      int kb_ = kk * 64 + (fh << 4);
#pragma unroll
      for (int mi = 0; mi < MI; mi++) {
        int r = wm * ROWS + mi * 16 + fl;
        af[mi] = *(const bf16x8*)(AsB + r * 128 + (kb_ ^ ((r & 7) << 4)));
      }
#pragma unroll
      for (int ni = 0; ni < 4; ni++) {
        int r = wn * 64 + ni * 16 + fl;
        bfr[ni] = *(const bf16x8*)(BsB + r * 128 + (kb_ ^ ((r & 7) << 4)));
      }
#pragma unroll
      for (int mi = 0; mi < MI; mi++)
#pragma unroll
        for (int ni = 0; ni < 4; ni++)
          acc[mi][ni] = __builtin_amdgcn_mfma_f32_16x16x32_bf16(af[mi], bfr[ni], acc[mi][ni], 0, 0, 0);
    }
    __syncthreads();
  }

#pragma unroll
  for (int mi = 0; mi < MI; mi++) {
    int crow0 = row0 + wm * ROWS + mi * 16 + fh * 4;
#pragma unroll
    for (int ni = 0; ni < 4; ni++) {
      int ccol = col0 + wn * 64 + ni * 16 + fl;
#pragma unroll
      for (int e = 0; e < 4; e++) {
        size_t off = (size_t)(crow0 + e) * N + ccol;
        float v = acc[mi][ni][e];
        if constexpr (MEPI == 0) {
          C[off] = v;
        } else if constexpr (MEPI == 1) {
          C[off] += v;
        } else if constexpr (MEPI == 2) {
          float t = fmaxf(v, 0.f);
          Cbf[off] = __float2bfloat16(t * t);
        } else if constexpr (MEPI == 3) {
          Cbf[off] = __float2bfloat16(v);
        } else if constexpr (MEPI == 4) {
          float sv = (ccol < Nreal) ? sigmoidf_(v) : 0.f;
          Cbf[off] = __float2bfloat16(sv);
        } else if constexpr (MEPI == 5) {
          C[off] = sigmoidf_(bias[ccol] + v);
        } else if constexpr (MEPI == 6) {
          float sg = sigmoidf_(bias[ccol] + v);
          float vv = aux0[off];
          C[off] = vv + (aux1[off] - vv) * sg;
        }
      }
    }
  }
}

template<int MEPI, int BN>
__global__ __launch_bounds__(256)
void gemm_bf16(const __hip_bfloat16* __restrict__ A, const __hip_bfloat16* __restrict__ Bt,
               float* __restrict__ C, __hip_bfloat16* __restrict__ Cbf,
               int N, int K, const float* __restrict__ bias,
               const float* __restrict__ aux0, const float* __restrict__ aux1, int Nreal)
{
  gemm_body<MEPI, BN>(A, Bt, C, Cbf, N, K, bias, aux0, aux1, Nreal, blockIdx.x, blockIdx.y);
}

// batched r/k/v projection, grid (7,16,3)
__global__ __launch_bounds__(256)
void gemm_rkv(const __hip_bfloat16* Ar, const __hip_bfloat16* Ak, const __hip_bfloat16* Av,
              const __hip_bfloat16* Br, const __hip_bfloat16* Bk, const __hip_bfloat16* Bv,
              float* Cr, float* Ck, float* Cv)
{
  const __hip_bfloat16* A; const __hip_bfloat16* Bt; float* C;
  if (blockIdx.z == 0)      { A = Ar; Bt = Br; C = Cr; }
  else if (blockIdx.z == 1) { A = Ak; Bt = Bk; C = Ck; }
  else                      { A = Av; Bt = Bv; C = Cv; }
  gemm_body<0, 128>(A, Bt, C, nullptr, CC, CC, nullptr, nullptr, nullptr, CC,
                    blockIdx.x, blockIdx.y);
}

// ---------------- f32 GEMM (w path only). EPI: 1 tanh, 2 decay ----------------
template<int EPI>
__global__ __launch_bounds__(256)
void gemm_kernel(const float* __restrict__ A, const float* __restrict__ B,
                 float* __restrict__ Cout, int M, int N, int K,
                 const float* __restrict__ bias)
{
  __shared__ __align__(16) float As[16][68];
  __shared__ __align__(16) float Bs[16][68];
  int tid = threadIdx.x;
  int tx = tid & 15, ty = tid >> 4;
  int row0 = blockIdx.y * 64, col0 = blockIdx.x * 64;
  float acc[4][4] = {};
  int a_m = tid >> 2;
  int a_k = (tid & 3) * 4;
  int b_k = tid >> 4;
  int b_n = (tid & 15) * 4;
  for (int k0 = 0; k0 < K; k0 += 16) {
    float4 av = *(const float4*)(A + (size_t)(row0 + a_m) * K + k0 + a_k);
    As[a_k + 0][a_m] = av.x; As[a_k + 1][a_m] = av.y;
    As[a_k + 2][a_m] = av.z; As[a_k + 3][a_m] = av.w;
    float4 bv;
    if (col0 + b_n < N) bv = *(const float4*)(B + (size_t)(k0 + b_k) * N + col0 + b_n);
    else bv = make_float4(0.f, 0.f, 0.f, 0.f);
    *(float4*)&Bs[b_k][b_n] = bv;
    __syncthreads();
#pragma unroll
    for (int kk = 0; kk < 16; kk++) {
      float af[4], bfv[4];
#pragma unroll
      for (int i = 0; i < 4; i++) af[i] = As[kk][ty * 4 + i];
#pragma unroll
      for (int j = 0; j < 4; j++) bfv[j] = Bs[kk][tx * 4 + j];
#pragma unroll
      for (int i = 0; i < 4; i++)
#pragma unroll
        for (int j = 0; j < 4; j++)
          acc[i][j] = fmaf(af[i], bfv[j], acc[i][j]);
    }
    __syncthreads();
  }
#pragma unroll
  for (int i = 0; i < 4; i++) {
    int m = row0 + ty * 4 + i;
#pragma unroll
    for (int j = 0; j < 4; j++) {
      int n = col0 + tx * 4 + j;
      if (n >= N) continue;
      size_t off = (size_t)m * N + n;
      float v = acc[i][j];
      if constexpr (EPI == 1) {
        Cout[off] = tanhf(v);
      } else if constexpr (EPI == 2) {
        float z = bias[n] + v;
        float sp = fmaxf(-z, 0.f) + log1pf(expf(-fabsf(z)));
        float w = -sp - 0.5f;
        Cout[off] = expf(-expf(w));
      }
    }
  }
}

// ---------------- prep: kk norm, a_in=-kk, b_in=kk*a, k gating ----------------
__global__ __launch_bounds__(896)
void prep_kernel(const float* __restrict__ k_in, const float* __restrict__ a,
                 const float* __restrict__ k_k, const float* __restrict__ k_a,
                 float* __restrict__ kout, float* __restrict__ ain, float* __restrict__ bin)
{
  int m = blockIdx.x;
  int c = threadIdx.x;
  size_t off = (size_t)m * CC + c;
  float kv = k_in[off];
  float av = a[off];
  float kkv = kv * k_k[c];
  float ss = waveRedSum(kkv * kkv);
  float norm = sqrtf(ss);
  float kkn = kkv / fmaxf(norm, 1e-12f);
  ain[off] = -kkn;
  bin[off] = kkn * av;
  kout[off] = kv * (1.f + (av - 1.f) * k_a[c]);
}

// ================= chunk-parallel RWKV7 scan =================
// S_t = S_{t-1} (diag(d)+a b^T) + v k^T. Per chunk c (len CL):
//   S_t = S_in P_t + Z_t;  y_t = S_in u_t + y0_t;  u_t = P_t r_t.
// Phase 1 (448 blocks): chunk-local zero-state scan (Z,y0) + P product + u.
// Phase 2 (56 blocks):  S_in[c+1] = S_in[c] P_c + Z_c (sequential over c).
// Phase 3 (448 blocks): y_t += S_in[c] u_t.

__global__ __launch_bounds__(256)
void scanp1_kernel(const float* __restrict__ rp, const float* __restrict__ dp,
                   const float* __restrict__ kp, const float* __restrict__ vp,
                   const float* __restrict__ ap, const float* __restrict__ bp_,
                   float* __restrict__ yp, float* __restrict__ ubuf,
                   float* __restrict__ Pc, float* __restrict__ Zc)
{
  int bid = blockIdx.x;
  int bh = bid >> 3, c = bid & 7;
  int b = bh / HH, h = bh - b * HH;
  int tid = threadIdx.x, lane = tid & 63, w = tid >> 6;
  int w16 = w * 16;
  __shared__ __align__(16) float ring[RD][6][64];   // 0 r, 1 d, 2 k, 3 a, 4 b, 5 v
  __shared__ float sa_part[2][4][64];
  __shared__ float pa_part[2][4][64];
  __shared__ float y_part[2][4][64];
  __shared__ float u_part[2][4][64];

  float s[16], p[16];
#pragma unroll
  for (int jj = 0; jj < 16; jj++) {
    s[jj] = 0.f;
    p[jj] = (lane == w16 + jj) ? 1.f : 0.f;   // P = Identity
  }
  size_t base = ((size_t)b * TT + (size_t)c * CL) * CC + (size_t)h * NN + lane;

  const float* gA = nullptr; const float* gB = nullptr; int slA = 0, slB = 0;
  if (w == 1)      { gA = rp;  slA = 0; gB = dp;  slB = 1; }
  else if (w == 2) { gA = kp;  slA = 2; gB = vp;  slB = 5; }
  else if (w == 3) { gA = ap;  slA = 3; gB = bp_; slB = 4; }

  if (w) {
    for (int t0 = 0; t0 < RD; t0++) {
      gload_lds4(gA + base + (size_t)t0 * CC, &ring[t0][slA][0]);
      gload_lds4(gB + base + (size_t)t0 * CC, &ring[t0][slB][0]);
    }
    asm volatile("s_waitcnt vmcnt(0)" ::: "memory");
  }
  __builtin_amdgcn_s_barrier();
  __builtin_amdgcn_sched_barrier(0);

  for (int t = 0; t < CL; ++t) {
    int Pp = t & 1, Qp = Pp ^ 1;
    int slot = t & (RD - 1);
    float av[16], dv[16], kv[16], bv[16], rv[16];
#pragma unroll
    for (int q = 0; q < 4; q++) {
      *(float4*)&av[q * 4] = *(const float4*)&ring[slot][3][w16 + q * 4];
      *(float4*)&dv[q * 4] = *(const float4*)&ring[slot][1][w16 + q * 4];
      *(float4*)&kv[q * 4] = *(const float4*)&ring[slot][2][w16 + q * 4];
      *(float4*)&bv[q * 4] = *(const float4*)&ring[slot][4][w16 + q * 4];
      *(float4*)&rv[q * 4] = *(const float4*)&ring[slot][0][w16 + q * 4];
    }
    float vi = ring[slot][5][lane];
    // partial reductions over this wave's 16 columns
    float sp0 = 0.f, sp1 = 0.f, pp0 = 0.f, pp1 = 0.f;
#pragma unroll
    for (int jj = 0; jj < 8; jj++) {
      sp0 = fmaf(s[jj],     av[jj],     sp0);
      sp1 = fmaf(s[jj + 8], av[jj + 8], sp1);
      pp0 = fmaf(p[jj],     av[jj],     pp0);
      pp1 = fmaf(p[jj + 8], av[jj + 8], pp1);
    }
    sa_part[Pp][w][lane] = sp0 + sp1;
    pa_part[Pp][w][lane] = pp0 + pp1;
    if (w) { asm volatile("s_waitcnt vmcnt(12)" ::: "memory"); }
    asm volatile("s_waitcnt lgkmcnt(0)" ::: "memory");
    __builtin_amdgcn_s_barrier();
    __builtin_amdgcn_sched_barrier(0);
    if (w && t + RD < CL) {
      gload_lds4(gA + base + (size_t)(t + RD) * CC, &ring[slot][slA][0]);
      gload_lds4(gB + base + (size_t)(t + RD) * CC, &ring[slot][slB][0]);
    }
    if (w == 0 && t > 0) {
      float yo = (y_part[Qp][0][lane] + y_part[Qp][1][lane])
               + (y_part[Qp][2][lane] + y_part[Qp][3][lane]);
      yp[base + (size_t)(t - 1) * CC] = yo;
      float uo = (u_part[Qp][0][lane] + u_part[Qp][1][lane])
               + (u_part[Qp][2][lane] + u_part[Qp][3][lane]);
      ubuf[((size_t)bid * CL + (t - 1)) * 64 + lane] = uo;
    }
    float sa = (sa_part[Pp][0][lane] + sa_part[Pp][1][lane])
             + (sa_part[Pp][2][lane] + sa_part[Pp][3][lane]);
    float pa = (pa_part[Pp][0][lane] + pa_part[Pp][1][lane])
             + (pa_part[Pp][2][lane] + pa_part[Pp][3][lane]);
    float y0 = 0.f, y1 = 0.f, u0 = 0.f, u1 = 0.f;
#pragma unroll
    for (int jj = 0; jj < 8; jj++) {
      s[jj]     = fmaf(s[jj],     dv[jj],     fmaf(sa, bv[jj],     vi * kv[jj]));
      y0 = fmaf(s[jj], rv[jj], y0);
      s[jj + 8] = fmaf(s[jj + 8], dv[jj + 8], fmaf(sa, bv[jj + 8], vi * kv[jj + 8]));
      y1 = fmaf(s[jj + 8], rv[jj + 8], y1);
      p[jj]     = fmaf(p[jj],     dv[jj],     pa * bv[jj]);
      u0 = fmaf(p[jj], rv[jj], u0);
      p[jj + 8] = fmaf(p[jj + 8], dv[jj + 8], pa * bv[jj + 8]);
      u1 = fmaf(p[jj + 8], rv[jj + 8], u1);
    }
    y_part[Pp][w][lane] = y0 + y1;
    u_part[Pp][w][lane] = u0 + u1;
  }

  asm volatile("s_waitcnt lgkmcnt(0)" ::: "memory");
  __builtin_amdgcn_s_barrier();
  if (w == 0) {
    int Pl = (CL - 1) & 1;
    float yo = (y_part[Pl][0][lane] + y_part[Pl][1][lane])
             + (y_part[Pl][2][lane] + y_part[Pl][3][lane]);
    yp[base + (size_t)(CL - 1) * CC] = yo;
    float uo = (u_part[Pl][0][lane] + u_part[Pl][1][lane])
             + (u_part[Pl][2][lane] + u_part[Pl][3][lane]);
    ubuf[((size_t)bid * CL + (CL - 1)) * 64 + lane] = uo;
  }
  // store Z (= zero-state S) and P (= chunk transition)
  float* zp = Zc + ((size_t)bid * 64 + lane) * 64 + w16;
  float* pq = Pc + ((size_t)bid * 64 + lane) * 64 + w16;
#pragma unroll
  for (int q = 0; q < 4; q++) {
    *(float4*)&zp[q * 4] = make_float4(s[q*4], s[q*4+1], s[q*4+2], s[q*4+3]);
    *(float4*)&pq[q * 4] = make_float4(p[q*4], p[q*4+1], p[q*4+2], p[q*4+3]);
  }
}

// phase 2: per bh, sequential over chunks: Sin[c] = S; S = S*P_c + Z_c
__global__ __launch_bounds__(256)
void scanp2_kernel(const float* __restrict__ Pc, const float* __restrict__ Zc,
                   float* __restrict__ Sin)
{
  int bh = blockIdx.x;
  int tid = threadIdx.x, i = tid & 63, jg = tid >> 6, j0 = jg * 16;
  __shared__ float S_lds[64][65];
  __shared__ __align__(16) float P_lds[64][64];
#pragma unroll
  for (int jj = 0; jj < 16; jj++) S_lds[i][j0 + jj] = 0.f;

  for (int c = 0; c < NCH; c++) {
    size_t bidc = (size_t)(bh * NCH + c);
    // stage P_c: each thread 16 consecutive floats
    {
      const float4* src = (const float4*)(Pc + bidc * 4096 + (size_t)tid * 16);
      float4* dst = (float4*)(&P_lds[0][0] + tid * 16);
      dst[0] = src[0]; dst[1] = src[1]; dst[2] = src[2]; dst[3] = src[3];
    }
    __syncthreads();
    // Sin[c] = current S
    float sv[16];
#pragma unroll
    for (int jj = 0; jj < 16; jj++) sv[jj] = S_lds[i][j0 + jj];
    {
      float4* sp_ = (float4*)(Sin + bidc * 4096 + (size_t)i * 64 + j0);
#pragma unroll
      for (int q = 0; q < 4; q++)
        sp_[q] = make_float4(sv[q*4], sv[q*4+1], sv[q*4+2], sv[q*4+3]);
    }
    // nv = S * P_c + Z_c (row i x cols j0..j0+15)
    float nv[16];
#pragma unroll
    for (int jj = 0; jj < 16; jj++) nv[jj] = 0.f;
    for (int m = 0; m < 64; m++) {
      float sm = S_lds[i][m];
#pragma unroll
      for (int jj = 0; jj < 16; jj++)
        nv[jj] = fmaf(sm, P_lds[m][j0 + jj], nv[jj]);
    }
    {
      const float4* zp = (const float4*)(Zc + bidc * 4096 + (size_t)i * 64 + j0);
#pragma unroll
      for (int q = 0; q < 4; q++) {
        float4 z4 = zp[q];
        nv[q*4+0] += z4.x; nv[q*4+1] += z4.y; nv[q*4+2] += z4.z; nv[q*4+3] += z4.w;
      }
    }
    __syncthreads();
#pragma unroll
    for (int jj = 0; jj < 16; jj++) S_lds[i][j0 + jj] = nv[jj];
    // loop-top staging of next P is ordered by the __syncthreads() above + next one
  }
}

// phase 3: y_t += Sin[c] * u_t
__global__ __launch_bounds__(256)
void scanp3_kernel(const float* __restrict__ Sin, const float* __restrict__ ubuf,
                   float* __restrict__ yp)
{
  int bid = blockIdx.x;
  int bh = bid >> 3, c = bid & 7;
  int b = bh / HH, h = bh - b * HH;
  int tid = threadIdx.x, i = tid & 63, wv = tid >> 6;
  __shared__ float S_lds[64][65];
  __shared__ __align__(16) float U_lds[64][64];   // [t][j]
  {
    int r = tid >> 2, q = tid & 3;
    const float* src = Sin + (size_t)bid * 4096 + (size_t)r * 64 + q * 16;
#pragma unroll
    for (int jj = 0; jj < 16; jj++) S_lds[r][q * 16 + jj] = src[jj];
    const float4* us = (const float4*)(ubuf + (size_t)bid * 4096 + (size_t)r * 64 + q * 16);
    float4* ud = (float4*)(&U_lds[r][q * 16]);
    ud[0] = us[0]; ud[1] = us[1]; ud[2] = us[2]; ud[3] = us[3];
  }
  __syncthreads();
  // cache S row i in registers
  float sreg[64];
#pragma unroll
  for (int m = 0; m < 64; m++) sreg[m] = S_lds[i][m];
  size_t ybase = ((size_t)b * TT + (size_t)c * CL) * CC + (size_t)h * NN + i;
#pragma unroll 1
  for (int tt = 0; tt < 16; tt++) {
    int t = wv * 16 + tt;
    float a0 = 0.f, a1 = 0.f, a2 = 0.f, a3 = 0.f;
#pragma unroll
    for (int m4 = 0; m4 < 16; m4++) {
      float4 uu = *(const float4*)&U_lds[t][m4 * 4];
      a0 = fmaf(sreg[m4*4+0], uu.x, a0);
      a1 = fmaf(sreg[m4*4+1], uu.y, a1);
      a2 = fmaf(sreg[m4*4+2], uu.z, a2);
      a3 = fmaf(sreg[m4*4+3], uu.w, a3);
    }
    yp[ybase + (size_t)t * CC] += (a0 + a1) + (a2 + a3);
  }
}

// ---------------- groupnorm + rk*v + *g -> bf16 ----------------
__global__ __launch_bounds__(896)
void gn_kernel(const float* __restrict__ y_in, const float* __restrict__ r,
               const float* __restrict__ k, const float* __restrict__ v,
               const float* __restrict__ g, const float* __restrict__ lnx_w,
               const float* __restrict__ lnx_b, const float* __restrict__ r_k,
               __hip_bfloat16* __restrict__ yout_bf)
{
  int m = blockIdx.x;
  int c = threadIdx.x;
  size_t off = (size_t)m * CC + c;
  float yv = y_in[off];
  float s1 = waveRedSum(yv);
  float s2 = waveRedSum(yv * yv);
  float mean = s1 * (1.f / 64.f);
  float var  = s2 * (1.f / 64.f) - mean * mean;
  float norm = (yv - mean) * rsqrtf(var + 0.00064f);
  float rv = r[off], kv = k[off], vv = v[off];
  float rk = waveRedSum(rv * kv * r_k[c]);
  yout_bf[off] = __float2bfloat16((norm * lnx_w[c] + lnx_b[c] + rk * vv) * g[off]);
}

// ---------------- host ----------------
extern "C" void kernel_launch(void* const* d_in, const int* in_sizes, int n_in,
                              void* d_out, int out_size, void* d_ws, size_t ws_size,
                              hipStream_t stream)
{
  const int*   idx    = (const int*)d_in[0];
  const float* emb    = (const float*)d_in[1];
  const float* ln0_w  = (const float*)d_in[2];
  const float* ln0_b  = (const float*)d_in[3];
  const float* ln1_w  = (const float*)d_in[4];
  const float* ln1_b  = (const float*)d_in[5];
  const float* ln2_w  = (const float*)d_in[6];
  const float* ln2_b  = (const float*)d_in[7];
  const float* x_r    = (const float*)d_in[8];
  const float* x_w    = (const float*)d_in[9];
  const float* x_k    = (const float*)d_in[10];
  const float* x_v    = (const float*)d_in[11];
  const float* x_a    = (const float*)d_in[12];
  const float* x_g    = (const float*)d_in[13];
  const float* w0     = (const float*)d_in[14];
  const float* w1     = (const float*)d_in[15];
  const float* w2     = (const float*)d_in[16];
  const float* a0     = (const float*)d_in[17];
  const float* a1     = (const float*)d_in[18];
  const float* a2     = (const float*)d_in[19];
  const float* v0     = (const float*)d_in[20];
  const float* v1     = (const float*)d_in[21];
  const float* v2     = (const float*)d_in[22];
  const float* g1     = (const float*)d_in[23];
  const float* g2     = (const float*)d_in[24];
  const float* k_k    = (const float*)d_in[25];
  const float* k_a    = (const float*)d_in[26];
  const float* r_k    = (const float*)d_in[27];
  const float* Wr     = (const float*)d_in[28];
  const float* Wk     = (const float*)d_in[29];
  const float* Wv     = (const float*)d_in[30];
  const float* Wo     = (const float*)d_in[31];
  const float* lnx_w  = (const float*)d_in[32];
  const float* lnx_b  = (const float*)d_in[33];
  const float* f_xk   = (const float*)d_in[34];
  const float* f_key  = (const float*)d_in[35];
  const float* f_val  = (const float*)d_in[36];
  const float* lnout_w = (const float*)d_in[37];
  const float* lnout_b = (const float*)d_in[38];
  const float* head_w  = (const float*)d_in[39];
  float* out = (float*)d_out;

  const size_t MC = (size_t)MM * CC;
  const size_t W2 = (size_t)CC * CC;
  float* ws   = (float*)d_ws;
  float* x    = ws;
  float* xn   = x + MC;
  float* mixw = xn + MC;
  float* vfirst = mixw + MC;
  float* rb   = vfirst + MC;
  float* dcy  = rb + MC;
  float* kb   = dcy + MC;
  float* vb   = kb + MC;
  float* ab   = vb + MC;
  float* gb   = ab + MC;
  float* ainb = gb + MC;
  float* binb = ainb + MC;
  float* yb   = binb + MC;
  float* t64  = yb + MC;
  float* ubuf = t64 + (size_t)MM * DD;               // [448][64][64] = MC floats
  float* Pcb  = ubuf + MC;
  float* Zcb  = Pcb + MC;
  float* Sinb = Zcb + MC;
  float* fend = Sinb + MC;

  __hip_bfloat16* mixr_bf = (__hip_bfloat16*)fend;
  __hip_bfloat16* mixk_bf = mixr_bf + MC;
  __hip_bfloat16* mixv_bf = mixk_bf + MC;
  __hip_bfloat16* mixa_bf = mixv_bf + MC;
  __hip_bfloat16* mixg_bf = mixa_bf + MC;
  __hip_bfloat16* WrT = mixg_bf + MC;
  __hip_bfloat16* WkT = WrT + W2;
  __hip_bfloat16* WvT = WkT + W2;
  __hip_bfloat16* WoT = WvT + W2;
  __hip_bfloat16* fkT = WoT + W2;                    // [3584][896]
  __hip_bfloat16* fvT = fkT + (size_t)FF4 * CC;      // [896][3584]
  __hip_bfloat16* a1T = fvT + (size_t)FF4 * CC;      // [64][896]
  __hip_bfloat16* a2T = a1T + (size_t)64 * CC;       // [896][64]
  __hip_bfloat16* v1T = a2T + (size_t)64 * CC;
  __hip_bfloat16* v2T = v1T + (size_t)64 * CC;
  __hip_bfloat16* g1T = v2T + (size_t)64 * CC;       // [192][896]
  __hip_bfloat16* g2T = g1T + (size_t)192 * CC;      // [896][192]
  __hip_bfloat16* t64bf  = g2T + (size_t)192 * CC;   // [2048][64]
  __hip_bfloat16* t160bf = t64bf + (size_t)MM * 64;  // [2048][192]
  // aliases (dead fp32 buffers reused)
  __hip_bfloat16* h_bf  = (__hip_bfloat16*)rb;       // [2048][3584] spans rb+dcy
  __hip_bfloat16* yg_bf = (__hip_bfloat16*)ab;       // [2048][896]

  dim3 blk(256);
  const int MIX_GRID = (int)(MC / 256);

  ln_kernel<<<MM, blk, 0, stream>>>(emb, idx, ln0_w, ln0_b, x);

  for (int l = 0; l < 2; l++) {
    const float* Wr_l = Wr + (size_t)l * W2;
    const float* Wk_l = Wk + (size_t)l * W2;
    const float* Wv_l = Wv + (size_t)l * W2;
    const float* Wo_l = Wo + (size_t)l * W2;
    const float* w1_l = w1 + (size_t)l * CC * DD;
    const float* w2_l = w2 + (size_t)l * DD * CC;
    const float* a1_l = a1 + (size_t)l * CC * DD;
    const float* a2_l = a2 + (size_t)l * DD * CC;
    const float* v1_l = v1 + (size_t)l * CC * DD;
    const float* v2_l = v2 + (size_t)l * DD * CC;
    const float* g1_l = g1 + (size_t)l * CC * DGG;
    const float* g2_l = g2 + (size_t)l * DGG * CC;
    const float* fk_l = f_key + (size_t)l * CC * FF4;
    const float* fv_l = f_val + (size_t)l * FF4 * CC;

    convT_batch<<<dim3(28, 28, 10), blk, 0, stream>>>(
        Wr_l, Wk_l, Wv_l, Wo_l, a1_l, a2_l, v1_l, v2_l, g1_l, g2_l,
        WrT, WkT, WvT, WoT, a1T, a2T, v1T, v2T, g1T, g2T);
    convT_kernel<<<dim3(112, 28), blk, 0, stream>>>(fk_l, fkT, CC, FF4, CC, FF4);
    convT_kernel<<<dim3(28, 112), blk, 0, stream>>>(fv_l, fvT, FF4, CC, FF4, CC);

    ln_kernel<<<MM, blk, 0, stream>>>(x, nullptr, ln1_w + l * CC, ln1_b + l * CC, xn);
    mix6_kernel<<<MIX_GRID, blk, 0, stream>>>(xn,
        x_r + l * CC, x_w + l * CC, x_k + l * CC, x_v + l * CC, x_a + l * CC, x_g + l * CC,
        mixr_bf, mixw, mixk_bf, mixv_bf, mixa_bf, mixg_bf);

    dim3 gBig(CC / 128, MM / 128);     // (7,16)
    dim3 gF(FF4 / 128, MM / 128);      // (28,16)
    dim3 g64f(1, MM / 64);
    dim3 gCCs(CC / 64, MM / 64);
    dim3 gN64(1, MM / 128);
    dim3 gN192(3, MM / 128);

    // r,k,v batched
    gemm_rkv<<<dim3(7, 16, 3), blk, 0, stream>>>(mixr_bf, mixk_bf, mixv_bf,
                                                 WrT, WkT, WvT, rb, kb, vb);
    // w (fp32 path)
    gemm_kernel<1><<<g64f, blk, 0, stream>>>(mixw, w1_l, t64, MM, DD, CC, nullptr);
    gemm_kernel<2><<<gCCs, blk, 0, stream>>>(t64, w2_l, dcy, MM, CC, DD, w0 + l * CC);
    // v gate
    if (l == 0) {
      hipMemcpyAsync(vfirst, vb, MC * sizeof(float), hipMemcpyDeviceToDevice, stream);
    } else {
      gemm_bf16<3, 64><<<gN64, blk, 0, stream>>>(mixv_bf, v1T, nullptr, t64bf, DD, CC, nullptr, nullptr, nullptr, DD);
      gemm_bf16<6, 128><<<gBig, blk, 0, stream>>>(t64bf, v2T, vb, nullptr, CC, DD, v0 + l * CC, vb, vfirst, CC);
    }
    // a
    gemm_bf16<3, 64><<<gN64, blk, 0, stream>>>(mixa_bf, a1T, nullptr, t64bf, DD, CC, nullptr, nullptr, nullptr, DD);
    gemm_bf16<5, 128><<<gBig, blk, 0, stream>>>(t64bf, a2T, ab, nullptr, CC, DD, a0 + l * CC, nullptr, nullptr, CC);
    // g
    gemm_bf16<4, 64><<<gN192, blk, 0, stream>>>(mixg_bf, g1T, nullptr, t160bf, 192, CC, nullptr, nullptr, nullptr, DGG);
    gemm_bf16<0, 128><<<gBig, blk, 0, stream>>>(t160bf, g2T, gb, nullptr, CC, 192, nullptr, nullptr, nullptr, CC);
    // prep + chunked scan + gn
    prep_kernel<<<MM, dim3(896), 0, stream>>>(kb, ab, k_k + l * CC, k_a + l * CC, kb, ainb, binb);
    scanp1_kernel<<<BB * HH * NCH, blk, 0, stream>>>(rb, dcy, kb, vb, ainb, binb, yb, ubuf, Pcb, Zcb);
    scanp2_kernel<<<BB * HH, blk, 0, stream>>>(Pcb, Zcb, Sinb);
    scanp3_kernel<<<BB * HH * NCH, blk, 0, stream>>>(Sinb, ubuf, yb);
    gn_kernel<<<MM, dim3(896), 0, stream>>>(yb, rb, kb, vb, gb, lnx_w + l * CC, lnx_b + l * CC,
                                            r_k + (size_t)l * CC, yg_bf);
    // x += (y*g) @ Wo
    gemm_bf16<1, 128><<<gBig, blk, 0, stream>>>(yg_bf, WoT, x, nullptr, CC, CC, nullptr, nullptr, nullptr, CC);

    // ---- channel mix ----
    ln_kernel<<<MM, blk, 0, stream>>>(x, nullptr, ln2_w + l * CC, ln2_b + l * CC, xn);
    mix_kernel<<<MIX_GRID, blk, 0, stream>>>(xn, f_xk + l * CC, mixr_bf);
    gemm_bf16<2, 128><<<gF, blk, 0, stream>>>(mixr_bf, fkT, nullptr, h_bf, FF4, CC, nullptr, nullptr, nullptr, FF4);
    gemm_bf16<1, 128><<<gBig, blk, 0, stream>>>(h_bf, fvT, x, nullptr, CC, FF4, nullptr, nullptr, nullptr, CC);
  }

  head_kernel<<<MM, blk, 0, stream>>>(x, lnout_w, lnout_b, head_w, out);
}

// Round 6
// 956.403 us; speedup vs baseline: 5.3443x; 1.0065x over previous
//
#include <hip/hip_runtime.h>
#include <hip/hip_bf16.h>
#include <math.h>

#define CC 896
#define TT 512
#define BB 4
#define HH 14
#define NN 64
#define DD 64
#define DGG 160
#define FF4 3584
#define MM (BB*TT)   // 2048
#define RD 8         // scan ring depth
#define NCH 16       // chunks per (b,h)
#define CL 32        // chunk length = TT/NCH

typedef __attribute__((ext_vector_type(8))) short bf16x8;
typedef __attribute__((ext_vector_type(4))) float f32x4;

__device__ __forceinline__ float waveRedSum(float x) {
#pragma unroll
  for (int off = 32; off > 0; off >>= 1) x += __shfl_xor(x, off, 64);
  return x;
}

__device__ __forceinline__ float sigmoidf_(float x) { return 1.f / (1.f + expf(-x)); }

__device__ __forceinline__ void gload_lds16(const void* g, void* l) {
  __builtin_amdgcn_global_load_lds((const __attribute__((address_space(1))) void*)g,
                                   (__attribute__((address_space(3))) void*)l, 16, 0, 0);
}
__device__ __forceinline__ void gload_lds4(const void* g, void* l) {
  __builtin_amdgcn_global_load_lds((const __attribute__((address_space(1))) void*)g,
                                   (__attribute__((address_space(3))) void*)l, 4, 0, 0);
}

// ---------------- LayerNorm with idx gather (embedding + ln0) ----------------
__global__ __launch_bounds__(256)
void ln_kernel(const float* __restrict__ in, const int* __restrict__ idx,
               const float* __restrict__ w, const float* __restrict__ bvec,
               float* __restrict__ out)
{
  int m = blockIdx.x;
  const float* row = idx ? (in + (size_t)idx[m] * CC) : (in + (size_t)m * CC);
  float s = 0.f, s2 = 0.f;
  for (int c = threadIdx.x; c < CC; c += 256) { float x = row[c]; s += x; s2 += x * x; }
  __shared__ float red[2][4];
  float a = waveRedSum(s), b2 = waveRedSum(s2);
  int wid = threadIdx.x >> 6;
  if ((threadIdx.x & 63) == 0) { red[0][wid] = a; red[1][wid] = b2; }
  __syncthreads();
  s  = red[0][0] + red[0][1] + red[0][2] + red[0][3];
  s2 = red[1][0] + red[1][1] + red[1][2] + red[1][3];
  float mean = s * (1.f / CC);
  float var  = s2 * (1.f / CC) - mean * mean;
  float inv  = rsqrtf(var + 1e-5f);
  float* orow = out + (size_t)m * CC;
  for (int c = threadIdx.x; c < CC; c += 256)
    orow[c] = (row[c] - mean) * inv * w[c] + bvec[c];
}

// ---------------- final LN + head ----------------
__global__ __launch_bounds__(256)
void head_kernel(const float* __restrict__ x, const float* __restrict__ w,
                 const float* __restrict__ bvec, const float* __restrict__ hw,
                 float* __restrict__ out)
{
  int m = blockIdx.x;
  const float* row = x + (size_t)m * CC;
  float s = 0.f, s2 = 0.f;
  for (int c = threadIdx.x; c < CC; c += 256) { float v = row[c]; s += v; s2 += v * v; }
  __shared__ float red[2][4];
  float a = waveRedSum(s), b2 = waveRedSum(s2);
  int wid = threadIdx.x >> 6;
  if ((threadIdx.x & 63) == 0) { red[0][wid] = a; red[1][wid] = b2; }
  __syncthreads();
  s  = red[0][0] + red[0][1] + red[0][2] + red[0][3];
  s2 = red[1][0] + red[1][1] + red[1][2] + red[1][3];
  float mean = s * (1.f / CC);
  float var  = s2 * (1.f / CC) - mean * mean;
  float inv  = rsqrtf(var + 1e-5f);
  float p = 0.f;
  for (int c = threadIdx.x; c < CC; c += 256)
    p += ((row[c] - mean) * inv * w[c] + bvec[c]) * hw[c];
  p = waveRedSum(p);
  __shared__ float red2[4];
  if ((threadIdx.x & 63) == 0) red2[wid] = p;
  __syncthreads();
  if (threadIdx.x == 0) out[m] = red2[0] + red2[1] + red2[2] + red2[3];
}

// ---------------- fused LN + 6-way token-shift mix (time-mix entry) ----------------
__global__ __launch_bounds__(256)
void lnmix6_kernel(const float* __restrict__ x, const float* __restrict__ w,
                   const float* __restrict__ bvec,
                   const float* __restrict__ cr, const float* __restrict__ cw,
                   const float* __restrict__ ck, const float* __restrict__ cv,
                   const float* __restrict__ ca, const float* __restrict__ cg,
                   __hip_bfloat16* __restrict__ outr, __hip_bfloat16* __restrict__ outw,
                   __hip_bfloat16* __restrict__ outk, __hip_bfloat16* __restrict__ outv,
                   __hip_bfloat16* __restrict__ outa, __hip_bfloat16* __restrict__ outg)
{
  int m = blockIdx.x;
  int t = m % TT;
  const float* row  = x + (size_t)m * CC;
  const float* prow = row - CC;
  float s = 0.f, s2 = 0.f, sp = 0.f, sp2 = 0.f;
  for (int c = threadIdx.x; c < CC; c += 256) {
    float xv = row[c]; s += xv; s2 += xv * xv;
    if (t > 0) { float pv = prow[c]; sp += pv; sp2 += pv * pv; }
  }
  float a0 = waveRedSum(s), a1 = waveRedSum(s2), a2 = waveRedSum(sp), a3 = waveRedSum(sp2);
  __shared__ float red[4][4];
  int wid = threadIdx.x >> 6;
  if ((threadIdx.x & 63) == 0) { red[0][wid]=a0; red[1][wid]=a1; red[2][wid]=a2; red[3][wid]=a3; }
  __syncthreads();
  s   = red[0][0]+red[0][1]+red[0][2]+red[0][3];
  s2  = red[1][0]+red[1][1]+red[1][2]+red[1][3];
  sp  = red[2][0]+red[2][1]+red[2][2]+red[2][3];
  sp2 = red[3][0]+red[3][1]+red[3][2]+red[3][3];
  float mean = s * (1.f / CC);
  float inv  = rsqrtf(s2 * (1.f / CC) - mean * mean + 1e-5f);
  float meanp = sp * (1.f / CC);
  float invp  = rsqrtf(sp2 * (1.f / CC) - meanp * meanp + 1e-5f);
  for (int c = threadIdx.x; c < CC; c += 256) {
    float xnv = (row[c] - mean) * inv * w[c] + bvec[c];
    float xpv = (t > 0) ? (prow[c] - meanp) * invp * w[c] + bvec[c] : 0.f;
    float d = xpv - xnv;
    size_t off = (size_t)m * CC + c;
    outr[off] = __float2bfloat16(fmaf(d, cr[c], xnv));
    outw[off] = __float2bfloat16(fmaf(d, cw[c], xnv));
    outk[off] = __float2bfloat16(fmaf(d, ck[c], xnv));
    outv[off] = __float2bfloat16(fmaf(d, cv[c], xnv));
    outa[off] = __float2bfloat16(fmaf(d, ca[c], xnv));
    outg[off] = __float2bfloat16(fmaf(d, cg[c], xnv));
  }
}

// ---------------- fused LN + single mix (channel-mix entry) ----------------
__global__ __launch_bounds__(256)
void lnmixc_kernel(const float* __restrict__ x, const float* __restrict__ w,
                   const float* __restrict__ bvec, const float* __restrict__ coef,
                   __hip_bfloat16* __restrict__ outb)
{
  int m = blockIdx.x;
  int t = m % TT;
  const float* row  = x + (size_t)m * CC;
  const float* prow = row - CC;
  float s = 0.f, s2 = 0.f, sp = 0.f, sp2 = 0.f;
  for (int c = threadIdx.x; c < CC; c += 256) {
    float xv = row[c]; s += xv; s2 += xv * xv;
    if (t > 0) { float pv = prow[c]; sp += pv; sp2 += pv * pv; }
  }
  float a0 = waveRedSum(s), a1 = waveRedSum(s2), a2 = waveRedSum(sp), a3 = waveRedSum(sp2);
  __shared__ float red[4][4];
  int wid = threadIdx.x >> 6;
  if ((threadIdx.x & 63) == 0) { red[0][wid]=a0; red[1][wid]=a1; red[2][wid]=a2; red[3][wid]=a3; }
  __syncthreads();
  s   = red[0][0]+red[0][1]+red[0][2]+red[0][3];
  s2  = red[1][0]+red[1][1]+red[1][2]+red[1][3];
  sp  = red[2][0]+red[2][1]+red[2][2]+red[2][3];
  sp2 = red[3][0]+red[3][1]+red[3][2]+red[3][3];
  float mean = s * (1.f / CC);
  float inv  = rsqrtf(s2 * (1.f / CC) - mean * mean + 1e-5f);
  float meanp = sp * (1.f / CC);
  float invp  = rsqrtf(sp2 * (1.f / CC) - meanp * meanp + 1e-5f);
  for (int c = threadIdx.x; c < CC; c += 256) {
    float xnv = (row[c] - mean) * inv * w[c] + bvec[c];
    float xpv = (t > 0) ? (prow[c] - meanp) * invp * w[c] + bvec[c] : 0.f;
    outb[(size_t)m * CC + c] = __float2bfloat16(fmaf(xpv - xnv, coef[c], xnv));
  }
}

// ---------------- convert + transpose body ----------------
__device__ __forceinline__ void convT_body(const float* __restrict__ W,
                                           __hip_bfloat16* __restrict__ Wt,
                                           int K, int N, int KP, int NP,
                                           int bx, int by)
{
  __shared__ float tile[32][33];
  int bn = bx * 32, bk = by * 32;
  int tx = threadIdx.x & 31, ty = threadIdx.x >> 5;
#pragma unroll
  for (int i = 0; i < 4; i++) {
    int k = bk + ty + i * 8, n = bn + tx;
    tile[ty + i * 8][tx] = (k < K && n < N) ? W[(size_t)k * N + n] : 0.f;
  }
  __syncthreads();
#pragma unroll
  for (int i = 0; i < 4; i++) {
    int n = bn + ty + i * 8, k = bk + tx;
    if (n < NP && k < KP)
      Wt[(size_t)n * KP + k] = __float2bfloat16(tile[tx][ty + i * 8]);
  }
}

// all small per-layer weights in one launch, grid (28,28,12)
__global__ __launch_bounds__(256)
void convT_batch(const float* Wr, const float* Wk, const float* Wv, const float* Wo,
                 const float* a1, const float* a2, const float* v1, const float* v2,
                 const float* g1, const float* g2, const float* w1, const float* w2,
                 __hip_bfloat16* WrT, __hip_bfloat16* WkT, __hip_bfloat16* WvT,
                 __hip_bfloat16* WoT, __hip_bfloat16* a1T, __hip_bfloat16* a2T,
                 __hip_bfloat16* v1T, __hip_bfloat16* v2T, __hip_bfloat16* g1T,
                 __hip_bfloat16* g2T, __hip_bfloat16* w1T, __hip_bfloat16* w2T)
{
  const float* W; __hip_bfloat16* Wt; int K, N, KP, NP;
  switch (blockIdx.z) {
    case 0:  W = Wr; Wt = WrT; K = CC;  N = CC;  KP = CC;  NP = CC;  break;
    case 1:  W = Wk; Wt = WkT; K = CC;  N = CC;  KP = CC;  NP = CC;  break;
    case 2:  W = Wv; Wt = WvT; K = CC;  N = CC;  KP = CC;  NP = CC;  break;
    case 3:  W = Wo; Wt = WoT; K = CC;  N = CC;  KP = CC;  NP = CC;  break;
    case 4:  W = a1; Wt = a1T; K = CC;  N = DD;  KP = CC;  NP = DD;  break;
    case 5:  W = a2; Wt = a2T; K = DD;  N = CC;  KP = DD;  NP = CC;  break;
    case 6:  W = v1; Wt = v1T; K = CC;  N = DD;  KP = CC;  NP = DD;  break;
    case 7:  W = v2; Wt = v2T; K = DD;  N = CC;  KP = DD;  NP = CC;  break;
    case 8:  W = g1; Wt = g1T; K = CC;  N = DGG; KP = CC;  NP = 192; break;
    case 9:  W = g2; Wt = g2T; K = DGG; N = CC;  KP = 192; NP = CC;  break;
    case 10: W = w1; Wt = w1T; K = CC;  N = DD;  KP = CC;  NP = DD;  break;
    default: W = w2; Wt = w2T; K = DD;  N = CC;  KP = DD;  NP = CC;  break;
  }
  if ((int)blockIdx.x * 32 >= NP || (int)blockIdx.y * 32 >= KP) return;
  convT_body(W, Wt, K, N, KP, NP, blockIdx.x, blockIdx.y);
}

// the two big channel-mix weights, grid (112, 28, 2)
__global__ __launch_bounds__(256)
void convT_big(const float* fk, const float* fv,
               __hip_bfloat16* fkT, __hip_bfloat16* fvT)
{
  if (blockIdx.z == 0)
    convT_body(fk, fkT, CC, FF4, CC, FF4, blockIdx.x, blockIdx.y);
  else
    convT_body(fv, fvT, FF4, CC, FF4, CC, blockIdx.y, blockIdx.x);
}

// ---------------- bf16 MFMA GEMM body: C[M][N] = A[M][K] * Bt[N][K]^T ----------------
// epi (runtime): 0 store f32, 1 add f32, 2 relu^2->bf16, 3 store bf16,
//   4 sigmoid->bf16 (0 past Nreal), 5 sigmoid(bias+v)->f32, 6 v-gate->f32,
//   7 decay(bias)->f32, 8 tanh->bf16
template<int BN>
__device__ __forceinline__ void gemm_body(const __hip_bfloat16* __restrict__ A,
    const __hip_bfloat16* __restrict__ Bt, float* __restrict__ C,
    __hip_bfloat16* __restrict__ Cbf, int N, int K, const float* __restrict__ bias,
    const float* __restrict__ aux0, const float* __restrict__ aux1, int Nreal,
    int bx, int by, int epi)
{
  constexpr int WN = BN / 64;
  constexpr int WM = 4 / WN;
  constexpr int ROWS = 128 / WM;
  constexpr int MI = ROWS / 16;
  __shared__ __align__(16) ushort As[128 * 64];
  __shared__ __align__(16) ushort Bs[BN * 64];
  int tid = threadIdx.x;
  int lane = tid & 63, wave = tid >> 6;
  int wm, wn;
  if constexpr (WN == 2) { wm = wave >> 1; wn = wave & 1; } else { wm = wave; wn = 0; }
  int fl = lane & 15, fh = lane >> 4;
  int row0 = by * 128, col0 = bx * BN;

  const char* Abase = (const char*)A + (size_t)row0 * (size_t)(K * 2);
  const char* Bbase = (const char*)Bt + (size_t)col0 * (size_t)(K * 2);
  char* AsB = (char*)As;
  char* BsB = (char*)Bs;

  f32x4 acc[MI][4];
#pragma unroll
  for (int mi = 0; mi < MI; mi++)
#pragma unroll
    for (int ni = 0; ni < 4; ni++)
      acc[mi][ni] = (f32x4){0.f, 0.f, 0.f, 0.f};

  int srow = tid >> 3;
  int scol = (tid & 7) << 4;
  int ldsw = (wave << 10);

  for (int k0 = 0; k0 < K; k0 += 64) {
#pragma unroll
    for (int it = 0; it < 4; ++it) {
      int r = it * 32 + srow;
      int cbs = scol ^ ((r & 7) << 4);
      size_t goff = (size_t)r * (size_t)(K * 2) + (size_t)(k0 * 2) + cbs;
      gload_lds16(Abase + goff, AsB + (it << 12) + ldsw);
      if constexpr (BN == 128) {
        gload_lds16(Bbase + goff, BsB + (it << 12) + ldsw);
      } else {
        if (it < 2) gload_lds16(Bbase + goff, BsB + (it << 12) + ldsw);
      }
    }
    __syncthreads();
#pragma unroll
    for (int kk = 0; kk < 2; ++kk) {
      bf16x8 af[MI], bfr[4];
      int kb_ = kk * 64 + (fh << 4);
#pragma unroll
      for (int mi = 0; mi < MI; mi++) {
        int r = wm * ROWS + mi * 16 + fl;
        af[mi] = *(const bf16x8*)(AsB + r * 128 + (kb_ ^ ((r & 7) << 4)));
      }
#pragma unroll
      for (int ni = 0; ni < 4; ni++) {
        int r = wn * 64 + ni * 16 + fl;
        bfr[ni] = *(const bf16x8*)(BsB + r * 128 + (kb_ ^ ((r & 7) << 4)));
      }
#pragma unroll
      for (int mi = 0; mi < MI; mi++)
#pragma unroll
        for (int ni = 0; ni < 4; ni++)
          acc[mi][ni] = __builtin_amdgcn_mfma_f32_16x16x32_bf16(af[mi], bfr[ni], acc[mi][ni], 0, 0, 0);
    }
    __syncthreads();
  }

#pragma unroll
  for (int mi = 0; mi < MI; mi++) {
    int crow0 = row0 + wm * ROWS + mi * 16 + fh * 4;
#pragma unroll
    for (int ni = 0; ni < 4; ni++) {
      int ccol = col0 + wn * 64 + ni * 16 + fl;
#pragma unroll
      for (int e = 0; e < 4; e++) {
        size_t off = (size_t)(crow0 + e) * N + ccol;
        float v = acc[mi][ni][e];
        switch (epi) {
          case 0: C[off] = v; break;
          case 1: C[off] += v; break;
          case 2: { float t = fmaxf(v, 0.f); Cbf[off] = __float2bfloat16(t * t); } break;
          case 3: Cbf[off] = __float2bfloat16(v); break;
          case 4: { float sv = (ccol < Nreal) ? sigmoidf_(v) : 0.f;
                    Cbf[off] = __float2bfloat16(sv); } break;
          case 5: C[off] = sigmoidf_(bias[ccol] + v); break;
          case 6: { float sg = sigmoidf_(bias[ccol] + v);
                    float vv = aux0[off];
                    C[off] = vv + (aux1[off] - vv) * sg; } break;
          case 7: { float z_ = bias[ccol] + v;
                    float sp_ = fmaxf(-z_, 0.f) + log1pf(expf(-fabsf(z_)));
                    C[off] = expf(-expf(-sp_ - 0.5f)); } break;
          default: Cbf[off] = __float2bfloat16(tanhf(v)); break;  // 8
        }
      }
    }
  }
}

// generic single-GEMM kernel with runtime epilogue
template<int BN>
__global__ __launch_bounds__(256)
void gemm_ep(const __hip_bfloat16* __restrict__ A, const __hip_bfloat16* __restrict__ Bt,
             float* __restrict__ C, __hip_bfloat16* __restrict__ Cbf,
             int N, int K, const float* __restrict__ bias,
             const float* __restrict__ aux0, const float* __restrict__ aux1,
             int Nreal, int epi)
{
  gemm_body<BN>(A, Bt, C, Cbf, N, K, bias, aux0, aux1, Nreal, blockIdx.x, blockIdx.y, epi);
}

// batched r/k/v projection, grid (7,16,3)
__global__ __launch_bounds__(256)
void gemm_rkv(const __hip_bfloat16* Ar, const __hip_bfloat16* Ak, const __hip_bfloat16* Av,
              const __hip_bfloat16* Br, const __hip_bfloat16* Bk, const __hip_bfloat16* Bv,
              float* Cr, float* Ck, float* Cv)
{
  const __hip_bfloat16* A; const __hip_bfloat16* Bt; float* C;
  if (blockIdx.z == 0)      { A = Ar; Bt = Br; C = Cr; }
  else if (blockIdx.z == 1) { A = Ak; Bt = Bk; C = Ck; }
  else                      { A = Av; Bt = Bv; C = Cv; }
  gemm_body<128>(A, Bt, C, nullptr, CC, CC, nullptr, nullptr, nullptr, CC,
                 blockIdx.x, blockIdx.y, 0);
}

// batched LoRA stage-1: grid (6,16). z: 0 w1(tanh), 1 a1, 2 v1, 3..5 g1 tiles
__global__ __launch_bounds__(256)
void lora1_batch(const __hip_bfloat16* mixw, const __hip_bfloat16* mixa,
                 const __hip_bfloat16* mixv, const __hip_bfloat16* mixg,
                 const __hip_bfloat16* w1T, const __hip_bfloat16* a1T,
                 const __hip_bfloat16* v1T, const __hip_bfloat16* g1T,
                 __hip_bfloat16* t64w, __hip_bfloat16* t64a,
                 __hip_bfloat16* t64v, __hip_bfloat16* t160)
{
  int z = blockIdx.x;
  const __hip_bfloat16 *A, *Bt; __hip_bfloat16* Cbf; int N, epi, bx, Nreal;
  if (z == 0)      { A = mixw; Bt = w1T; Cbf = t64w; N = 64;  epi = 8; bx = 0; Nreal = 64; }
  else if (z == 1) { A = mixa; Bt = a1T; Cbf = t64a; N = 64;  epi = 3; bx = 0; Nreal = 64; }
  else if (z == 2) { A = mixv; Bt = v1T; Cbf = t64v; N = 64;  epi = 3; bx = 0; Nreal = 64; }
  else             { A = mixg; Bt = g1T; Cbf = t160; N = 192; epi = 4; bx = z - 3; Nreal = DGG; }
  gemm_body<64>(A, Bt, nullptr, Cbf, N, CC, nullptr, nullptr, nullptr, Nreal,
                bx, blockIdx.y, epi);
}

// batched LoRA stage-2: grid (7,16,nz). z: 0 w2(decay), 1 a2(sig), 2 g2, 3 v2(gate)
__global__ __launch_bounds__(256)
void lora2_batch(const __hip_bfloat16* t64w, const __hip_bfloat16* t64a,
                 const __hip_bfloat16* t160, const __hip_bfloat16* t64v,
                 const __hip_bfloat16* w2T, const __hip_bfloat16* a2T,
                 const __hip_bfloat16* g2T, const __hip_bfloat16* v2T,
                 float* dcy, float* ab, float* gb, float* vb,
                 const float* w0l, const float* a0l, const float* v0l,
                 const float* vfirst)
{
  int z = blockIdx.z;
  const __hip_bfloat16 *A, *Bt; float* C; const float* bias;
  const float *ax0, *ax1; int K, epi;
  if (z == 0)      { A = t64w; Bt = w2T; C = dcy; bias = w0l; K = 64;  epi = 7; ax0 = nullptr; ax1 = nullptr; }
  else if (z == 1) { A = t64a; Bt = a2T; C = ab;  bias = a0l; K = 64;  epi = 5; ax0 = nullptr; ax1 = nullptr; }
  else if (z == 2) { A = t160; Bt = g2T; C = gb;  bias = nullptr; K = 192; epi = 0; ax0 = nullptr; ax1 = nullptr; }
  else             { A = t64v; Bt = v2T; C = vb;  bias = v0l; K = 64;  epi = 6; ax0 = vb; ax1 = vfirst; }
  gemm_body<128>(A, Bt, C, nullptr, CC, K, bias, ax0, ax1, CC, blockIdx.x, blockIdx.y, epi);
}

// ---------------- prep: kk norm, a_in=-kk, b_in=kk*a, k gating ----------------
__global__ __launch_bounds__(896)
void prep_kernel(const float* __restrict__ k_in, const float* __restrict__ a,
                 const float* __restrict__ k_k, const float* __restrict__ k_a,
                 float* __restrict__ kout, float* __restrict__ ain, float* __restrict__ bin)
{
  int m = blockIdx.x;
  int c = threadIdx.x;
  size_t off = (size_t)m * CC + c;
  float kv = k_in[off];
  float av = a[off];
  float kkv = kv * k_k[c];
  float ss = waveRedSum(kkv * kkv);
  float norm = sqrtf(ss);
  float kkn = kkv / fmaxf(norm, 1e-12f);
  ain[off] = -kkn;
  bin[off] = kkn * av;
  kout[off] = kv * (1.f + (av - 1.f) * k_a[c]);
}

// ================= chunk-parallel RWKV7 scan =================
// Phase 1 (896 blocks): chunk-local zero-state scan (Z,y0) + P product + u.
__global__ __launch_bounds__(256)
void scanp1_kernel(const float* __restrict__ rp, const float* __restrict__ dp,
                   const float* __restrict__ kp, const float* __restrict__ vp,
                   const float* __restrict__ ap, const float* __restrict__ bp_,
                   float* __restrict__ yp, float* __restrict__ ubuf,
                   float* __restrict__ Pc, float* __restrict__ Zc)
{
  int bid = blockIdx.x;
  int bh = bid >> 4, c = bid & 15;
  int b = bh / HH, h = bh - b * HH;
  int tid = threadIdx.x, lane = tid & 63, w = tid >> 6;
  int w16 = w * 16;
  __shared__ __align__(16) float ring[RD][6][64];   // 0 r, 1 d, 2 k, 3 a, 4 b, 5 v
  __shared__ float sa_part[2][4][64];
  __shared__ float pa_part[2][4][64];
  __shared__ float y_part[2][4][64];
  __shared__ float u_part[2][4][64];

  float s[16], p[16];
#pragma unroll
  for (int jj = 0; jj < 16; jj++) {
    s[jj] = 0.f;
    p[jj] = (lane == w16 + jj) ? 1.f : 0.f;
  }
  size_t base = ((size_t)b * TT + (size_t)c * CL) * CC + (size_t)h * NN + lane;

  const float* gA = nullptr; const float* gB = nullptr; int slA = 0, slB = 0;
  if (w == 1)      { gA = rp;  slA = 0; gB = dp;  slB = 1; }
  else if (w == 2) { gA = kp;  slA = 2; gB = vp;  slB = 5; }
  else if (w == 3) { gA = ap;  slA = 3; gB = bp_; slB = 4; }

  if (w) {
    for (int t0 = 0; t0 < RD; t0++) {
      gload_lds4(gA + base + (size_t)t0 * CC, &ring[t0][slA][0]);
      gload_lds4(gB + base + (size_t)t0 * CC, &ring[t0][slB][0]);
    }
    asm volatile("s_waitcnt vmcnt(0)" ::: "memory");
  }
  __builtin_amdgcn_s_barrier();
  __builtin_amdgcn_sched_barrier(0);

  for (int t = 0; t < CL; ++t) {
    int Pp = t & 1, Qp = Pp ^ 1;
    int slot = t & (RD - 1);
    float av[16], dv[16], kv[16], bv[16], rv[16];
#pragma unroll
    for (int q = 0; q < 4; q++) {
      *(float4*)&av[q * 4] = *(const float4*)&ring[slot][3][w16 + q * 4];
      *(float4*)&dv[q * 4] = *(const float4*)&ring[slot][1][w16 + q * 4];
      *(float4*)&kv[q * 4] = *(const float4*)&ring[slot][2][w16 + q * 4];
      *(float4*)&bv[q * 4] = *(const float4*)&ring[slot][4][w16 + q * 4];
      *(float4*)&rv[q * 4] = *(const float4*)&ring[slot][0][w16 + q * 4];
    }
    float vi = ring[slot][5][lane];
    float sp0 = 0.f, sp1 = 0.f, pp0 = 0.f, pp1 = 0.f;
#pragma unroll
    for (int jj = 0; jj < 8; jj++) {
      sp0 = fmaf(s[jj],     av[jj],     sp0);
      sp1 = fmaf(s[jj + 8], av[jj + 8], sp1);
      pp0 = fmaf(p[jj],     av[jj],     pp0);
      pp1 = fmaf(p[jj + 8], av[jj + 8], pp1);
    }
    sa_part[Pp][w][lane] = sp0 + sp1;
    pa_part[Pp][w][lane] = pp0 + pp1;
    if (w) { asm volatile("s_waitcnt vmcnt(12)" ::: "memory"); }
    asm volatile("s_waitcnt lgkmcnt(0)" ::: "memory");
    __builtin_amdgcn_s_barrier();
    __builtin_amdgcn_sched_barrier(0);
    if (w && t + RD < CL) {
      gload_lds4(gA + base + (size_t)(t + RD) * CC, &ring[slot][slA][0]);
      gload_lds4(gB + base + (size_t)(t + RD) * CC, &ring[slot][slB][0]);
    }
    if (w == 0 && t > 0) {
      float yo = (y_part[Qp][0][lane] + y_part[Qp][1][lane])
               + (y_part[Qp][2][lane] + y_part[Qp][3][lane]);
      yp[base + (size_t)(t - 1) * CC] = yo;
      float uo = (u_part[Qp][0][lane] + u_part[Qp][1][lane])
               + (u_part[Qp][2][lane] + u_part[Qp][3][lane]);
      ubuf[((size_t)bid * CL + (t - 1)) * 64 + lane] = uo;
    }
    float sa = (sa_part[Pp][0][lane] + sa_part[Pp][1][lane])
             + (sa_part[Pp][2][lane] + sa_part[Pp][3][lane]);
    float pa = (pa_part[Pp][0][lane] + pa_part[Pp][1][lane])
             + (pa_part[Pp][2][lane] + pa_part[Pp][3][lane]);
    float y0 = 0.f, y1 = 0.f, u0 = 0.f, u1 = 0.f;
#pragma unroll
    for (int jj = 0; jj < 8; jj++) {
      s[jj]     = fmaf(s[jj],     dv[jj],     fmaf(sa, bv[jj],     vi * kv[jj]));
      y0 = fmaf(s[jj], rv[jj], y0);
      s[jj + 8] = fmaf(s[jj + 8], dv[jj + 8], fmaf(sa, bv[jj + 8], vi * kv[jj + 8]));
      y1 = fmaf(s[jj + 8], rv[jj + 8], y1);
      p[jj]     = fmaf(p[jj],     dv[jj],     pa * bv[jj]);
      u0 = fmaf(p[jj], rv[jj], u0);
      p[jj + 8] = fmaf(p[jj + 8], dv[jj + 8], pa * bv[jj + 8]);
      u1 = fmaf(p[jj + 8], rv[jj + 8], u1);
    }
    y_part[Pp][w][lane] = y0 + y1;
    u_part[Pp][w][lane] = u0 + u1;
  }

  asm volatile("s_waitcnt lgkmcnt(0)" ::: "memory");
  __builtin_amdgcn_s_barrier();
  if (w == 0) {
    int Pl = (CL - 1) & 1;
    float yo = (y_part[Pl][0][lane] + y_part[Pl][1][lane])
             + (y_part[Pl][2][lane] + y_part[Pl][3][lane]);
    yp[base + (size_t)(CL - 1) * CC] = yo;
    float uo = (u_part[Pl][0][lane] + u_part[Pl][1][lane])
             + (u_part[Pl][2][lane] + u_part[Pl][3][lane]);
    ubuf[((size_t)bid * CL + (CL - 1)) * 64 + lane] = uo;
  }
  float* zp = Zc + ((size_t)bid * 64 + lane) * 64 + w16;
  float* pq = Pc + ((size_t)bid * 64 + lane) * 64 + w16;
#pragma unroll
  for (int q = 0; q < 4; q++) {
    *(float4*)&zp[q * 4] = make_float4(s[q*4], s[q*4+1], s[q*4+2], s[q*4+3]);
    *(float4*)&pq[q * 4] = make_float4(p[q*4], p[q*4+1], p[q*4+2], p[q*4+3]);
  }
}

// Phase 2 (56 blocks): Sin[c] = S; S = S*P_c + Z_c, sequential over c
__global__ __launch_bounds__(256)
void scanp2_kernel(const float* __restrict__ Pc, const float* __restrict__ Zc,
                   float* __restrict__ Sin)
{
  int bh = blockIdx.x;
  int tid = threadIdx.x, i = tid & 63, jg = tid >> 6, j0 = jg * 16;
  __shared__ float S_lds[64][65];
  __shared__ __align__(16) float P_lds[64][64];
#pragma unroll
  for (int jj = 0; jj < 16; jj++) S_lds[i][j0 + jj] = 0.f;

  for (int c = 0; c < NCH; c++) {
    size_t bidc = (size_t)(bh * NCH + c);
    {
      const float4* src = (const float4*)(Pc + bidc * 4096 + (size_t)tid * 16);
      float4* dst = (float4*)(&P_lds[0][0] + tid * 16);
      dst[0] = src[0]; dst[1] = src[1]; dst[2] = src[2]; dst[3] = src[3];
    }
    __syncthreads();
    float sv[16];
#pragma unroll
    for (int jj = 0; jj < 16; jj++) sv[jj] = S_lds[i][j0 + jj];
    {
      float4* sp_ = (float4*)(Sin + bidc * 4096 + (size_t)i * 64 + j0);
#pragma unroll
      for (int q = 0; q < 4; q++)
        sp_[q] = make_float4(sv[q*4], sv[q*4+1], sv[q*4+2], sv[q*4+3]);
    }
    float nv[16];
#pragma unroll
    for (int jj = 0; jj < 16; jj++) nv[jj] = 0.f;
    for (int m = 0; m < 64; m++) {
      float sm = S_lds[i][m];
#pragma unroll
      for (int jj = 0; jj < 16; jj++)
        nv[jj] = fmaf(sm, P_lds[m][j0 + jj], nv[jj]);
    }
    {
      const float4* zp = (const float4*)(Zc + bidc * 4096 + (size_t)i * 64 + j0);
#pragma unroll
      for (int q = 0; q < 4; q++) {
        float4 z4 = zp[q];
        nv[q*4+0] += z4.x; nv[q*4+1] += z4.y; nv[q*4+2] += z4.z; nv[q*4+3] += z4.w;
      }
    }
    __syncthreads();
#pragma unroll
    for (int jj = 0; jj < 16; jj++) S_lds[i][j0 + jj] = nv[jj];
  }
}

// Phase 3 + groupnorm + rk*v + gate fused (896 blocks)
__global__ __launch_bounds__(256)
void scanp3gn_kernel(const float* __restrict__ Sin, const float* __restrict__ ubuf,
                     const float* __restrict__ y0p,
                     const float* __restrict__ rp, const float* __restrict__ kp,
                     const float* __restrict__ vp, const float* __restrict__ gp,
                     const float* __restrict__ lnxw, const float* __restrict__ lnxb,
                     const float* __restrict__ rkco,
                     __hip_bfloat16* __restrict__ yout)
{
  int bid = blockIdx.x;
  int bh = bid >> 4, c = bid & 15;
  int b = bh / HH, h = bh - b * HH;
  int tid = threadIdx.x, i = tid & 63, wv = tid >> 6;
  __shared__ float S_lds[64][65];
  __shared__ __align__(16) float U_lds[CL][64];
  {
    int r = tid >> 2, q = tid & 3;
    const float* src = Sin + (size_t)bid * 4096 + (size_t)r * 64 + q * 16;
#pragma unroll
    for (int jj = 0; jj < 16; jj++) S_lds[r][q * 16 + jj] = src[jj];
  }
  {
    int r = tid >> 3, q = tid & 7;
    const float4* us = (const float4*)(ubuf + (size_t)bid * (CL * 64) + (size_t)r * 64 + q * 8);
    float4* ud = (float4*)(&U_lds[r][q * 8]);
    ud[0] = us[0]; ud[1] = us[1];
  }
  __syncthreads();
  float sreg[64];
#pragma unroll
  for (int m = 0; m < 64; m++) sreg[m] = S_lds[i][m];
  int ch = h * NN + i;
  float lw = lnxw[ch], lb = lnxb[ch], rkc = rkco[ch];
  size_t rowbase = ((size_t)b * TT + (size_t)c * CL) * CC + ch;
#pragma unroll 1
  for (int tt = 0; tt < CL / 4; tt++) {
    int t = wv * (CL / 4) + tt;
    size_t off = rowbase + (size_t)t * CC;
    float a0 = 0.f, a1 = 0.f, a2 = 0.f, a3 = 0.f;
#pragma unroll
    for (int m4 = 0; m4 < 16; m4++) {
      float4 uu = *(const float4*)&U_lds[t][m4 * 4];
      a0 = fmaf(sreg[m4*4+0], uu.x, a0);
      a1 = fmaf(sreg[m4*4+1], uu.y, a1);
      a2 = fmaf(sreg[m4*4+2], uu.z, a2);
      a3 = fmaf(sreg[m4*4+3], uu.w, a3);
    }
    float yv = y0p[off] + (a0 + a1) + (a2 + a3);
    float s1 = waveRedSum(yv);
    float s2 = waveRedSum(yv * yv);
    float mean = s1 * (1.f / 64.f);
    float var  = s2 * (1.f / 64.f) - mean * mean;
    float norm = (yv - mean) * rsqrtf(var + 0.00064f);
    float rv = rp[off], kv = kp[off], vv = vp[off], gv = gp[off];
    float rk = waveRedSum(rv * kv * rkc);
    yout[off] = __float2bfloat16((norm * lw + lb + rk * vv) * gv);
  }
}

// ---------------- host ----------------
extern "C" void kernel_launch(void* const* d_in, const int* in_sizes, int n_in,
                              void* d_out, int out_size, void* d_ws, size_t ws_size,
                              hipStream_t stream)
{
  const int*   idx    = (const int*)d_in[0];
  const float* emb    = (const float*)d_in[1];
  const float* ln0_w  = (const float*)d_in[2];
  const float* ln0_b  = (const float*)d_in[3];
  const float* ln1_w  = (const float*)d_in[4];
  const float* ln1_b  = (const float*)d_in[5];
  const float* ln2_w  = (const float*)d_in[6];
  const float* ln2_b  = (const float*)d_in[7];
  const float* x_r    = (const float*)d_in[8];
  const float* x_w    = (const float*)d_in[9];
  const float* x_k    = (const float*)d_in[10];
  const float* x_v    = (const float*)d_in[11];
  const float* x_a    = (const float*)d_in[12];
  const float* x_g    = (const float*)d_in[13];
  const float* w0     = (const float*)d_in[14];
  const float* w1     = (const float*)d_in[15];
  const float* w2     = (const float*)d_in[16];
  const float* a0     = (const float*)d_in[17];
  const float* a1     = (const float*)d_in[18];
  const float* a2     = (const float*)d_in[19];
  const float* v0     = (const float*)d_in[20];
  const float* v1     = (const float*)d_in[21];
  const float* v2     = (const float*)d_in[22];
  const float* g1     = (const float*)d_in[23];
  const float* g2     = (const float*)d_in[24];
  const float* k_k    = (const float*)d_in[25];
  const float* k_a    = (const float*)d_in[26];
  const float* r_k    = (const float*)d_in[27];
  const float* Wr     = (const float*)d_in[28];
  const float* Wk     = (const float*)d_in[29];
  const float* Wv     = (const float*)d_in[30];
  const float* Wo     = (const float*)d_in[31];
  const float* lnx_w  = (const float*)d_in[32];
  const float* lnx_b  = (const float*)d_in[33];
  const float* f_xk   = (const float*)d_in[34];
  const float* f_key  = (const float*)d_in[35];
  const float* f_val  = (const float*)d_in[36];
  const float* lnout_w = (const float*)d_in[37];
  const float* lnout_b = (const float*)d_in[38];
  const float* head_w  = (const float*)d_in[39];
  float* out = (float*)d_out;

  const size_t MC = (size_t)MM * CC;
  const size_t W2 = (size_t)CC * CC;
  float* ws   = (float*)d_ws;
  float* x      = ws;
  float* vfirst = x + MC;
  float* rb     = vfirst + MC;
  float* dcy    = rb + MC;       // rb+dcy contiguous: h_bf alias spans both
  float* kb     = dcy + MC;
  float* vb     = kb + MC;
  float* ab     = vb + MC;
  float* gb     = ab + MC;
  float* ainb   = gb + MC;
  float* binb   = ainb + MC;
  float* yb     = binb + MC;
  float* ubuf   = yb + MC;       // 896*32*64 = MC
  float* Pcb    = ubuf + MC;     // 2*MC
  float* Zcb    = Pcb + 2 * MC;  // 2*MC
  float* Sinb   = Zcb + 2 * MC;  // 2*MC
  float* fend   = Sinb + 2 * MC;

  __hip_bfloat16* mixr_bf = (__hip_bfloat16*)fend;
  __hip_bfloat16* mixw_bf = mixr_bf + MC;
  __hip_bfloat16* mixk_bf = mixw_bf + MC;
  __hip_bfloat16* mixv_bf = mixk_bf + MC;
  __hip_bfloat16* mixa_bf = mixv_bf + MC;
  __hip_bfloat16* mixg_bf = mixa_bf + MC;
  __hip_bfloat16* WrT = mixg_bf + MC;
  __hip_bfloat16* WkT = WrT + W2;
  __hip_bfloat16* WvT = WkT + W2;
  __hip_bfloat16* WoT = WvT + W2;
  __hip_bfloat16* fkT = WoT + W2;                    // [3584][896]
  __hip_bfloat16* fvT = fkT + (size_t)FF4 * CC;      // [896][3584]
  __hip_bfloat16* w1T = fvT + (size_t)FF4 * CC;      // [64][896]
  __hip_bfloat16* a1T = w1T + (size_t)DD * CC;
  __hip_bfloat16* v1T = a1T + (size_t)DD * CC;
  __hip_bfloat16* w2T = v1T + (size_t)DD * CC;       // [896][64]
  __hip_bfloat16* a2T = w2T + (size_t)DD * CC;
  __hip_bfloat16* v2T = a2T + (size_t)DD * CC;
  __hip_bfloat16* g1T = v2T + (size_t)DD * CC;       // [192][896]
  __hip_bfloat16* g2T = g1T + (size_t)192 * CC;      // [896][192]
  __hip_bfloat16* t64w = g2T + (size_t)192 * CC;     // [2048][64]
  __hip_bfloat16* t64a = t64w + (size_t)MM * 64;
  __hip_bfloat16* t64v = t64a + (size_t)MM * 64;
  __hip_bfloat16* t160 = t64v + (size_t)MM * 64;     // [2048][192]
  // aliases on dead f32 regions
  __hip_bfloat16* h_bf  = (__hip_bfloat16*)rb;       // [2048][3584] over rb+dcy
  __hip_bfloat16* yg_bf = (__hip_bfloat16*)ab;       // [2048][896]

  dim3 blk(256);

  ln_kernel<<<MM, blk, 0, stream>>>(emb, idx, ln0_w, ln0_b, x);

  for (int l = 0; l < 2; l++) {
    const float* Wr_l = Wr + (size_t)l * W2;
    const float* Wk_l = Wk + (size_t)l * W2;
    const float* Wv_l = Wv + (size_t)l * W2;
    const float* Wo_l = Wo + (size_t)l * W2;
    const float* w1_l = w1 + (size_t)l * CC * DD;
    const float* w2_l = w2 + (size_t)l * DD * CC;
    const float* a1_l = a1 + (size_t)l * CC * DD;
    const float* a2_l = a2 + (size_t)l * DD * CC;
    const float* v1_l = v1 + (size_t)l * CC * DD;
    const float* v2_l = v2 + (size_t)l * DD * CC;
    const float* g1_l = g1 + (size_t)l * CC * DGG;
    const float* g2_l = g2 + (size_t)l * DGG * CC;
    const float* fk_l = f_key + (size_t)l * CC * FF4;
    const float* fv_l = f_val + (size_t)l * FF4 * CC;

    convT_batch<<<dim3(28, 28, 12), blk, 0, stream>>>(
        Wr_l, Wk_l, Wv_l, Wo_l, a1_l, a2_l, v1_l, v2_l, g1_l, g2_l, w1_l, w2_l,
        WrT, WkT, WvT, WoT, a1T, a2T, v1T, v2T, g1T, g2T, w1T, w2T);
    convT_big<<<dim3(112, 28, 2), blk, 0, stream>>>(fk_l, fv_l, fkT, fvT);

    lnmix6_kernel<<<MM, blk, 0, stream>>>(x, ln1_w + l * CC, ln1_b + l * CC,
        x_r + l * CC, x_w + l * CC, x_k + l * CC, x_v + l * CC, x_a + l * CC, x_g + l * CC,
        mixr_bf, mixw_bf, mixk_bf, mixv_bf, mixa_bf, mixg_bf);

    // r,k,v projections
    gemm_rkv<<<dim3(7, 16, 3), blk, 0, stream>>>(mixr_bf, mixk_bf, mixv_bf,
                                                 WrT, WkT, WvT, rb, kb, vb);
    if (l == 0)
      hipMemcpyAsync(vfirst, vb, MC * sizeof(float), hipMemcpyDeviceToDevice, stream);

    // LoRA stage 1 (w tanh, a, v, g sigmoid) and stage 2 (decay, sigmoid, g, v-gate)
    lora1_batch<<<dim3(6, 16), blk, 0, stream>>>(mixw_bf, mixa_bf, mixv_bf, mixg_bf,
                                                 w1T, a1T, v1T, g1T,
                                                 t64w, t64a, t64v, t160);
    lora2_batch<<<dim3(7, 16, l == 0 ? 3 : 4), blk, 0, stream>>>(
        t64w, t64a, t160, t64v, w2T, a2T, g2T, v2T,
        dcy, ab, gb, vb, w0 + l * CC, a0 + l * CC, v0 + l * CC, vfirst);

    // prep + chunked scan (+fused gn)
    prep_kernel<<<MM, dim3(896), 0, stream>>>(kb, ab, k_k + l * CC, k_a + l * CC,
                                              kb, ainb, binb);
    scanp1_kernel<<<BB * HH * NCH, blk, 0, stream>>>(rb, dcy, kb, vb, ainb, binb,
                                                     yb, ubuf, Pcb, Zcb);
    scanp2_kernel<<<BB * HH, blk, 0, stream>>>(Pcb, Zcb, Sinb);
    scanp3gn_kernel<<<BB * HH * NCH, blk, 0, stream>>>(Sinb, ubuf, yb, rb, kb, vb, gb,
        lnx_w + l * CC, lnx_b + l * CC, r_k + (size_t)l * CC, yg_bf);

    // x += (y*g) @ Wo   (BN=64 -> 224 blocks)
    gemm_ep<64><<<dim3(14, 16), blk, 0, stream>>>(yg_bf, WoT, x, nullptr, CC, CC,
                                                  nullptr, nullptr, nullptr, CC, 1);

    // ---- channel mix ----
    lnmixc_kernel<<<MM, blk, 0, stream>>>(x, ln2_w + l * CC, ln2_b + l * CC,
                                          f_xk + l * CC, mixr_bf);
    gemm_ep<128><<<dim3(28, 16), blk, 0, stream>>>(mixr_bf, fkT, nullptr, h_bf, FF4, CC,
                                                   nullptr, nullptr, nullptr, FF4, 2);
    gemm_ep<64><<<dim3(14, 16), blk, 0, stream>>>(h_bf, fvT, x, nullptr, CC, FF4,
                                                  nullptr, nullptr, nullptr, CC, 1);
  }

  head_kernel<<<MM, blk, 0, stream>>>(x, lnout_w, lnout_b, head_w, out);
}

// Round 7
// 834.675 us; speedup vs baseline: 6.1237x; 1.1458x over previous
//
#include <hip/hip_runtime.h>
#include <hip/hip_bf16.h>
#include <math.h>

#define CC 896
#define TT 512
#define BB 4
#define HH 14
#define NN 64
#define DD 64
#define DGG 160
#define FF4 3584
#define MM (BB*TT)   // 2048
#define RD 8         // scan ring depth
#define NCH 16       // chunks per (b,h)
#define CL 32        // chunk length = TT/NCH

typedef __attribute__((ext_vector_type(8))) short bf16x8;
typedef __attribute__((ext_vector_type(4))) float f32x4;

__device__ __forceinline__ float waveRedSum(float x) {
#pragma unroll
  for (int off = 32; off > 0; off >>= 1) x += __shfl_xor(x, off, 64);
  return x;
}

__device__ __forceinline__ float sigmoidf_(float x) { return 1.f / (1.f + expf(-x)); }

__device__ __forceinline__ ushort bf16bits(float v) {
  __hip_bfloat16 h = __float2bfloat16(v);
  return *(ushort*)&h;
}

__device__ __forceinline__ void gload_lds16(const void* g, void* l) {
  __builtin_amdgcn_global_load_lds((const __attribute__((address_space(1))) void*)g,
                                   (__attribute__((address_space(3))) void*)l, 16, 0, 0);
}
__device__ __forceinline__ void gload_lds4(const void* g, void* l) {
  __builtin_amdgcn_global_load_lds((const __attribute__((address_space(1))) void*)g,
                                   (__attribute__((address_space(3))) void*)l, 4, 0, 0);
}

// ---------------- LayerNorm with idx gather (embedding + ln0) ----------------
__global__ __launch_bounds__(256)
void ln_kernel(const float* __restrict__ in, const int* __restrict__ idx,
               const float* __restrict__ w, const float* __restrict__ bvec,
               float* __restrict__ out)
{
  int m = blockIdx.x;
  const float* row = idx ? (in + (size_t)idx[m] * CC) : (in + (size_t)m * CC);
  float s = 0.f, s2 = 0.f;
  for (int c = threadIdx.x; c < CC; c += 256) { float x = row[c]; s += x; s2 += x * x; }
  __shared__ float red[2][4];
  float a = waveRedSum(s), b2 = waveRedSum(s2);
  int wid = threadIdx.x >> 6;
  if ((threadIdx.x & 63) == 0) { red[0][wid] = a; red[1][wid] = b2; }
  __syncthreads();
  s  = red[0][0] + red[0][1] + red[0][2] + red[0][3];
  s2 = red[1][0] + red[1][1] + red[1][2] + red[1][3];
  float mean = s * (1.f / CC);
  float var  = s2 * (1.f / CC) - mean * mean;
  float inv  = rsqrtf(var + 1e-5f);
  float* orow = out + (size_t)m * CC;
  for (int c = threadIdx.x; c < CC; c += 256)
    orow[c] = (row[c] - mean) * inv * w[c] + bvec[c];
}

// ---------------- final LN + head ----------------
__global__ __launch_bounds__(256)
void head_kernel(const float* __restrict__ x, const float* __restrict__ w,
                 const float* __restrict__ bvec, const float* __restrict__ hw,
                 float* __restrict__ out)
{
  int m = blockIdx.x;
  const float* row = x + (size_t)m * CC;
  float s = 0.f, s2 = 0.f;
  for (int c = threadIdx.x; c < CC; c += 256) { float v = row[c]; s += v; s2 += v * v; }
  __shared__ float red[2][4];
  float a = waveRedSum(s), b2 = waveRedSum(s2);
  int wid = threadIdx.x >> 6;
  if ((threadIdx.x & 63) == 0) { red[0][wid] = a; red[1][wid] = b2; }
  __syncthreads();
  s  = red[0][0] + red[0][1] + red[0][2] + red[0][3];
  s2 = red[1][0] + red[1][1] + red[1][2] + red[1][3];
  float mean = s * (1.f / CC);
  float var  = s2 * (1.f / CC) - mean * mean;
  float inv  = rsqrtf(var + 1e-5f);
  float p = 0.f;
  for (int c = threadIdx.x; c < CC; c += 256)
    p += ((row[c] - mean) * inv * w[c] + bvec[c]) * hw[c];
  p = waveRedSum(p);
  __shared__ float red2[4];
  if ((threadIdx.x & 63) == 0) red2[wid] = p;
  __syncthreads();
  if (threadIdx.x == 0) out[m] = red2[0] + red2[1] + red2[2] + red2[3];
}

// ---------------- fused LN + 6-way token-shift mix (time-mix entry) ----------------
__global__ __launch_bounds__(256)
void lnmix6_kernel(const float* __restrict__ x, const float* __restrict__ w,
                   const float* __restrict__ bvec,
                   const float* __restrict__ cr, const float* __restrict__ cw,
                   const float* __restrict__ ck, const float* __restrict__ cv,
                   const float* __restrict__ ca, const float* __restrict__ cg,
                   __hip_bfloat16* __restrict__ outr, __hip_bfloat16* __restrict__ outw,
                   __hip_bfloat16* __restrict__ outk, __hip_bfloat16* __restrict__ outv,
                   __hip_bfloat16* __restrict__ outa, __hip_bfloat16* __restrict__ outg)
{
  int m = blockIdx.x;
  int t = m % TT;
  const float* row  = x + (size_t)m * CC;
  const float* prow = row - CC;
  float s = 0.f, s2 = 0.f, sp = 0.f, sp2 = 0.f;
  for (int c = threadIdx.x; c < CC; c += 256) {
    float xv = row[c]; s += xv; s2 += xv * xv;
    if (t > 0) { float pv = prow[c]; sp += pv; sp2 += pv * pv; }
  }
  float a0 = waveRedSum(s), a1 = waveRedSum(s2), a2 = waveRedSum(sp), a3 = waveRedSum(sp2);
  __shared__ float red[4][4];
  int wid = threadIdx.x >> 6;
  if ((threadIdx.x & 63) == 0) { red[0][wid]=a0; red[1][wid]=a1; red[2][wid]=a2; red[3][wid]=a3; }
  __syncthreads();
  s   = red[0][0]+red[0][1]+red[0][2]+red[0][3];
  s2  = red[1][0]+red[1][1]+red[1][2]+red[1][3];
  sp  = red[2][0]+red[2][1]+red[2][2]+red[2][3];
  sp2 = red[3][0]+red[3][1]+red[3][2]+red[3][3];
  float mean = s * (1.f / CC);
  float inv  = rsqrtf(s2 * (1.f / CC) - mean * mean + 1e-5f);
  float meanp = sp * (1.f / CC);
  float invp  = rsqrtf(sp2 * (1.f / CC) - meanp * meanp + 1e-5f);
  for (int c = threadIdx.x; c < CC; c += 256) {
    float xnv = (row[c] - mean) * inv * w[c] + bvec[c];
    float xpv = (t > 0) ? (prow[c] - meanp) * invp * w[c] + bvec[c] : 0.f;
    float d = xpv - xnv;
    size_t off = (size_t)m * CC + c;
    outr[off] = __float2bfloat16(fmaf(d, cr[c], xnv));
    outw[off] = __float2bfloat16(fmaf(d, cw[c], xnv));
    outk[off] = __float2bfloat16(fmaf(d, ck[c], xnv));
    outv[off] = __float2bfloat16(fmaf(d, cv[c], xnv));
    outa[off] = __float2bfloat16(fmaf(d, ca[c], xnv));
    outg[off] = __float2bfloat16(fmaf(d, cg[c], xnv));
  }
}

// ---------------- fused LN + single mix (channel-mix entry) ----------------
__global__ __launch_bounds__(256)
void lnmixc_kernel(const float* __restrict__ x, const float* __restrict__ w,
                   const float* __restrict__ bvec, const float* __restrict__ coef,
                   __hip_bfloat16* __restrict__ outb)
{
  int m = blockIdx.x;
  int t = m % TT;
  const float* row  = x + (size_t)m * CC;
  const float* prow = row - CC;
  float s = 0.f, s2 = 0.f, sp = 0.f, sp2 = 0.f;
  for (int c = threadIdx.x; c < CC; c += 256) {
    float xv = row[c]; s += xv; s2 += xv * xv;
    if (t > 0) { float pv = prow[c]; sp += pv; sp2 += pv * pv; }
  }
  float a0 = waveRedSum(s), a1 = waveRedSum(s2), a2 = waveRedSum(sp), a3 = waveRedSum(sp2);
  __shared__ float red[4][4];
  int wid = threadIdx.x >> 6;
  if ((threadIdx.x & 63) == 0) { red[0][wid]=a0; red[1][wid]=a1; red[2][wid]=a2; red[3][wid]=a3; }
  __syncthreads();
  s   = red[0][0]+red[0][1]+red[0][2]+red[0][3];
  s2  = red[1][0]+red[1][1]+red[1][2]+red[1][3];
  sp  = red[2][0]+red[2][1]+red[2][2]+red[2][3];
  sp2 = red[3][0]+red[3][1]+red[3][2]+red[3][3];
  float mean = s * (1.f / CC);
  float inv  = rsqrtf(s2 * (1.f / CC) - mean * mean + 1e-5f);
  float meanp = sp * (1.f / CC);
  float invp  = rsqrtf(sp2 * (1.f / CC) - meanp * meanp + 1e-5f);
  for (int c = threadIdx.x; c < CC; c += 256) {
    float xnv = (row[c] - mean) * inv * w[c] + bvec[c];
    float xpv = (t > 0) ? (prow[c] - meanp) * invp * w[c] + bvec[c] : 0.f;
    outb[(size_t)m * CC + c] = __float2bfloat16(fmaf(xpv - xnv, coef[c], xnv));
  }
}

// ---------------- convert + transpose body ----------------
__device__ __forceinline__ void convT_body(const float* __restrict__ W,
                                           __hip_bfloat16* __restrict__ Wt,
                                           int K, int N, int KP, int NP,
                                           int bx, int by)
{
  __shared__ float tile[32][33];
  int bn = bx * 32, bk = by * 32;
  int tx = threadIdx.x & 31, ty = threadIdx.x >> 5;
#pragma unroll
  for (int i = 0; i < 4; i++) {
    int k = bk + ty + i * 8, n = bn + tx;
    tile[ty + i * 8][tx] = (k < K && n < N) ? W[(size_t)k * N + n] : 0.f;
  }
  __syncthreads();
#pragma unroll
  for (int i = 0; i < 4; i++) {
    int n = bn + ty + i * 8, k = bk + tx;
    if (n < NP && k < KP)
      Wt[(size_t)n * KP + k] = __float2bfloat16(tile[tx][ty + i * 8]);
  }
}

// all small per-layer weights in one launch, grid (28,28,12)
__global__ __launch_bounds__(256)
void convT_batch(const float* Wr, const float* Wk, const float* Wv, const float* Wo,
                 const float* a1, const float* a2, const float* v1, const float* v2,
                 const float* g1, const float* g2, const float* w1, const float* w2,
                 __hip_bfloat16* WrT, __hip_bfloat16* WkT, __hip_bfloat16* WvT,
                 __hip_bfloat16* WoT, __hip_bfloat16* a1T, __hip_bfloat16* a2T,
                 __hip_bfloat16* v1T, __hip_bfloat16* v2T, __hip_bfloat16* g1T,
                 __hip_bfloat16* g2T, __hip_bfloat16* w1T, __hip_bfloat16* w2T)
{
  const float* W; __hip_bfloat16* Wt; int K, N, KP, NP;
  switch (blockIdx.z) {
    case 0:  W = Wr; Wt = WrT; K = CC;  N = CC;  KP = CC;  NP = CC;  break;
    case 1:  W = Wk; Wt = WkT; K = CC;  N = CC;  KP = CC;  NP = CC;  break;
    case 2:  W = Wv; Wt = WvT; K = CC;  N = CC;  KP = CC;  NP = CC;  break;
    case 3:  W = Wo; Wt = WoT; K = CC;  N = CC;  KP = CC;  NP = CC;  break;
    case 4:  W = a1; Wt = a1T; K = CC;  N = DD;  KP = CC;  NP = DD;  break;
    case 5:  W = a2; Wt = a2T; K = DD;  N = CC;  KP = DD;  NP = CC;  break;
    case 6:  W = v1; Wt = v1T; K = CC;  N = DD;  KP = CC;  NP = DD;  break;
    case 7:  W = v2; Wt = v2T; K = DD;  N = CC;  KP = DD;  NP = CC;  break;
    case 8:  W = g1; Wt = g1T; K = CC;  N = DGG; KP = CC;  NP = 192; break;
    case 9:  W = g2; Wt = g2T; K = DGG; N = CC;  KP = 192; NP = CC;  break;
    case 10: W = w1; Wt = w1T; K = CC;  N = DD;  KP = CC;  NP = DD;  break;
    default: W = w2; Wt = w2T; K = DD;  N = CC;  KP = DD;  NP = CC;  break;
  }
  if ((int)blockIdx.x * 32 >= NP || (int)blockIdx.y * 32 >= KP) return;
  convT_body(W, Wt, K, N, KP, NP, blockIdx.x, blockIdx.y);
}

// the two big channel-mix weights, grid (112, 28, 2)
__global__ __launch_bounds__(256)
void convT_big(const float* fk, const float* fv,
               __hip_bfloat16* fkT, __hip_bfloat16* fvT)
{
  if (blockIdx.z == 0)
    convT_body(fk, fkT, CC, FF4, CC, FF4, blockIdx.x, blockIdx.y);
  else
    convT_body(fv, fvT, FF4, CC, FF4, CC, blockIdx.y, blockIdx.x);
}

// ---------------- bf16 MFMA GEMM body: C[M][N] = A[M][K] * Bt[N][K]^T ----------------
// epi (runtime): 0 store f32, 1 add f32, 2 relu^2->bf16, 3 store bf16,
//   4 sigmoid->bf16 (0 past Nreal), 5 sigmoid(bias+v)->f32, 6 v-gate->f32,
//   7 decay(bias)->f32, 8 tanh->bf16
// bf16 outputs are re-staged through LDS for full-width coalesced stores
// (direct 2B/lane fragment stores caused ~25x HBM write amplification).
template<int BN>
__device__ __forceinline__ void gemm_body(const __hip_bfloat16* __restrict__ A,
    const __hip_bfloat16* __restrict__ Bt, float* __restrict__ C,
    __hip_bfloat16* __restrict__ Cbf, int N, int K, const float* __restrict__ bias,
    const float* __restrict__ aux0, const float* __restrict__ aux1, int Nreal,
    int bx, int by, int epi)
{
  constexpr int WN = BN / 64;
  constexpr int WM = 4 / WN;
  constexpr int ROWS = 128 / WM;
  constexpr int MI = ROWS / 16;
  __shared__ __align__(16) ushort ldsu[128 * 64 + BN * 64];
  ushort* As = ldsu;
  ushort* Bs = ldsu + 128 * 64;
  int tid = threadIdx.x;
  int lane = tid & 63, wave = tid >> 6;
  int wm, wn;
  if constexpr (WN == 2) { wm = wave >> 1; wn = wave & 1; } else { wm = wave; wn = 0; }
  int fl = lane & 15, fh = lane >> 4;
  int row0 = by * 128, col0 = bx * BN;

  const char* Abase = (const char*)A + (size_t)row0 * (size_t)(K * 2);
  const char* Bbase = (const char*)Bt + (size_t)col0 * (size_t)(K * 2);
  char* AsB = (char*)As;
  char* BsB = (char*)Bs;

  f32x4 acc[MI][4];
#pragma unroll
  for (int mi = 0; mi < MI; mi++)
#pragma unroll
    for (int ni = 0; ni < 4; ni++)
      acc[mi][ni] = (f32x4){0.f, 0.f, 0.f, 0.f};

  int srow = tid >> 3;
  int scol = (tid & 7) << 4;
  int ldsw = (wave << 10);

  for (int k0 = 0; k0 < K; k0 += 64) {
#pragma unroll
    for (int it = 0; it < 4; ++it) {
      int r = it * 32 + srow;
      int cbs = scol ^ ((r & 7) << 4);
      size_t goff = (size_t)r * (size_t)(K * 2) + (size_t)(k0 * 2) + cbs;
      gload_lds16(Abase + goff, AsB + (it << 12) + ldsw);
      if constexpr (BN == 128) {
        gload_lds16(Bbase + goff, BsB + (it << 12) + ldsw);
      } else {
        if (it < 2) gload_lds16(Bbase + goff, BsB + (it << 12) + ldsw);
      }
    }
    __syncthreads();
#pragma unroll
    for (int kk = 0; kk < 2; ++kk) {
      bf16x8 af[MI], bfr[4];
      int kb_ = kk * 64 + (fh << 4);
#pragma unroll
      for (int mi = 0; mi < MI; mi++) {
        int r = wm * ROWS + mi * 16 + fl;
        af[mi] = *(const bf16x8*)(AsB + r * 128 + (kb_ ^ ((r & 7) << 4)));
      }
#pragma unroll
      for (int ni = 0; ni < 4; ni++) {
        int r = wn * 64 + ni * 16 + fl;
        bfr[ni] = *(const bf16x8*)(BsB + r * 128 + (kb_ ^ ((r & 7) << 4)));
      }
#pragma unroll
      for (int mi = 0; mi < MI; mi++)
#pragma unroll
        for (int ni = 0; ni < 4; ni++)
          acc[mi][ni] = __builtin_amdgcn_mfma_f32_16x16x32_bf16(af[mi], bfr[ni], acc[mi][ni], 0, 0, 0);
    }
    __syncthreads();
  }

  if (epi == 2 || epi == 3 || epi == 4 || epi == 8) {
    // --- bf16 output: stage tile in LDS, then coalesced 16B stores ---
#pragma unroll
    for (int mi = 0; mi < MI; mi++) {
      int lrow0 = wm * ROWS + mi * 16 + fh * 4;
#pragma unroll
      for (int ni = 0; ni < 4; ni++) {
        int lcol = wn * 64 + ni * 16 + fl;
        int gcol = col0 + lcol;
#pragma unroll
        for (int e = 0; e < 4; e++) {
          float v = acc[mi][ni][e];
          float o;
          if (epi == 2)      { float t = fmaxf(v, 0.f); o = t * t; }
          else if (epi == 4) { o = (gcol < Nreal) ? sigmoidf_(v) : 0.f; }
          else if (epi == 8) { o = tanhf(v); }
          else               { o = v; }
          ldsu[(lrow0 + e) * BN + lcol] = bf16bits(o);
        }
      }
    }
    __syncthreads();
    constexpr int ITER = (128 * BN) / (256 * 8);
#pragma unroll
    for (int it2 = 0; it2 < ITER; ++it2) {
      int idx = (it2 * 256 + tid) * 8;
      int row = idx / BN;
      int col = idx - row * BN;
      float4 v4 = *(const float4*)&ldsu[idx];
      *(float4*)((char*)Cbf + ((size_t)(row0 + row) * N + col0 + col) * 2) = v4;
    }
  } else {
    // --- f32 output: direct stores (64B/row-segment, full cache lines) ---
#pragma unroll
    for (int mi = 0; mi < MI; mi++) {
      int crow0 = row0 + wm * ROWS + mi * 16 + fh * 4;
#pragma unroll
      for (int ni = 0; ni < 4; ni++) {
        int ccol = col0 + wn * 64 + ni * 16 + fl;
#pragma unroll
        for (int e = 0; e < 4; e++) {
          size_t off = (size_t)(crow0 + e) * N + ccol;
          float v = acc[mi][ni][e];
          switch (epi) {
            case 0: C[off] = v; break;
            case 1: C[off] += v; break;
            case 5: C[off] = sigmoidf_(bias[ccol] + v); break;
            case 6: { float sg = sigmoidf_(bias[ccol] + v);
                      float vv = aux0[off];
                      C[off] = vv + (aux1[off] - vv) * sg; } break;
            default: { float z_ = bias[ccol] + v;                       // 7: decay
                       float sp_ = fmaxf(-z_, 0.f) + log1pf(expf(-fabsf(z_)));
                       C[off] = expf(-expf(-sp_ - 0.5f)); } break;
          }
        }
      }
    }
  }
}

// generic single-GEMM kernel with runtime epilogue
template<int BN>
__global__ __launch_bounds__(256)
void gemm_ep(const __hip_bfloat16* __restrict__ A, const __hip_bfloat16* __restrict__ Bt,
             float* __restrict__ C, __hip_bfloat16* __restrict__ Cbf,
             int N, int K, const float* __restrict__ bias,
             const float* __restrict__ aux0, const float* __restrict__ aux1,
             int Nreal, int epi)
{
  gemm_body<BN>(A, Bt, C, Cbf, N, K, bias, aux0, aux1, Nreal, blockIdx.x, blockIdx.y, epi);
}

// batched r/k/v projection, grid (7,16,3)
__global__ __launch_bounds__(256)
void gemm_rkv(const __hip_bfloat16* Ar, const __hip_bfloat16* Ak, const __hip_bfloat16* Av,
              const __hip_bfloat16* Br, const __hip_bfloat16* Bk, const __hip_bfloat16* Bv,
              float* Cr, float* Ck, float* Cv)
{
  const __hip_bfloat16* A; const __hip_bfloat16* Bt; float* C;
  if (blockIdx.z == 0)      { A = Ar; Bt = Br; C = Cr; }
  else if (blockIdx.z == 1) { A = Ak; Bt = Bk; C = Ck; }
  else                      { A = Av; Bt = Bv; C = Cv; }
  gemm_body<128>(A, Bt, C, nullptr, CC, CC, nullptr, nullptr, nullptr, CC,
                 blockIdx.x, blockIdx.y, 0);
}

// batched LoRA stage-1: grid (6,16). z: 0 w1(tanh), 1 a1, 2 v1, 3..5 g1 tiles
__global__ __launch_bounds__(256)
void lora1_batch(const __hip_bfloat16* mixw, const __hip_bfloat16* mixa,
                 const __hip_bfloat16* mixv, const __hip_bfloat16* mixg,
                 const __hip_bfloat16* w1T, const __hip_bfloat16* a1T,
                 const __hip_bfloat16* v1T, const __hip_bfloat16* g1T,
                 __hip_bfloat16* t64w, __hip_bfloat16* t64a,
                 __hip_bfloat16* t64v, __hip_bfloat16* t160)
{
  int z = blockIdx.x;
  const __hip_bfloat16 *A, *Bt; __hip_bfloat16* Cbf; int N, epi, bx, Nreal;
  if (z == 0)      { A = mixw; Bt = w1T; Cbf = t64w; N = 64;  epi = 8; bx = 0; Nreal = 64; }
  else if (z == 1) { A = mixa; Bt = a1T; Cbf = t64a; N = 64;  epi = 3; bx = 0; Nreal = 64; }
  else if (z == 2) { A = mixv; Bt = v1T; Cbf = t64v; N = 64;  epi = 3; bx = 0; Nreal = 64; }
  else             { A = mixg; Bt = g1T; Cbf = t160; N = 192; epi = 4; bx = z - 3; Nreal = DGG; }
  gemm_body<64>(A, Bt, nullptr, Cbf, N, CC, nullptr, nullptr, nullptr, Nreal,
                bx, blockIdx.y, epi);
}

// batched LoRA stage-2: grid (7,16,nz). z: 0 w2(decay), 1 a2(sig), 2 g2, 3 v2(gate)
__global__ __launch_bounds__(256)
void lora2_batch(const __hip_bfloat16* t64w, const __hip_bfloat16* t64a,
                 const __hip_bfloat16* t160, const __hip_bfloat16* t64v,
                 const __hip_bfloat16* w2T, const __hip_bfloat16* a2T,
                 const __hip_bfloat16* g2T, const __hip_bfloat16* v2T,
                 float* dcy, float* ab, float* gb, float* vb,
                 const float* w0l, const float* a0l, const float* v0l,
                 const float* vfirst)
{
  int z = blockIdx.z;
  const __hip_bfloat16 *A, *Bt; float* C; const float* bias;
  const float *ax0, *ax1; int K, epi;
  if (z == 0)      { A = t64w; Bt = w2T; C = dcy; bias = w0l; K = 64;  epi = 7; ax0 = nullptr; ax1 = nullptr; }
  else if (z == 1) { A = t64a; Bt = a2T; C = ab;  bias = a0l; K = 64;  epi = 5; ax0 = nullptr; ax1 = nullptr; }
  else if (z == 2) { A = t160; Bt = g2T; C = gb;  bias = nullptr; K = 192; epi = 0; ax0 = nullptr; ax1 = nullptr; }
  else             { A = t64v; Bt = v2T; C = vb;  bias = v0l; K = 64;  epi = 6; ax0 = vb; ax1 = vfirst; }
  gemm_body<128>(A, Bt, C, nullptr, CC, K, bias, ax0, ax1, CC, blockIdx.x, blockIdx.y, epi);
}

// ---------------- prep: kk norm, a_in=-kk, b_in=kk*a, k gating ----------------
__global__ __launch_bounds__(896)
void prep_kernel(const float* __restrict__ k_in, const float* __restrict__ a,
                 const float* __restrict__ k_k, const float* __restrict__ k_a,
                 float* __restrict__ kout, float* __restrict__ ain, float* __restrict__ bin)
{
  int m = blockIdx.x;
  int c = threadIdx.x;
  size_t off = (size_t)m * CC + c;
  float kv = k_in[off];
  float av = a[off];
  float kkv = kv * k_k[c];
  float ss = waveRedSum(kkv * kkv);
  float norm = sqrtf(ss);
  float kkn = kkv / fmaxf(norm, 1e-12f);
  ain[off] = -kkn;
  bin[off] = kkn * av;
  kout[off] = kv * (1.f + (av - 1.f) * k_a[c]);
}

// ================= chunk-parallel RWKV7 scan =================
// Phase 1 (896 blocks): chunk-local zero-state scan (Z,y0) + P product + u.
__global__ __launch_bounds__(256)
void scanp1_kernel(const float* __restrict__ rp, const float* __restrict__ dp,
                   const float* __restrict__ kp, const float* __restrict__ vp,
                   const float* __restrict__ ap, const float* __restrict__ bp_,
                   float* __restrict__ yp, float* __restrict__ ubuf,
                   float* __restrict__ Pc, float* __restrict__ Zc)
{
  int bid = blockIdx.x;
  int bh = bid >> 4, c = bid & 15;
  int b = bh / HH, h = bh - b * HH;
  int tid = threadIdx.x, lane = tid & 63, w = tid >> 6;
  int w16 = w * 16;
  __shared__ __align__(16) float ring[RD][6][64];   // 0 r, 1 d, 2 k, 3 a, 4 b, 5 v
  __shared__ float sa_part[2][4][64];
  __shared__ float pa_part[2][4][64];
  __shared__ float y_part[2][4][64];
  __shared__ float u_part[2][4][64];

  float s[16], p[16];
#pragma unroll
  for (int jj = 0; jj < 16; jj++) {
    s[jj] = 0.f;
    p[jj] = (lane == w16 + jj) ? 1.f : 0.f;
  }
  size_t base = ((size_t)b * TT + (size_t)c * CL) * CC + (size_t)h * NN + lane;

  const float* gA = nullptr; const float* gB = nullptr; int slA = 0, slB = 0;
  if (w == 1)      { gA = rp;  slA = 0; gB = dp;  slB = 1; }
  else if (w == 2) { gA = kp;  slA = 2; gB = vp;  slB = 5; }
  else if (w == 3) { gA = ap;  slA = 3; gB = bp_; slB = 4; }

  if (w) {
    for (int t0 = 0; t0 < RD; t0++) {
      gload_lds4(gA + base + (size_t)t0 * CC, &ring[t0][slA][0]);
      gload_lds4(gB + base + (size_t)t0 * CC, &ring[t0][slB][0]);
    }
    asm volatile("s_waitcnt vmcnt(0)" ::: "memory");
  }
  __builtin_amdgcn_s_barrier();
  __builtin_amdgcn_sched_barrier(0);

  for (int t = 0; t < CL; ++t) {
    int Pp = t & 1, Qp = Pp ^ 1;
    int slot = t & (RD - 1);
    float av[16], dv[16], kv[16], bv[16], rv[16];
#pragma unroll
    for (int q = 0; q < 4; q++) {
      *(float4*)&av[q * 4] = *(const float4*)&ring[slot][3][w16 + q * 4];
      *(float4*)&dv[q * 4] = *(const float4*)&ring[slot][1][w16 + q * 4];
      *(float4*)&kv[q * 4] = *(const float4*)&ring[slot][2][w16 + q * 4];
      *(float4*)&bv[q * 4] = *(const float4*)&ring[slot][4][w16 + q * 4];
      *(float4*)&rv[q * 4] = *(const float4*)&ring[slot][0][w16 + q * 4];
    }
    float vi = ring[slot][5][lane];
    float sp0 = 0.f, sp1 = 0.f, pp0 = 0.f, pp1 = 0.f;
#pragma unroll
    for (int jj = 0; jj < 8; jj++) {
      sp0 = fmaf(s[jj],     av[jj],     sp0);
      sp1 = fmaf(s[jj + 8], av[jj + 8], sp1);
      pp0 = fmaf(p[jj],     av[jj],     pp0);
      pp1 = fmaf(p[jj + 8], av[jj + 8], pp1);
    }
    sa_part[Pp][w][lane] = sp0 + sp1;
    pa_part[Pp][w][lane] = pp0 + pp1;
    if (w) { asm volatile("s_waitcnt vmcnt(12)" ::: "memory"); }
    asm volatile("s_waitcnt lgkmcnt(0)" ::: "memory");
    __builtin_amdgcn_s_barrier();
    __builtin_amdgcn_sched_barrier(0);
    if (w && t + RD < CL) {
      gload_lds4(gA + base + (size_t)(t + RD) * CC, &ring[slot][slA][0]);
      gload_lds4(gB + base + (size_t)(t + RD) * CC, &ring[slot][slB][0]);
    }
    if (w == 0 && t > 0) {
      float yo = (y_part[Qp][0][lane] + y_part[Qp][1][lane])
               + (y_part[Qp][2][lane] + y_part[Qp][3][lane]);
      yp[base + (size_t)(t - 1) * CC] = yo;
      float uo = (u_part[Qp][0][lane] + u_part[Qp][1][lane])
               + (u_part[Qp][2][lane] + u_part[Qp][3][lane]);
      ubuf[((size_t)bid * CL + (t - 1)) * 64 + lane] = uo;
    }
    float sa = (sa_part[Pp][0][lane] + sa_part[Pp][1][lane])
             + (sa_part[Pp][2][lane] + sa_part[Pp][3][lane]);
    float pa = (pa_part[Pp][0][lane] + pa_part[Pp][1][lane])
             + (pa_part[Pp][2][lane] + pa_part[Pp][3][lane]);
    float y0 = 0.f, y1 = 0.f, u0 = 0.f, u1 = 0.f;
#pragma unroll
    for (int jj = 0; jj < 8; jj++) {
      s[jj]     = fmaf(s[jj],     dv[jj],     fmaf(sa, bv[jj],     vi * kv[jj]));
      y0 = fmaf(s[jj], rv[jj], y0);
      s[jj + 8] = fmaf(s[jj + 8], dv[jj + 8], fmaf(sa, bv[jj + 8], vi * kv[jj + 8]));
      y1 = fmaf(s[jj + 8], rv[jj + 8], y1);
      p[jj]     = fmaf(p[jj],     dv[jj],     pa * bv[jj]);
      u0 = fmaf(p[jj], rv[jj], u0);
      p[jj + 8] = fmaf(p[jj + 8], dv[jj + 8], pa * bv[jj + 8]);
      u1 = fmaf(p[jj + 8], rv[jj + 8], u1);
    }
    y_part[Pp][w][lane] = y0 + y1;
    u_part[Pp][w][lane] = u0 + u1;
  }

  asm volatile("s_waitcnt lgkmcnt(0)" ::: "memory");
  __builtin_amdgcn_s_barrier();
  if (w == 0) {
    int Pl = (CL - 1) & 1;
    float yo = (y_part[Pl][0][lane] + y_part[Pl][1][lane])
             + (y_part[Pl][2][lane] + y_part[Pl][3][lane]);
    yp[base + (size_t)(CL - 1) * CC] = yo;
    float uo = (u_part[Pl][0][lane] + u_part[Pl][1][lane])
             + (u_part[Pl][2][lane] + u_part[Pl][3][lane]);
    ubuf[((size_t)bid * CL + (CL - 1)) * 64 + lane] = uo;
  }
  float* zp = Zc + ((size_t)bid * 64 + lane) * 64 + w16;
  float* pq = Pc + ((size_t)bid * 64 + lane) * 64 + w16;
#pragma unroll
  for (int q = 0; q < 4; q++) {
    *(float4*)&zp[q * 4] = make_float4(s[q*4], s[q*4+1], s[q*4+2], s[q*4+3]);
    *(float4*)&pq[q * 4] = make_float4(p[q*4], p[q*4+1], p[q*4+2], p[q*4+3]);
  }
}

// Phase 2 (56 blocks): Sin[c] = S; S = S*P_c + Z_c, sequential over c
__global__ __launch_bounds__(256)
void scanp2_kernel(const float* __restrict__ Pc, const float* __restrict__ Zc,
                   float* __restrict__ Sin)
{
  int bh = blockIdx.x;
  int tid = threadIdx.x, i = tid & 63, jg = tid >> 6, j0 = jg * 16;
  __shared__ float S_lds[64][65];
  __shared__ __align__(16) float P_lds[64][64];
#pragma unroll
  for (int jj = 0; jj < 16; jj++) S_lds[i][j0 + jj] = 0.f;

  for (int c = 0; c < NCH; c++) {
    size_t bidc = (size_t)(bh * NCH + c);
    {
      const float4* src = (const float4*)(Pc + bidc * 4096 + (size_t)tid * 16);
      float4* dst = (float4*)(&P_lds[0][0] + tid * 16);
      dst[0] = src[0]; dst[1] = src[1]; dst[2] = src[2]; dst[3] = src[3];
    }
    __syncthreads();
    float sv[16];
#pragma unroll
    for (int jj = 0; jj < 16; jj++) sv[jj] = S_lds[i][j0 + jj];
    {
      float4* sp_ = (float4*)(Sin + bidc * 4096 + (size_t)i * 64 + j0);
#pragma unroll
      for (int q = 0; q < 4; q++)
        sp_[q] = make_float4(sv[q*4], sv[q*4+1], sv[q*4+2], sv[q*4+3]);
    }
    float nv[16];
#pragma unroll
    for (int jj = 0; jj < 16; jj++) nv[jj] = 0.f;
    for (int m = 0; m < 64; m++) {
      float sm = S_lds[i][m];
#pragma unroll
      for (int jj = 0; jj < 16; jj++)
        nv[jj] = fmaf(sm, P_lds[m][j0 + jj], nv[jj]);
    }
    {
      const float4* zp = (const float4*)(Zc + bidc * 4096 + (size_t)i * 64 + j0);
#pragma unroll
      for (int q = 0; q < 4; q++) {
        float4 z4 = zp[q];
        nv[q*4+0] += z4.x; nv[q*4+1] += z4.y; nv[q*4+2] += z4.z; nv[q*4+3] += z4.w;
      }
    }
    __syncthreads();
#pragma unroll
    for (int jj = 0; jj < 16; jj++) S_lds[i][j0 + jj] = nv[jj];
  }
}

// Phase 3 + groupnorm + rk*v + gate fused (896 blocks)
__global__ __launch_bounds__(256)
void scanp3gn_kernel(const float* __restrict__ Sin, const float* __restrict__ ubuf,
                     const float* __restrict__ y0p,
                     const float* __restrict__ rp, const float* __restrict__ kp,
                     const float* __restrict__ vp, const float* __restrict__ gp,
                     const float* __restrict__ lnxw, const float* __restrict__ lnxb,
                     const float* __restrict__ rkco,
                     __hip_bfloat16* __restrict__ yout)
{
  int bid = blockIdx.x;
  int bh = bid >> 4, c = bid & 15;
  int b = bh / HH, h = bh - b * HH;
  int tid = threadIdx.x, i = tid & 63, wv = tid >> 6;
  __shared__ float S_lds[64][65];
  __shared__ __align__(16) float U_lds[CL][64];
  {
    int r = tid >> 2, q = tid & 3;
    const float* src = Sin + (size_t)bid * 4096 + (size_t)r * 64 + q * 16;
#pragma unroll
    for (int jj = 0; jj < 16; jj++) S_lds[r][q * 16 + jj] = src[jj];
  }
  {
    int r = tid >> 3, q = tid & 7;
    const float4* us = (const float4*)(ubuf + (size_t)bid * (CL * 64) + (size_t)r * 64 + q * 8);
    float4* ud = (float4*)(&U_lds[r][q * 8]);
    ud[0] = us[0]; ud[1] = us[1];
  }
  __syncthreads();
  float sreg[64];
#pragma unroll
  for (int m = 0; m < 64; m++) sreg[m] = S_lds[i][m];
  int ch = h * NN + i;
  float lw = lnxw[ch], lb = lnxb[ch], rkc = rkco[ch];
  size_t rowbase = ((size_t)b * TT + (size_t)c * CL) * CC + ch;
#pragma unroll 1
  for (int tt = 0; tt < CL / 4; tt++) {
    int t = wv * (CL / 4) + tt;
    size_t off = rowbase + (size_t)t * CC;
    float a0 = 0.f, a1 = 0.f, a2 = 0.f, a3 = 0.f;
#pragma unroll
    for (int m4 = 0; m4 < 16; m4++) {
      float4 uu = *(const float4*)&U_lds[t][m4 * 4];
      a0 = fmaf(sreg[m4*4+0], uu.x, a0);
      a1 = fmaf(sreg[m4*4+1], uu.y, a1);
      a2 = fmaf(sreg[m4*4+2], uu.z, a2);
      a3 = fmaf(sreg[m4*4+3], uu.w, a3);
    }
    float yv = y0p[off] + (a0 + a1) + (a2 + a3);
    float s1 = waveRedSum(yv);
    float s2 = waveRedSum(yv * yv);
    float mean = s1 * (1.f / 64.f);
    float var  = s2 * (1.f / 64.f) - mean * mean;
    float norm = (yv - mean) * rsqrtf(var + 0.00064f);
    float rv = rp[off], kv = kp[off], vv = vp[off], gv = gp[off];
    float rk = waveRedSum(rv * kv * rkc);
    yout[off] = __float2bfloat16((norm * lw + lb + rk * vv) * gv);
  }
}

// ---------------- host ----------------
extern "C" void kernel_launch(void* const* d_in, const int* in_sizes, int n_in,
                              void* d_out, int out_size, void* d_ws, size_t ws_size,
                              hipStream_t stream)
{
  const int*   idx    = (const int*)d_in[0];
  const float* emb    = (const float*)d_in[1];
  const float* ln0_w  = (const float*)d_in[2];
  const float* ln0_b  = (const float*)d_in[3];
  const float* ln1_w  = (const float*)d_in[4];
  const float* ln1_b  = (const float*)d_in[5];
  const float* ln2_w  = (const float*)d_in[6];
  const float* ln2_b  = (const float*)d_in[7];
  const float* x_r    = (const float*)d_in[8];
  const float* x_w    = (const float*)d_in[9];
  const float* x_k    = (const float*)d_in[10];
  const float* x_v    = (const float*)d_in[11];
  const float* x_a    = (const float*)d_in[12];
  const float* x_g    = (const float*)d_in[13];
  const float* w0     = (const float*)d_in[14];
  const float* w1     = (const float*)d_in[15];
  const float* w2     = (const float*)d_in[16];
  const float* a0     = (const float*)d_in[17];
  const float* a1     = (const float*)d_in[18];
  const float* a2     = (const float*)d_in[19];
  const float* v0     = (const float*)d_in[20];
  const float* v1     = (const float*)d_in[21];
  const float* v2     = (const float*)d_in[22];
  const float* g1     = (const float*)d_in[23];
  const float* g2     = (const float*)d_in[24];
  const float* k_k    = (const float*)d_in[25];
  const float* k_a    = (const float*)d_in[26];
  const float* r_k    = (const float*)d_in[27];
  const float* Wr     = (const float*)d_in[28];
  const float* Wk     = (const float*)d_in[29];
  const float* Wv     = (const float*)d_in[30];
  const float* Wo     = (const float*)d_in[31];
  const float* lnx_w  = (const float*)d_in[32];
  const float* lnx_b  = (const float*)d_in[33];
  const float* f_xk   = (const float*)d_in[34];
  const float* f_key  = (const float*)d_in[35];
  const float* f_val  = (const float*)d_in[36];
  const float* lnout_w = (const float*)d_in[37];
  const float* lnout_b = (const float*)d_in[38];
  const float* head_w  = (const float*)d_in[39];
  float* out = (float*)d_out;

  const size_t MC = (size_t)MM * CC;
  const size_t W2 = (size_t)CC * CC;
  float* ws   = (float*)d_ws;
  float* x      = ws;
  float* vfirst = x + MC;
  float* rb     = vfirst + MC;
  float* dcy    = rb + MC;       // rb+dcy contiguous: h_bf alias spans both
  float* kb     = dcy + MC;
  float* vb     = kb + MC;
  float* ab     = vb + MC;
  float* gb     = ab + MC;
  float* ainb   = gb + MC;
  float* binb   = ainb + MC;
  float* yb     = binb + MC;
  float* ubuf   = yb + MC;       // 896*32*64 = MC
  float* Pcb    = ubuf + MC;     // 2*MC
  float* Zcb    = Pcb + 2 * MC;  // 2*MC
  float* Sinb   = Zcb + 2 * MC;  // 2*MC
  float* fend   = Sinb + 2 * MC;

  __hip_bfloat16* mixr_bf = (__hip_bfloat16*)fend;
  __hip_bfloat16* mixw_bf = mixr_bf + MC;
  __hip_bfloat16* mixk_bf = mixw_bf + MC;
  __hip_bfloat16* mixv_bf = mixk_bf + MC;
  __hip_bfloat16* mixa_bf = mixv_bf + MC;
  __hip_bfloat16* mixg_bf = mixa_bf + MC;
  __hip_bfloat16* WrT = mixg_bf + MC;
  __hip_bfloat16* WkT = WrT + W2;
  __hip_bfloat16* WvT = WkT + W2;
  __hip_bfloat16* WoT = WvT + W2;
  __hip_bfloat16* fkT = WoT + W2;                    // [3584][896]
  __hip_bfloat16* fvT = fkT + (size_t)FF4 * CC;      // [896][3584]
  __hip_bfloat16* w1T = fvT + (size_t)FF4 * CC;      // [64][896]
  __hip_bfloat16* a1T = w1T + (size_t)DD * CC;
  __hip_bfloat16* v1T = a1T + (size_t)DD * CC;
  __hip_bfloat16* w2T = v1T + (size_t)DD * CC;       // [896][64]
  __hip_bfloat16* a2T = w2T + (size_t)DD * CC;
  __hip_bfloat16* v2T = a2T + (size_t)DD * CC;
  __hip_bfloat16* g1T = v2T + (size_t)DD * CC;       // [192][896]
  __hip_bfloat16* g2T = g1T + (size_t)192 * CC;      // [896][192]
  __hip_bfloat16* t64w = g2T + (size_t)192 * CC;     // [2048][64]
  __hip_bfloat16* t64a = t64w + (size_t)MM * 64;
  __hip_bfloat16* t64v = t64a + (size_t)MM * 64;
  __hip_bfloat16* t160 = t64v + (size_t)MM * 64;     // [2048][192]
  // aliases on dead f32 regions
  __hip_bfloat16* h_bf  = (__hip_bfloat16*)rb;       // [2048][3584] over rb+dcy
  __hip_bfloat16* yg_bf = (__hip_bfloat16*)ab;       // [2048][896]

  dim3 blk(256);

  ln_kernel<<<MM, blk, 0, stream>>>(emb, idx, ln0_w, ln0_b, x);

  for (int l = 0; l < 2; l++) {
    const float* Wr_l = Wr + (size_t)l * W2;
    const float* Wk_l = Wk + (size_t)l * W2;
    const float* Wv_l = Wv + (size_t)l * W2;
    const float* Wo_l = Wo + (size_t)l * W2;
    const float* w1_l = w1 + (size_t)l * CC * DD;
    const float* w2_l = w2 + (size_t)l * DD * CC;
    const float* a1_l = a1 + (size_t)l * CC * DD;
    const float* a2_l = a2 + (size_t)l * DD * CC;
    const float* v1_l = v1 + (size_t)l * CC * DD;
    const float* v2_l = v2 + (size_t)l * DD * CC;
    const float* g1_l = g1 + (size_t)l * CC * DGG;
    const float* g2_l = g2 + (size_t)l * DGG * CC;
    const float* fk_l = f_key + (size_t)l * CC * FF4;
    const float* fv_l = f_val + (size_t)l * FF4 * CC;

    convT_batch<<<dim3(28, 28, 12), blk, 0, stream>>>(
        Wr_l, Wk_l, Wv_l, Wo_l, a1_l, a2_l, v1_l, v2_l, g1_l, g2_l, w1_l, w2_l,
        WrT, WkT, WvT, WoT, a1T, a2T, v1T, v2T, g1T, g2T, w1T, w2T);
    convT_big<<<dim3(112, 28, 2), blk, 0, stream>>>(fk_l, fv_l, fkT, fvT);

    lnmix6_kernel<<<MM, blk, 0, stream>>>(x, ln1_w + l * CC, ln1_b + l * CC,
        x_r + l * CC, x_w + l * CC, x_k + l * CC, x_v + l * CC, x_a + l * CC, x_g + l * CC,
        mixr_bf, mixw_bf, mixk_bf, mixv_bf, mixa_bf, mixg_bf);

    // r,k,v projections
    gemm_rkv<<<dim3(7, 16, 3), blk, 0, stream>>>(mixr_bf, mixk_bf, mixv_bf,
                                                 WrT, WkT, WvT, rb, kb, vb);
    if (l == 0)
      hipMemcpyAsync(vfirst, vb, MC * sizeof(float), hipMemcpyDeviceToDevice, stream);

    // LoRA stage 1 (w tanh, a, v, g sigmoid) and stage 2 (decay, sigmoid, g, v-gate)
    lora1_batch<<<dim3(6, 16), blk, 0, stream>>>(mixw_bf, mixa_bf, mixv_bf, mixg_bf,
                                                 w1T, a1T, v1T, g1T,
                                                 t64w, t64a, t64v, t160);
    lora2_batch<<<dim3(7, 16, l == 0 ? 3 : 4), blk, 0, stream>>>(
        t64w, t64a, t160, t64v, w2T, a2T, g2T, v2T,
        dcy, ab, gb, vb, w0 + l * CC, a0 + l * CC, v0 + l * CC, vfirst);

    // prep + chunked scan (+fused gn)
    prep_kernel<<<MM, dim3(896), 0, stream>>>(kb, ab, k_k + l * CC, k_a + l * CC,
                                              kb, ainb, binb);
    scanp1_kernel<<<BB * HH * NCH, blk, 0, stream>>>(rb, dcy, kb, vb, ainb, binb,
                                                     yb, ubuf, Pcb, Zcb);
    scanp2_kernel<<<BB * HH, blk, 0, stream>>>(Pcb, Zcb, Sinb);
    scanp3gn_kernel<<<BB * HH * NCH, blk, 0, stream>>>(Sinb, ubuf, yb, rb, kb, vb, gb,
        lnx_w + l * CC, lnx_b + l * CC, r_k + (size_t)l * CC, yg_bf);

    // x += (y*g) @ Wo   (BN=64 -> 224 blocks)
    gemm_ep<64><<<dim3(14, 16), blk, 0, stream>>>(yg_bf, WoT, x, nullptr, CC, CC,
                                                  nullptr, nullptr, nullptr, CC, 1);

    // ---- channel mix ----
    lnmixc_kernel<<<MM, blk, 0, stream>>>(x, ln2_w + l * CC, ln2_b + l * CC,
                                          f_xk + l * CC, mixr_bf);
    gemm_ep<128><<<dim3(28, 16), blk, 0, stream>>>(mixr_bf, fkT, nullptr, h_bf, FF4, CC,
                                                   nullptr, nullptr, nullptr, FF4, 2);
    gemm_ep<64><<<dim3(14, 16), blk, 0, stream>>>(h_bf, fvT, x, nullptr, CC, FF4,
                                                  nullptr, nullptr, nullptr, CC, 1);
  }

  head_kernel<<<MM, blk, 0, stream>>>(x, lnout_w, lnout_b, head_w, out);
}